// Round 2
// baseline (1959.504 us; speedup 1.0000x reference)
//
#include <hip/hip_runtime.h>
#include <math.h>

#define NN 64000      // nodes
#define NE 1024000    // edges
#define NB 4000       // sequences
#define NT 16         // timesteps
#define AS_STRIDE 196 // 16B-aligned float4 rows, (196 mod 32)=4 -> 2-way max on scalar reads (free)

__device__ __forceinline__ float sigm(float x) { return 1.0f / (1.0f + expf(-x)); }

// ---------- degree / norm ----------
__global__ __launch_bounds__(256) void k_deg_init(float* __restrict__ deg) {
    int i = blockIdx.x * 256 + threadIdx.x;
    if (i < NN) deg[i] = 1.0f;
}

__global__ __launch_bounds__(256) void k_deg_accum(const int* __restrict__ ei,
                                                   const float* __restrict__ ew,
                                                   float* __restrict__ deg) {
    int e = blockIdx.x * 256 + threadIdx.x;
    if (e < NE) atomicAdd(&deg[ei[NE + e]], ew[e]);
}

__global__ __launch_bounds__(256) void k_dinv(float* __restrict__ deg) {
    int i = blockIdx.x * 256 + threadIdx.x;
    if (i < NN) deg[i] = rsqrtf(deg[i]);
}

__global__ __launch_bounds__(256) void k_norm(const int* __restrict__ ei,
                                              const float* __restrict__ ew,
                                              const float* __restrict__ dinv,
                                              float* __restrict__ nrm) {
    int e = blockIdx.x * 256 + threadIdx.x;
    if (e < NE) nrm[e] = dinv[ei[e]] * ew[e] * dinv[ei[NE + e]];
}

// ---------- node linear: Y[n][64] = (relu?)X[n][:K] @ W[K][64] ----------
template<int K, bool RELU_IN>
__global__ __launch_bounds__(256) void k_lin(const float* __restrict__ X,
                                             const float* __restrict__ W,
                                             float* __restrict__ Y) {
    __shared__ float Wl[K * 64];
    __shared__ float Xl[4][K];
    int tid = threadIdx.x;
    for (int i = tid; i < K * 64; i += 256) Wl[i] = W[i];
    int n0 = blockIdx.x * 4;
    for (int i = tid; i < 4 * K; i += 256) {
        int r = i / K, d = i % K;
        float v = X[(n0 + r) * K + d];
        Xl[r][d] = RELU_IN ? fmaxf(v, 0.0f) : v;
    }
    __syncthreads();
    int r = tid >> 6, f = tid & 63;
    float acc = 0.0f;
    #pragma unroll
    for (int d = 0; d < K; ++d) acc = fmaf(Xl[r][d], Wl[d * 64 + f], acc);
    Y[(n0 + r) * 64 + f] = acc;
}

// ---------- agg init: agg = lin*dinv^2 + bias ----------
__global__ __launch_bounds__(256) void k_agg_init(const float* __restrict__ lin,
                                                  const float* __restrict__ dinv,
                                                  const float* __restrict__ b,
                                                  float* __restrict__ agg) {
    int i = blockIdx.x * 256 + threadIdx.x;   // i < NN*64
    int n = i >> 6, f = i & 63;
    float di = dinv[n];
    agg[i] = lin[i] * di * di + b[f];
}

// ---------- edge scatter: agg[col] += norm * lin[row] ----------
__global__ __launch_bounds__(256) void k_scatter(const int* __restrict__ ei,
                                                 const float* __restrict__ nrm,
                                                 const float* __restrict__ lin,
                                                 float* __restrict__ agg) {
    int tid = threadIdx.x;
    int e = blockIdx.x * 4 + (tid >> 6);
    int f = tid & 63;
    int r = ei[e];
    int c = ei[NE + e];
    float w = nrm[e];
    atomicAdd(&agg[c * 64 + f], w * lin[r * 64 + f]);
}

// ---------- LSTM weight prep ----------
// Wg[k][u][j]: k<192 (k<64 from W_ih, else W_hh), u<128 hidden unit, j in {i,f,g,o}
// biasg[u][j] = b_ih[j*128+u] + b_hh[j*128+u]
__global__ __launch_bounds__(256) void k_wprep(const float* __restrict__ W_ih,
                                               const float* __restrict__ W_hh,
                                               const float* __restrict__ b_ih,
                                               const float* __restrict__ b_hh,
                                               float* __restrict__ Wg,
                                               float* __restrict__ biasg) {
    int i = blockIdx.x * 256 + threadIdx.x;
    if (i < 192 * 512) {
        int k = i >> 9;
        int rest = i & 511;
        int u = rest >> 2, j = rest & 3;
        int g = j * 128 + u;
        Wg[i] = (k < 64) ? W_ih[g * 64 + k] : W_hh[g * 128 + (k - 64)];
    }
    if (i < 512) {
        int u = i >> 2, j = i & 3;
        biasg[i] = b_ih[j * 128 + u] + b_hh[j * 128 + u];
    }
}

// ---------- LSTM: 16 rows/block; wave w owns units w*16..+15 for ALL rows ----------
// lane: row = lane>>2, units u0 = w*16 + (lane&3)*4 (4 units x 4 gates in regs).
// A-panel As[row][0..63]=relu(seq_t), As[row][64..191]=h_{t-1}; c stays in registers.
__global__ __launch_bounds__(512) void k_lstm(const float* __restrict__ seq,   // pre-relu (NN x 64)
                                              const float* __restrict__ Wg,    // [192][128][4]
                                              const float* __restrict__ biasg, // [128][4]
                                              float* __restrict__ hout) {      // [NB][128]
    __shared__ float As[16][AS_STRIDE];
    int tid = threadIdx.x;
    int w = tid >> 6;
    int lane = tid & 63;
    int r = lane >> 2;                  // 0..15
    int u0 = w * 16 + (lane & 3) * 4;   // 4 units
    int b0 = blockIdx.x * 16;

    // h = 0
    for (int i = tid; i < 16 * 128; i += 512) {
        int rr = i >> 7, k = i & 127;
        As[rr][64 + k] = 0.0f;
    }
    // seq t=0 (fused relu)
    {
        int i = tid * 2;
        int rr = i >> 6, k = i & 63;
        float2 v = *(const float2*)&seq[((b0 + rr) * NT + 0) * 64 + k];
        As[rr][k] = fmaxf(v.x, 0.0f);
        As[rr][k + 1] = fmaxf(v.y, 0.0f);
    }
    float4 bias[4];
    #pragma unroll
    for (int uu = 0; uu < 4; ++uu) bias[uu] = *(const float4*)&biasg[(u0 + uu) * 4];
    float c[4] = {0.0f, 0.0f, 0.0f, 0.0f};
    __syncthreads();

    for (int t = 0; t < NT; ++t) {
        float4 acc[4];
        #pragma unroll
        for (int uu = 0; uu < 4; ++uu) acc[uu] = bias[uu];
        const float* wp = &Wg[u0 * 4];
        #pragma unroll 4
        for (int k = 0; k < 192; ++k) {
            float a = As[r][k];
            const float* wk = wp + k * 512;
            #pragma unroll
            for (int uu = 0; uu < 4; ++uu) {
                float4 wv = *(const float4*)&wk[uu * 4];
                acc[uu].x = fmaf(a, wv.x, acc[uu].x);
                acc[uu].y = fmaf(a, wv.y, acc[uu].y);
                acc[uu].z = fmaf(a, wv.z, acc[uu].z);
                acc[uu].w = fmaf(a, wv.w, acc[uu].w);
            }
        }
        float hv[4];
        #pragma unroll
        for (int uu = 0; uu < 4; ++uu) {
            float nc = sigm(acc[uu].y) * c[uu] + sigm(acc[uu].x) * tanhf(acc[uu].z);
            c[uu] = nc;
            hv[uu] = sigm(acc[uu].w) * tanhf(nc);
        }
        if (t == NT - 1) {
            *(float4*)&hout[(b0 + r) * 128 + u0] = make_float4(hv[0], hv[1], hv[2], hv[3]);
        } else {
            __syncthreads();  // all waves done reading As
            *(float4*)&As[r][64 + u0] = make_float4(hv[0], hv[1], hv[2], hv[3]);
            int i = tid * 2;
            int rr = i >> 6, k = i & 63;
            float2 v = *(const float2*)&seq[((b0 + rr) * NT + (t + 1)) * 64 + k];
            As[rr][k] = fmaxf(v.x, 0.0f);
            As[rr][k + 1] = fmaxf(v.y, 0.0f);
            __syncthreads();
        }
    }
}

// ---------- FC head + softmax: one wave per row ----------
__global__ __launch_bounds__(256) void k_fc(const float* __restrict__ h,
                                            const float* __restrict__ fw1,
                                            const float* __restrict__ fb1,
                                            const float* __restrict__ fw2,
                                            const float* __restrict__ fb2,
                                            float* __restrict__ out) {
    __shared__ float hid[4][64];
    int tid = threadIdx.x;
    int lane = tid & 63;
    int w = tid >> 6;
    int b = blockIdx.x * 4 + w;
    const float* hr = h + b * 128;
    float acc = fb1[lane];
    #pragma unroll 4
    for (int k = 0; k < 128; ++k) acc = fmaf(hr[k], fw1[k * 64 + lane], acc);
    hid[w][lane] = fmaxf(acc, 0.0f);
    __syncthreads();
    if (lane == 0) {
        float lg[3];
        #pragma unroll
        for (int l = 0; l < 3; ++l) {
            float a = fb2[l];
            for (int j = 0; j < 64; ++j) a = fmaf(hid[w][j], fw2[j * 3 + l], a);
            lg[l] = a;
        }
        float m = fmaxf(lg[0], fmaxf(lg[1], lg[2]));
        float e0 = expf(lg[0] - m), e1 = expf(lg[1] - m), e2 = expf(lg[2] - m);
        float s = 1.0f / (e0 + e1 + e2);
        out[b * 3 + 0] = e0 * s;
        out[b * 3 + 1] = e1 * s;
        out[b * 3 + 2] = e2 * s;
    }
}

extern "C" void kernel_launch(void* const* d_in, const int* in_sizes, int n_in,
                              void* d_out, int out_size, void* d_ws, size_t ws_size,
                              hipStream_t stream) {
    const float* x    = (const float*)d_in[0];
    const float* ea   = (const float*)d_in[1];
    const float* W1   = (const float*)d_in[2];
    const float* b1   = (const float*)d_in[3];
    const float* W2   = (const float*)d_in[4];
    const float* b2   = (const float*)d_in[5];
    const float* W_ih = (const float*)d_in[6];
    const float* W_hh = (const float*)d_in[7];
    const float* b_ih = (const float*)d_in[8];
    const float* b_hh = (const float*)d_in[9];
    const float* fw1  = (const float*)d_in[10];
    const float* fb1  = (const float*)d_in[11];
    const float* fw2  = (const float*)d_in[12];
    const float* fb2  = (const float*)d_in[13];
    const int*   ei   = (const int*)d_in[14];
    float* out = (float*)d_out;

    float* ws    = (float*)d_ws;
    float* dinv  = ws;                    // 64,000
    float* nrm   = dinv + NN;             // 1,024,000
    float* bufA  = nrm + NE;              // 4,096,000
    float* bufB  = bufA + NN * 64;        // 4,096,000
    float* Wg    = bufB + NN * 64;        // 98,304
    float* biasg = Wg + 192 * 512;        // 512
    float* hbuf  = biasg + 512;           // 512,000

    // degree / norm (shared by both GCN layers)
    k_deg_init<<<250, 256, 0, stream>>>(dinv);
    k_deg_accum<<<4000, 256, 0, stream>>>(ei, ea, dinv);
    k_dinv<<<250, 256, 0, stream>>>(dinv);
    k_norm<<<4000, 256, 0, stream>>>(ei, ea, dinv, nrm);
    k_wprep<<<384, 256, 0, stream>>>(W_ih, W_hh, b_ih, b_hh, Wg, biasg);

    // GCN layer 1
    k_lin<16, false><<<16000, 256, 0, stream>>>(x, W1, bufA);
    k_agg_init<<<16000, 256, 0, stream>>>(bufA, dinv, b1, bufB);
    k_scatter<<<256000, 256, 0, stream>>>(ei, nrm, bufA, bufB);

    // GCN layer 2 (relu of layer-1 output fused into read)
    k_lin<64, true><<<16000, 256, 0, stream>>>(bufB, W2, bufA);
    k_agg_init<<<16000, 256, 0, stream>>>(bufA, dinv, b2, bufB);
    k_scatter<<<256000, 256, 0, stream>>>(ei, nrm, bufA, bufB);

    // LSTM (relu of layer-2 output fused into read)
    k_lstm<<<250, 512, 0, stream>>>(bufB, Wg, biasg, hbuf);

    // FC head + softmax
    k_fc<<<1000, 256, 0, stream>>>(hbuf, fw1, fb1, fw2, fb2, out);
}

// Round 3
// 865.141 us; speedup vs baseline: 2.2650x; 2.2650x over previous
//
#include <hip/hip_runtime.h>
#include <math.h>

#define NN 64000      // nodes
#define NE 1024000    // edges
#define NB 4000       // sequences
#define NT 16         // timesteps

#define ROWS 8        // sequences per LSTM block
#define AS_K 12       // floats per k-row of A-panel (8 used + pad, 48B = 16B aligned)
#define GS_STR 520    // gate buffer row stride (512 + 8 pad)

__device__ __forceinline__ float sigm(float x) { return 1.0f / (1.0f + expf(-x)); }

// ---------- degree / norm ----------
__global__ __launch_bounds__(256) void k_deg_init(float* __restrict__ deg) {
    int i = blockIdx.x * 256 + threadIdx.x;
    if (i < NN) deg[i] = 1.0f;
}

__global__ __launch_bounds__(256) void k_deg_accum(const int* __restrict__ ei,
                                                   const float* __restrict__ ew,
                                                   float* __restrict__ deg) {
    int e = blockIdx.x * 256 + threadIdx.x;
    if (e < NE) atomicAdd(&deg[ei[NE + e]], ew[e]);
}

__global__ __launch_bounds__(256) void k_dinv(float* __restrict__ deg) {
    int i = blockIdx.x * 256 + threadIdx.x;
    if (i < NN) deg[i] = rsqrtf(deg[i]);
}

__global__ __launch_bounds__(256) void k_norm(const int* __restrict__ ei,
                                              const float* __restrict__ ew,
                                              const float* __restrict__ dinv,
                                              float* __restrict__ nrm) {
    int e = blockIdx.x * 256 + threadIdx.x;
    if (e < NE) nrm[e] = dinv[ei[e]] * ew[e] * dinv[ei[NE + e]];
}

// ---------- node linear: Y[n][64] = (relu?)X[n][:K] @ W[K][64] ----------
template<int K, bool RELU_IN>
__global__ __launch_bounds__(256) void k_lin(const float* __restrict__ X,
                                             const float* __restrict__ W,
                                             float* __restrict__ Y) {
    __shared__ float Wl[K * 64];
    __shared__ float Xl[4][K];
    int tid = threadIdx.x;
    for (int i = tid; i < K * 64; i += 256) Wl[i] = W[i];
    int n0 = blockIdx.x * 4;
    for (int i = tid; i < 4 * K; i += 256) {
        int r = i / K, d = i % K;
        float v = X[(n0 + r) * K + d];
        Xl[r][d] = RELU_IN ? fmaxf(v, 0.0f) : v;
    }
    __syncthreads();
    int r = tid >> 6, f = tid & 63;
    float acc = 0.0f;
    #pragma unroll
    for (int d = 0; d < K; ++d) acc = fmaf(Xl[r][d], Wl[d * 64 + f], acc);
    Y[(n0 + r) * 64 + f] = acc;
}

// ---------- agg init: agg = lin*dinv^2 + bias ----------
__global__ __launch_bounds__(256) void k_agg_init(const float* __restrict__ lin,
                                                  const float* __restrict__ dinv,
                                                  const float* __restrict__ b,
                                                  float* __restrict__ agg) {
    int i = blockIdx.x * 256 + threadIdx.x;   // i < NN*64
    int n = i >> 6, f = i & 63;
    float di = dinv[n];
    agg[i] = lin[i] * di * di + b[f];
}

// ---------- edge scatter: agg[col] += norm * lin[row], grid-stride ----------
__global__ __launch_bounds__(256) void k_scatter(const int* __restrict__ ei,
                                                 const float* __restrict__ nrm,
                                                 const float* __restrict__ lin,
                                                 float* __restrict__ agg) {
    int tid = threadIdx.x;
    int f = tid & 63;
    int eq = tid >> 6;
    for (int e = blockIdx.x * 4 + eq; e < NE; e += gridDim.x * 4) {
        int r = ei[e];
        int c = ei[NE + e];
        float w = nrm[e];
        atomicAdd(&agg[c * 64 + f], w * lin[r * 64 + f]);
    }
}

// ---------- LSTM weight prep ----------
// Wg2[k][col], col = w*64 + l; lane l of wave w owns unit u = w*16 + (l>>2), gate g = l&3
// gate row in original layout: grow = g*128 + u
__global__ __launch_bounds__(256) void k_wprep(const float* __restrict__ W_ih,
                                               const float* __restrict__ W_hh,
                                               const float* __restrict__ b_ih,
                                               const float* __restrict__ b_hh,
                                               float* __restrict__ Wg2,
                                               float* __restrict__ biasg2) {
    int i = blockIdx.x * 256 + threadIdx.x;
    if (i < 192 * 512) {
        int k = i >> 9;
        int col = i & 511;
        int w = col >> 6, l = col & 63;
        int u = w * 16 + (l >> 2);
        int g = l & 3;
        int grow = g * 128 + u;
        Wg2[i] = (k < 64) ? W_ih[grow * 64 + k] : W_hh[grow * 128 + (k - 64)];
    }
    if (i < 512) {
        int w = i >> 6, l = i & 63;
        int u = w * 16 + (l >> 2);
        int g = l & 3;
        int grow = g * 128 + u;
        biasg2[i] = b_ih[grow] + b_hh[grow];
    }
}

// ---------- LSTM: weights register-resident; 8 rows/block, 8 waves ----------
// Wave w owns units [w*16, w*16+16); lane l: (u = w*16+(l>>2), gate g = l&3).
// wreg[192] = full k-column for this lane's (u,g). A-panel transposed in LDS:
// As[k][r], uniform broadcast reads. Gates staged via LDS gs for activation pass.
__global__ __launch_bounds__(512, 2) void k_lstm(const float* __restrict__ seq,    // pre-relu (NN x 64)
                                                 const float* __restrict__ Wg2,    // [192][512]
                                                 const float* __restrict__ biasg2, // [512]
                                                 float* __restrict__ hout) {       // [NB][128]
    __shared__ float As[192 * AS_K];
    __shared__ float gs[ROWS * GS_STR];
    int tid = threadIdx.x;
    int w = tid >> 6;
    int lane = tid & 63;
    int b0 = blockIdx.x * ROWS;

    // register-resident weights: one (u,g) column per lane
    float wreg[192];
    {
        const float* wp = Wg2 + (w * 64 + lane);
        #pragma unroll
        for (int k = 0; k < 192; ++k) wreg[k] = wp[k * 512];
    }
    float bias = biasg2[w * 64 + lane];
    int gidx = (lane & 3) * 128 + w * 16 + (lane >> 2);   // gs column for this lane

    // activation-pass assignment: r = tid&7, units u and u+64
    int ar = tid & 7;
    int au = tid >> 3;       // 0..63
    float c0 = 0.0f, c1 = 0.0f;

    // initial staging: h0 = 0, seq_0
    for (int i = tid; i < 128 * ROWS; i += 512) {
        As[(64 + (i >> 3)) * AS_K + (i & 7)] = 0.0f;
    }
    {
        int rr = tid >> 6, k = tid & 63;
        As[k * AS_K + rr] = fmaxf(seq[((b0 + rr) * NT + 0) * 64 + k], 0.0f);
    }

    #pragma unroll 1
    for (int t = 0; t < NT; ++t) {
        __syncthreads();   // As staged (h_{t-1}, seq_t); prev activation done with gs

        float acc[ROWS];
        #pragma unroll
        for (int r = 0; r < ROWS; ++r) acc[r] = bias;
        #pragma unroll
        for (int k = 0; k < 192; ++k) {
            float4 aLo = *(const float4*)&As[k * AS_K + 0];
            float4 aHi = *(const float4*)&As[k * AS_K + 4];
            float wv = wreg[k];
            acc[0] = fmaf(aLo.x, wv, acc[0]);
            acc[1] = fmaf(aLo.y, wv, acc[1]);
            acc[2] = fmaf(aLo.z, wv, acc[2]);
            acc[3] = fmaf(aLo.w, wv, acc[3]);
            acc[4] = fmaf(aHi.x, wv, acc[4]);
            acc[5] = fmaf(aHi.y, wv, acc[5]);
            acc[6] = fmaf(aHi.z, wv, acc[6]);
            acc[7] = fmaf(aHi.w, wv, acc[7]);
        }
        #pragma unroll
        for (int r = 0; r < ROWS; ++r) gs[r * GS_STR + gidx] = acc[r];

        __syncthreads();   // gates visible

        // activation: this thread owns (ar, au) and (ar, au+64)
        {
            float ig = gs[ar * GS_STR + au];
            float fg = gs[ar * GS_STR + 128 + au];
            float gg = gs[ar * GS_STR + 256 + au];
            float og = gs[ar * GS_STR + 384 + au];
            float nc = sigm(fg) * c0 + sigm(ig) * tanhf(gg);
            c0 = nc;
            float hv = sigm(og) * tanhf(nc);
            if (t == NT - 1) hout[(b0 + ar) * 128 + au] = hv;
            else             As[(64 + au) * AS_K + ar] = hv;

            int au2 = au + 64;
            ig = gs[ar * GS_STR + au2];
            fg = gs[ar * GS_STR + 128 + au2];
            gg = gs[ar * GS_STR + 256 + au2];
            og = gs[ar * GS_STR + 384 + au2];
            nc = sigm(fg) * c1 + sigm(ig) * tanhf(gg);
            c1 = nc;
            hv = sigm(og) * tanhf(nc);
            if (t == NT - 1) hout[(b0 + ar) * 128 + au2] = hv;
            else             As[(64 + au2) * AS_K + ar] = hv;
        }
        // stage next timestep's inputs
        if (t < NT - 1) {
            int rr = tid >> 6, k = tid & 63;
            As[k * AS_K + rr] = fmaxf(seq[((b0 + rr) * NT + (t + 1)) * 64 + k], 0.0f);
        }
    }
}

// ---------- FC head + softmax: one wave per row ----------
__global__ __launch_bounds__(256) void k_fc(const float* __restrict__ h,
                                            const float* __restrict__ fw1,
                                            const float* __restrict__ fb1,
                                            const float* __restrict__ fw2,
                                            const float* __restrict__ fb2,
                                            float* __restrict__ out) {
    __shared__ float hid[4][64];
    int tid = threadIdx.x;
    int lane = tid & 63;
    int w = tid >> 6;
    int b = blockIdx.x * 4 + w;
    const float* hr = h + b * 128;
    float acc = fb1[lane];
    #pragma unroll 4
    for (int k = 0; k < 128; ++k) acc = fmaf(hr[k], fw1[k * 64 + lane], acc);
    hid[w][lane] = fmaxf(acc, 0.0f);
    __syncthreads();
    if (lane == 0) {
        float lg[3];
        #pragma unroll
        for (int l = 0; l < 3; ++l) {
            float a = fb2[l];
            for (int j = 0; j < 64; ++j) a = fmaf(hid[w][j], fw2[j * 3 + l], a);
            lg[l] = a;
        }
        float m = fmaxf(lg[0], fmaxf(lg[1], lg[2]));
        float e0 = expf(lg[0] - m), e1 = expf(lg[1] - m), e2 = expf(lg[2] - m);
        float s = 1.0f / (e0 + e1 + e2);
        out[b * 3 + 0] = e0 * s;
        out[b * 3 + 1] = e1 * s;
        out[b * 3 + 2] = e2 * s;
    }
}

extern "C" void kernel_launch(void* const* d_in, const int* in_sizes, int n_in,
                              void* d_out, int out_size, void* d_ws, size_t ws_size,
                              hipStream_t stream) {
    const float* x    = (const float*)d_in[0];
    const float* ea   = (const float*)d_in[1];
    const float* W1   = (const float*)d_in[2];
    const float* b1   = (const float*)d_in[3];
    const float* W2   = (const float*)d_in[4];
    const float* b2   = (const float*)d_in[5];
    const float* W_ih = (const float*)d_in[6];
    const float* W_hh = (const float*)d_in[7];
    const float* b_ih = (const float*)d_in[8];
    const float* b_hh = (const float*)d_in[9];
    const float* fw1  = (const float*)d_in[10];
    const float* fb1  = (const float*)d_in[11];
    const float* fw2  = (const float*)d_in[12];
    const float* fb2  = (const float*)d_in[13];
    const int*   ei   = (const int*)d_in[14];
    float* out = (float*)d_out;

    float* ws    = (float*)d_ws;
    float* dinv  = ws;                    // 64,000
    float* nrm   = dinv + NN;             // 1,024,000
    float* bufA  = nrm + NE;              // 4,096,000
    float* bufB  = bufA + NN * 64;        // 4,096,000
    float* Wg2   = bufB + NN * 64;        // 98,304
    float* biasg2 = Wg2 + 192 * 512;      // 512
    float* hbuf  = biasg2 + 512;          // 512,000

    // degree / norm (shared by both GCN layers)
    k_deg_init<<<250, 256, 0, stream>>>(dinv);
    k_deg_accum<<<4000, 256, 0, stream>>>(ei, ea, dinv);
    k_dinv<<<250, 256, 0, stream>>>(dinv);
    k_norm<<<4000, 256, 0, stream>>>(ei, ea, dinv, nrm);
    k_wprep<<<384, 256, 0, stream>>>(W_ih, W_hh, b_ih, b_hh, Wg2, biasg2);

    // GCN layer 1
    k_lin<16, false><<<16000, 256, 0, stream>>>(x, W1, bufA);
    k_agg_init<<<16000, 256, 0, stream>>>(bufA, dinv, b1, bufB);
    k_scatter<<<2048, 256, 0, stream>>>(ei, nrm, bufA, bufB);

    // GCN layer 2 (relu of layer-1 output fused into read)
    k_lin<64, true><<<16000, 256, 0, stream>>>(bufB, W2, bufA);
    k_agg_init<<<16000, 256, 0, stream>>>(bufA, dinv, b2, bufB);
    k_scatter<<<2048, 256, 0, stream>>>(ei, nrm, bufA, bufB);

    // LSTM (relu of layer-2 output fused into read)
    k_lstm<<<500, 512, 0, stream>>>(bufB, Wg2, biasg2, hbuf);

    // FC head + softmax
    k_fc<<<1000, 256, 0, stream>>>(hbuf, fw1, fb1, fw2, fb2, out);
}

// Round 4
// 689.394 us; speedup vs baseline: 2.8424x; 1.2549x over previous
//
#include <hip/hip_runtime.h>
#include <hip/hip_bf16.h>
#include <math.h>

#define NN 64000      // nodes
#define NE 1024000    // edges
#define NB 4000       // sequences
#define NT 16         // timesteps
#define LROWS 32      // sequences per LSTM block
#define GS_STR 513    // gs row stride (conflict-free: bank advances by 1 per row)

typedef __attribute__((ext_vector_type(8))) short short8;
typedef __attribute__((ext_vector_type(4))) float f32x4;

__device__ __forceinline__ float sigm(float x) { return 1.0f / (1.0f + expf(-x)); }
__device__ __forceinline__ unsigned short bfbits(float v) {
    __hip_bfloat16 h = __float2bfloat16(v);
    return reinterpret_cast<unsigned short&>(h);
}
__device__ __forceinline__ float bfval(float v) {
    return __bfloat162float(__float2bfloat16(v));
}

// ---------- degree ----------
__global__ __launch_bounds__(256) void k_deg_init(float* __restrict__ deg) {
    int i = blockIdx.x * 256 + threadIdx.x;
    if (i < NN) deg[i] = 1.0f;
}
__global__ __launch_bounds__(256) void k_deg_accum(const int* __restrict__ ei,
                                                   const float* __restrict__ ew,
                                                   float* __restrict__ deg) {
    int e = blockIdx.x * 256 + threadIdx.x;
    if (e < NE) atomicAdd(&deg[ei[NE + e]], ew[e]);
}
__global__ __launch_bounds__(256) void k_dinv(float* __restrict__ deg) {
    int i = blockIdx.x * 256 + threadIdx.x;
    if (i < NN) deg[i] = rsqrtf(deg[i]);
}

// ---------- CSR build ----------
__global__ __launch_bounds__(256) void k_zeroi(int* __restrict__ p) {
    int i = blockIdx.x * 256 + threadIdx.x;
    if (i < NN) p[i] = 0;
}
__global__ __launch_bounds__(256) void k_hist(const int* __restrict__ ei, int* __restrict__ cnt) {
    int e = blockIdx.x * 256 + threadIdx.x;
    if (e < NE) atomicAdd(&cnt[ei[NE + e]], 1);
}
// one-block exclusive scan over NN bins (each thread owns 63 bins)
__global__ __launch_bounds__(1024) void k_scan(const int* __restrict__ cnt, int* __restrict__ off) {
    __shared__ int sm[1024];
    int tid = threadIdx.x;
    int base = tid * 63;
    int s = 0;
    for (int j = 0; j < 63; ++j) {
        int idx = base + j;
        if (idx < NN) s += cnt[idx];
    }
    sm[tid] = s;
    __syncthreads();
    for (int d = 1; d < 1024; d <<= 1) {
        int v = (tid >= d) ? sm[tid - d] : 0;
        __syncthreads();
        sm[tid] += v;
        __syncthreads();
    }
    int run = sm[tid] - s;   // exclusive
    for (int j = 0; j < 63; ++j) {
        int idx = base + j;
        if (idx < NN) { off[idx] = run; run += cnt[idx]; }
        else if (idx == NN) off[NN] = run;
    }
}
// place edges into CSR slots; edata = {row, norm-weight}
__global__ __launch_bounds__(256) void k_place(const int* __restrict__ ei,
                                               const float* __restrict__ ew,
                                               const float* __restrict__ dinv,
                                               const int* __restrict__ off,
                                               int* __restrict__ cur,
                                               uint2* __restrict__ edata) {
    int e = blockIdx.x * 256 + threadIdx.x;
    if (e >= NE) return;
    int r = ei[e];
    int c = ei[NE + e];
    float w = ew[e] * dinv[r] * dinv[c];
    int p = off[c] + atomicAdd(&cur[c], 1);
    edata[p] = make_uint2((unsigned)r, __float_as_uint(w));
}

// ---------- node linear: Y[n][64] = (relu?)X[n][:K] @ W[K][64] ----------
template<int K, bool RELU_IN>
__global__ __launch_bounds__(256) void k_lin(const float* __restrict__ X,
                                             const float* __restrict__ W,
                                             float* __restrict__ Y) {
    __shared__ float Wl[K * 64];
    __shared__ float Xl[4][K];
    int tid = threadIdx.x;
    for (int i = tid; i < K * 64; i += 256) Wl[i] = W[i];
    int n0 = blockIdx.x * 4;
    for (int i = tid; i < 4 * K; i += 256) {
        int r = i / K, d = i % K;
        float v = X[(n0 + r) * K + d];
        Xl[r][d] = RELU_IN ? fmaxf(v, 0.0f) : v;
    }
    __syncthreads();
    int r = tid >> 6, f = tid & 63;
    float acc = 0.0f;
    #pragma unroll
    for (int d = 0; d < K; ++d) acc = fmaf(Xl[r][d], Wl[d * 64 + f], acc);
    Y[(n0 + r) * 64 + f] = acc;
}

// ---------- CSR gather (fused agg_init): one wave per node ----------
__global__ __launch_bounds__(256) void k_gather(const float* __restrict__ lin,
                                                const uint2* __restrict__ edata,
                                                const int* __restrict__ off,
                                                const float* __restrict__ dinv,
                                                const float* __restrict__ bvec,
                                                float* __restrict__ agg) {
    int tid = threadIdx.x;
    int f = tid & 63;
    int n = blockIdx.x * 4 + (tid >> 6);
    float di = dinv[n];
    float acc = bvec[f] + lin[n * 64 + f] * di * di;
    int s = off[n], e1 = off[n + 1];
    for (int e = s; e < e1; ++e) {
        uint2 d = edata[e];
        acc = fmaf(__uint_as_float(d.y), lin[(size_t)d.x * 64 + f], acc);
    }
    agg[n * 64 + f] = acc;
}

// ---------- LSTM weight fragment prep (bf16 hi/lo, MFMA B layout) ----------
// col = g*128+u == row index of [W_ih|W_hh]; chunk ci = (ks*32+ntg)*2+hl, 1KB each:
// lane l, elem j -> col = ntg*16+(l&15), k = ks*32+(l>>4)*8+j
__global__ __launch_bounds__(256) void k_wfrag(const float* __restrict__ W_ih,
                                               const float* __restrict__ W_hh,
                                               const float* __restrict__ b_ih,
                                               const float* __restrict__ b_hh,
                                               unsigned short* __restrict__ Bus,
                                               float* __restrict__ biasb) {
    int i = blockIdx.x * 256 + threadIdx.x;
    if (i < 192 * 512 * 2) {
        int j = i & 7;
        int l = (i >> 3) & 63;
        int ci = i >> 9;
        int hl = ci & 1;
        int ntg = (ci >> 1) & 31;
        int ks = ci >> 6;
        int col = ntg * 16 + (l & 15);
        int k = ks * 32 + ((l >> 4) << 3) + j;
        float w = (k < 64) ? W_ih[col * 64 + k] : W_hh[col * 128 + (k - 64)];
        float hi = bfval(w);
        Bus[i] = bfbits(hl ? (w - hi) : w);
    }
    if (i < 512) biasb[i] = b_ih[i] + b_hh[i];
}

// ---------- LSTM: MFMA bf16x3, 32 rows/block, B streamed from L2 ----------
__global__ __launch_bounds__(512, 2) void k_lstm(const float* __restrict__ seq,
                                                 const unsigned short* __restrict__ Bus,
                                                 const float* __restrict__ biasb,
                                                 float* __restrict__ hout) {
    __shared__ unsigned short Aus[24 * 512];   // 24 chunks x 1KB (2mt x 6ks x hi/lo)
    __shared__ float gs[LROWS * GS_STR];
    int tid = threadIdx.x;
    int lane = tid & 63;
    int w = tid >> 6;
    int b0 = blockIdx.x * LROWS;

    // activation ownership: row = tid&31, units u0..u0+7
    int arow = tid & 31;
    int u0 = (tid >> 5) * 8;
    float c8[8], bi[8], bf_[8], bg[8], bo[8];
    #pragma unroll
    for (int p = 0; p < 8; ++p) {
        c8[p] = 0.0f;
        bi[p]  = biasb[u0 + p];
        bf_[p] = biasb[128 + u0 + p];
        bg[p]  = biasb[256 + u0 + p];
        bo[p]  = biasb[384 + u0 + p];
    }

    // zero A panel (h region), then stage seq t=0
    for (int i = tid; i < 24 * 256; i += 512) ((unsigned int*)Aus)[i] = 0;
    __syncthreads();
    {
        for (int i = tid; i < LROWS * 64; i += 512) {
            int row = i >> 6, k = i & 63;
            float v = fmaxf(seq[((size_t)(b0 + row) * NT + 0) * 64 + k], 0.0f);
            float hi = bfval(v);
            int mt = row >> 4, r = row & 15, ks = k >> 5, kr = k & 31;
            int idx = ((mt * 6 + ks) * 2) * 512 + (((kr >> 3) << 4) + r) * 8 + (kr & 7);
            Aus[idx] = bfbits(v);
            Aus[idx + 512] = bfbits(v - hi);
        }
    }
    __syncthreads();

    for (int t = 0; t < NT; ++t) {
        // ---- MFMA phase ----
        f32x4 a00 = {0.f, 0.f, 0.f, 0.f}, a01 = a00, a02 = a00, a03 = a00;
        f32x4 a10 = a00, a11 = a00, a12 = a00, a13 = a00;
        #pragma unroll
        for (int ks = 0; ks < 6; ++ks) {
            short8 a0h = *(const short8*)&Aus[((0 * 6 + ks) * 2 + 0) * 512 + lane * 8];
            short8 a0l = *(const short8*)&Aus[((0 * 6 + ks) * 2 + 1) * 512 + lane * 8];
            short8 a1h = *(const short8*)&Aus[((1 * 6 + ks) * 2 + 0) * 512 + lane * 8];
            short8 a1l = *(const short8*)&Aus[((1 * 6 + ks) * 2 + 1) * 512 + lane * 8];
            #pragma unroll
            for (int nt = 0; nt < 4; ++nt) {
                int ci = (ks * 32 + (w * 4 + nt)) * 2;
                short8 bh = *(const short8*)&Bus[ci * 512 + lane * 8];
                short8 bl = *(const short8*)&Bus[(ci + 1) * 512 + lane * 8];
                f32x4* p0 = (nt == 0) ? &a00 : (nt == 1) ? &a01 : (nt == 2) ? &a02 : &a03;
                f32x4* p1 = (nt == 0) ? &a10 : (nt == 1) ? &a11 : (nt == 2) ? &a12 : &a13;
                *p0 = __builtin_amdgcn_mfma_f32_16x16x32_bf16(a0h, bh, *p0, 0, 0, 0);
                *p0 = __builtin_amdgcn_mfma_f32_16x16x32_bf16(a0h, bl, *p0, 0, 0, 0);
                *p0 = __builtin_amdgcn_mfma_f32_16x16x32_bf16(a0l, bh, *p0, 0, 0, 0);
                *p1 = __builtin_amdgcn_mfma_f32_16x16x32_bf16(a1h, bh, *p1, 0, 0, 0);
                *p1 = __builtin_amdgcn_mfma_f32_16x16x32_bf16(a1h, bl, *p1, 0, 0, 0);
                *p1 = __builtin_amdgcn_mfma_f32_16x16x32_bf16(a1l, bh, *p1, 0, 0, 0);
            }
        }
        // write gates: D row=(lane>>4)*4+q (+mt*16), col=lane&15 (+nt*16+w*64)
        {
            int rb = (lane >> 4) * 4;
            int cb = w * 64 + (lane & 15);
            #pragma unroll
            for (int q = 0; q < 4; ++q) {
                gs[(rb + q) * GS_STR + cb +  0] = a00[q];
                gs[(rb + q) * GS_STR + cb + 16] = a01[q];
                gs[(rb + q) * GS_STR + cb + 32] = a02[q];
                gs[(rb + q) * GS_STR + cb + 48] = a03[q];
                gs[(16 + rb + q) * GS_STR + cb +  0] = a10[q];
                gs[(16 + rb + q) * GS_STR + cb + 16] = a11[q];
                gs[(16 + rb + q) * GS_STR + cb + 32] = a12[q];
                gs[(16 + rb + q) * GS_STR + cb + 48] = a13[q];
            }
        }
        __syncthreads();   // gates visible; A reads of t complete

        // ---- activation phase ----
        #pragma unroll
        for (int p = 0; p < 8; ++p) {
            int u = u0 + p;
            float gi = gs[arow * GS_STR + u]       + bi[p];
            float gf = gs[arow * GS_STR + 128 + u] + bf_[p];
            float gg = gs[arow * GS_STR + 256 + u] + bg[p];
            float go = gs[arow * GS_STR + 384 + u] + bo[p];
            float nc = sigm(gf) * c8[p] + sigm(gi) * tanhf(gg);
            c8[p] = nc;
            float hv = sigm(go) * tanhf(nc);
            if (t == NT - 1) {
                hout[(size_t)(b0 + arow) * 128 + u] = hv;
            } else {
                int kh = 64 + u;
                int ks = kh >> 5, kr = kh & 31;
                int mt = arow >> 4, r = arow & 15;
                float hi = bfval(hv);
                int idx = ((mt * 6 + ks) * 2) * 512 + (((kr >> 3) << 4) + r) * 8 + (kr & 7);
                Aus[idx] = bfbits(hv);
                Aus[idx + 512] = bfbits(hv - hi);
            }
        }
        // stage seq for t+1
        if (t < NT - 1) {
            for (int i = tid; i < LROWS * 64; i += 512) {
                int row = i >> 6, k = i & 63;
                float v = fmaxf(seq[((size_t)(b0 + row) * NT + (t + 1)) * 64 + k], 0.0f);
                float hi = bfval(v);
                int mt = row >> 4, r = row & 15, ks = k >> 5, kr = k & 31;
                int idx = ((mt * 6 + ks) * 2) * 512 + (((kr >> 3) << 4) + r) * 8 + (kr & 7);
                Aus[idx] = bfbits(v);
                Aus[idx + 512] = bfbits(v - hi);
            }
        }
        __syncthreads();   // A(t+1) staged; gs free for overwrite
    }
}

// ---------- FC head + softmax: one wave per row ----------
__global__ __launch_bounds__(256) void k_fc(const float* __restrict__ h,
                                            const float* __restrict__ fw1,
                                            const float* __restrict__ fb1,
                                            const float* __restrict__ fw2,
                                            const float* __restrict__ fb2,
                                            float* __restrict__ out) {
    __shared__ float hid[4][64];
    int tid = threadIdx.x;
    int lane = tid & 63;
    int w = tid >> 6;
    int b = blockIdx.x * 4 + w;
    const float* hr = h + b * 128;
    float acc = fb1[lane];
    #pragma unroll 4
    for (int k = 0; k < 128; ++k) acc = fmaf(hr[k], fw1[k * 64 + lane], acc);
    hid[w][lane] = fmaxf(acc, 0.0f);
    __syncthreads();
    if (lane == 0) {
        float lg[3];
        #pragma unroll
        for (int l = 0; l < 3; ++l) {
            float a = fb2[l];
            for (int j = 0; j < 64; ++j) a = fmaf(hid[w][j], fw2[j * 3 + l], a);
            lg[l] = a;
        }
        float m = fmaxf(lg[0], fmaxf(lg[1], lg[2]));
        float e0 = expf(lg[0] - m), e1 = expf(lg[1] - m), e2 = expf(lg[2] - m);
        float s = 1.0f / (e0 + e1 + e2);
        out[b * 3 + 0] = e0 * s;
        out[b * 3 + 1] = e1 * s;
        out[b * 3 + 2] = e2 * s;
    }
}

extern "C" void kernel_launch(void* const* d_in, const int* in_sizes, int n_in,
                              void* d_out, int out_size, void* d_ws, size_t ws_size,
                              hipStream_t stream) {
    const float* x    = (const float*)d_in[0];
    const float* ea   = (const float*)d_in[1];
    const float* W1   = (const float*)d_in[2];
    const float* b1   = (const float*)d_in[3];
    const float* W2   = (const float*)d_in[4];
    const float* b2   = (const float*)d_in[5];
    const float* W_ih = (const float*)d_in[6];
    const float* W_hh = (const float*)d_in[7];
    const float* b_ih = (const float*)d_in[8];
    const float* b_hh = (const float*)d_in[9];
    const float* fw1  = (const float*)d_in[10];
    const float* fb1  = (const float*)d_in[11];
    const float* fw2  = (const float*)d_in[12];
    const float* fb2  = (const float*)d_in[13];
    const int*   ei   = (const int*)d_in[14];
    float* out = (float*)d_out;

    float* ws    = (float*)d_ws;
    float* dinv  = ws;                          // NN
    float* bufA  = dinv + NN;                   // NN*64
    float* bufB  = bufA + NN * 64;              // NN*64
    unsigned short* Bus = (unsigned short*)(bufB + NN * 64);   // 196608 ushort = 98304 fl
    float* biasb = bufB + NN * 64 + 98304;      // 512
    float* hbuf  = biasb + 512;                 // NB*128
    int*   cnt   = (int*)(hbuf + NB * 128);     // NN (also reused as cur)
    int*   off   = cnt + NN;                    // NN+1
    int*   cur   = off + NN + 1;                // NN
    uint2* edata = (uint2*)(cur + NN);          // NE * 8B

    // degree -> dinv
    k_deg_init<<<250, 256, 0, stream>>>(dinv);
    k_deg_accum<<<4000, 256, 0, stream>>>(ei, ea, dinv);
    k_dinv<<<250, 256, 0, stream>>>(dinv);

    // CSR build (sorted by destination col)
    k_zeroi<<<250, 256, 0, stream>>>(cnt);
    k_hist<<<4000, 256, 0, stream>>>(ei, cnt);
    k_scan<<<1, 1024, 0, stream>>>(cnt, off);
    k_zeroi<<<250, 256, 0, stream>>>(cur);
    k_place<<<4000, 256, 0, stream>>>(ei, ea, dinv, off, cur, edata);

    // LSTM weight fragments
    k_wfrag<<<768, 256, 0, stream>>>(W_ih, W_hh, b_ih, b_hh, Bus, biasb);

    // GCN layer 1
    k_lin<16, false><<<16000, 256, 0, stream>>>(x, W1, bufA);
    k_gather<<<16000, 256, 0, stream>>>(bufA, edata, off, dinv, b1, bufB);

    // GCN layer 2 (relu fused into k_lin read)
    k_lin<64, true><<<16000, 256, 0, stream>>>(bufB, W2, bufA);
    k_gather<<<16000, 256, 0, stream>>>(bufA, edata, off, dinv, b2, bufB);

    // LSTM (relu fused into staging)
    k_lstm<<<125, 512, 0, stream>>>(bufB, Bus, biasb, hbuf);

    // FC head + softmax
    k_fc<<<1000, 256, 0, stream>>>(hbuf, fw1, fb1, fw2, fb2, out);
}

// Round 5
// 531.609 us; speedup vs baseline: 3.6860x; 1.2968x over previous
//
#include <hip/hip_runtime.h>
#include <hip/hip_bf16.h>
#include <math.h>

#define NN 64000      // nodes
#define NE 1024000    // edges
#define NB 4000       // sequences
#define NT 16         // timesteps
#define LROWS 16      // sequences per LSTM block

typedef __attribute__((ext_vector_type(8))) short short8;
typedef __attribute__((ext_vector_type(4))) float f32x4;

__device__ __forceinline__ float sigm(float x) { return 1.0f / (1.0f + expf(-x)); }
__device__ __forceinline__ unsigned short bfbits(float v) {
    __hip_bfloat16 h = __float2bfloat16(v);
    return reinterpret_cast<unsigned short&>(h);
}
__device__ __forceinline__ float bfval(float v) {
    return __bfloat162float(__float2bfloat16(v));
}

// ---------- init: deg=1, cnt=0, cur=0 ----------
__global__ __launch_bounds__(256) void k_init(float* __restrict__ deg,
                                              int* __restrict__ cnt,
                                              int* __restrict__ cur) {
    int i = blockIdx.x * 256 + threadIdx.x;
    if (i < NN) { deg[i] = 1.0f; cnt[i] = 0; cur[i] = 0; }
}

// ---------- fused degree-accum + histogram ----------
__global__ __launch_bounds__(256) void k_degcnt(const int* __restrict__ ei,
                                                const float* __restrict__ ew,
                                                float* __restrict__ deg,
                                                int* __restrict__ cnt) {
    int e = blockIdx.x * 256 + threadIdx.x;
    if (e < NE) {
        int c = ei[NE + e];
        atomicAdd(&deg[c], ew[e]);
        atomicAdd(&cnt[c], 1);
    }
}

__global__ __launch_bounds__(256) void k_dinv(float* __restrict__ deg) {
    int i = blockIdx.x * 256 + threadIdx.x;
    if (i < NN) deg[i] = rsqrtf(deg[i]);
}

// one-block exclusive scan over NN bins (each thread owns 63 bins)
__global__ __launch_bounds__(1024) void k_scan(const int* __restrict__ cnt, int* __restrict__ off) {
    __shared__ int sm[1024];
    int tid = threadIdx.x;
    int base = tid * 63;
    int s = 0;
    for (int j = 0; j < 63; ++j) {
        int idx = base + j;
        if (idx < NN) s += cnt[idx];
    }
    sm[tid] = s;
    __syncthreads();
    for (int d = 1; d < 1024; d <<= 1) {
        int v = (tid >= d) ? sm[tid - d] : 0;
        __syncthreads();
        sm[tid] += v;
        __syncthreads();
    }
    int run = sm[tid] - s;   // exclusive
    for (int j = 0; j < 63; ++j) {
        int idx = base + j;
        if (idx < NN) { off[idx] = run; run += cnt[idx]; }
        else if (idx == NN) off[NN] = run;
    }
}

// place edges into CSR slots; edata = {row, norm-weight}
__global__ __launch_bounds__(256) void k_place(const int* __restrict__ ei,
                                               const float* __restrict__ ew,
                                               const float* __restrict__ dinv,
                                               const int* __restrict__ off,
                                               int* __restrict__ cur,
                                               uint2* __restrict__ edata) {
    int e = blockIdx.x * 256 + threadIdx.x;
    if (e >= NE) return;
    int r = ei[e];
    int c = ei[NE + e];
    float w = ew[e] * dinv[r] * dinv[c];
    int p = off[c] + atomicAdd(&cur[c], 1);
    edata[p] = make_uint2((unsigned)r, __float_as_uint(w));
}

// ---------- node linear: Y[n][64] = (relu?)X[n][:K] @ W[K][64] ----------
template<int K, bool RELU_IN>
__global__ __launch_bounds__(256) void k_lin(const float* __restrict__ X,
                                             const float* __restrict__ W,
                                             float* __restrict__ Y) {
    __shared__ float Wl[K * 64];
    __shared__ float Xl[4][K];
    int tid = threadIdx.x;
    for (int i = tid; i < K * 64; i += 256) Wl[i] = W[i];
    int n0 = blockIdx.x * 4;
    for (int i = tid; i < 4 * K; i += 256) {
        int r = i / K, d = i % K;
        float v = X[(n0 + r) * K + d];
        Xl[r][d] = RELU_IN ? fmaxf(v, 0.0f) : v;
    }
    __syncthreads();
    int r = tid >> 6, f = tid & 63;
    float acc = 0.0f;
    #pragma unroll
    for (int d = 0; d < K; ++d) acc = fmaf(Xl[r][d], Wl[d * 64 + f], acc);
    Y[(n0 + r) * 64 + f] = acc;
}

// ---------- CSR gather (fused agg_init): one wave per node ----------
__global__ __launch_bounds__(256) void k_gather(const float* __restrict__ lin,
                                                const uint2* __restrict__ edata,
                                                const int* __restrict__ off,
                                                const float* __restrict__ dinv,
                                                const float* __restrict__ bvec,
                                                float* __restrict__ agg) {
    int tid = threadIdx.x;
    int f = tid & 63;
    int n = blockIdx.x * 4 + (tid >> 6);
    float di = dinv[n];
    float acc = bvec[f] + lin[n * 64 + f] * di * di;
    int s = off[n], e1 = off[n + 1];
    int e = s;
    for (; e + 1 < e1; e += 2) {
        uint2 d0 = edata[e];
        uint2 d1 = edata[e + 1];
        float l0 = lin[(size_t)d0.x * 64 + f];
        float l1 = lin[(size_t)d1.x * 64 + f];
        acc = fmaf(__uint_as_float(d0.y), l0, acc);
        acc = fmaf(__uint_as_float(d1.y), l1, acc);
    }
    if (e < e1) {
        uint2 d0 = edata[e];
        acc = fmaf(__uint_as_float(d0.y), lin[(size_t)d0.x * 64 + f], acc);
    }
    agg[n * 64 + f] = acc;
}

// ---------- LSTM weight fragment prep (bf16 hi/lo, MFMA B layout) ----------
// chunk ci = (ks*32+ntg)*2+hl, 1KB each: lane l, elem j -> col = ntg*16+(l&15),
// k = ks*32+(l>>4)*8+j; col = gate-row index g*128+u
__global__ __launch_bounds__(256) void k_wfrag(const float* __restrict__ W_ih,
                                               const float* __restrict__ W_hh,
                                               const float* __restrict__ b_ih,
                                               const float* __restrict__ b_hh,
                                               unsigned short* __restrict__ Bus,
                                               float* __restrict__ biasb) {
    int i = blockIdx.x * 256 + threadIdx.x;
    if (i < 192 * 512 * 2) {
        int j = i & 7;
        int l = (i >> 3) & 63;
        int ci = i >> 9;
        int hl = ci & 1;
        int ntg = (ci >> 1) & 31;
        int ks = ci >> 6;
        int col = ntg * 16 + (l & 15);
        int k = ks * 32 + ((l >> 4) << 3) + j;
        float w = (k < 64) ? W_ih[col * 64 + k] : W_hh[col * 128 + (k - 64)];
        float hi = bfval(w);
        Bus[i] = bfbits(hl ? (w - hi) : w);
    }
    if (i < 512) biasb[i] = b_ih[i] + b_hh[i];
}

// ---------- LSTM: MFMA bf16x3, 16 rows/block, gate-quad wave split ----------
// Wave w owns units u = w*16 + (lane&15) across ALL four gates
// (B chunks ntg = 8*g + w). Thread holds (i,f,g,o) for rows rbase..rbase+3
// at unit u -> activation fully in-register, c in 4 VGPRs. No gate LDS buffer.
__global__ __launch_bounds__(512, 2) void k_lstm(const float* __restrict__ seq,
                                                 const unsigned short* __restrict__ Bus,
                                                 const float* __restrict__ biasb,
                                                 float* __restrict__ hout) {
    __shared__ unsigned short Aus[12 * 512];   // 6 ks x hi/lo x 1KB
    int tid = threadIdx.x;
    int lane = tid & 63;
    int w = tid >> 6;
    int b0 = blockIdx.x * LROWS;

    int u = w * 16 + (lane & 15);
    int rbase = (lane >> 4) * 4;
    float bI = biasb[u], bF = biasb[128 + u], bG = biasb[256 + u], bO = biasb[384 + u];
    float cst[4] = {0.0f, 0.0f, 0.0f, 0.0f};

    // zero h region (chunks 4..11), stage seq t=0 (chunks 0..3)
    for (int i = tid; i < 2048; i += 512) ((unsigned int*)Aus)[2 * 512 + i] = 0;
    {
        int i0 = tid * 2;                 // 0..1022, two consecutive k same row
        int row = i0 >> 6, k0 = i0 & 63;
        float2 v = *(const float2*)&seq[((size_t)(b0 + row) * NT + 0) * 64 + k0];
        float v0 = fmaxf(v.x, 0.0f), v1 = fmaxf(v.y, 0.0f);
        int ks = k0 >> 5, kr = k0 & 31;
        int idx = (ks * 2) * 512 + (((kr >> 3) << 4) + row) * 8 + (kr & 7);
        Aus[idx] = bfbits(v0);
        Aus[idx + 512] = bfbits(v0 - bfval(v0));
        kr = (k0 + 1) & 31; ks = (k0 + 1) >> 5;
        idx = (ks * 2) * 512 + (((kr >> 3) << 4) + row) * 8 + (kr & 7);
        Aus[idx] = bfbits(v1);
        Aus[idx + 512] = bfbits(v1 - bfval(v1));
    }
    __syncthreads();

    for (int t = 0; t < NT; ++t) {
        // ---- MFMA phase: 4 accumulators = gates i,f,g,o for cols u ----
        f32x4 acc[4];
        #pragma unroll
        for (int g = 0; g < 4; ++g) acc[g] = (f32x4){0.f, 0.f, 0.f, 0.f};
        #pragma unroll
        for (int ks = 0; ks < 6; ++ks) {
            short8 ah = *(const short8*)&Aus[(ks * 2 + 0) * 512 + lane * 8];
            short8 al = *(const short8*)&Aus[(ks * 2 + 1) * 512 + lane * 8];
            short8 bh[4], bl[4];
            #pragma unroll
            for (int g = 0; g < 4; ++g) {
                size_t ci = (size_t)(ks * 32 + 8 * g + w) * 2;
                bh[g] = *(const short8*)&Bus[ci * 512 + lane * 8];
                bl[g] = *(const short8*)&Bus[(ci + 1) * 512 + lane * 8];
            }
            #pragma unroll
            for (int g = 0; g < 4; ++g)
                acc[g] = __builtin_amdgcn_mfma_f32_16x16x32_bf16(ah, bh[g], acc[g], 0, 0, 0);
            #pragma unroll
            for (int g = 0; g < 4; ++g)
                acc[g] = __builtin_amdgcn_mfma_f32_16x16x32_bf16(ah, bl[g], acc[g], 0, 0, 0);
            #pragma unroll
            for (int g = 0; g < 4; ++g)
                acc[g] = __builtin_amdgcn_mfma_f32_16x16x32_bf16(al, bh[g], acc[g], 0, 0, 0);
        }
        __syncthreads();   // all A reads of t complete

        // ---- in-register activation; h -> Aus (or hout at last t) ----
        if (t == NT - 1) {
            #pragma unroll
            for (int q = 0; q < 4; ++q) {
                float nc = sigm(acc[1][q] + bF) * cst[q]
                         + sigm(acc[0][q] + bI) * tanhf(acc[2][q] + bG);
                cst[q] = nc;
                float hv = sigm(acc[3][q] + bO) * tanhf(nc);
                hout[(size_t)(b0 + rbase + q) * 128 + u] = hv;
            }
        } else {
            int kh = 64 + u;
            int ksh = kh >> 5, krh = kh & 31;
            int hbase = (ksh * 2) * 512 + ((krh >> 3) << 4) * 8 + (krh & 7);
            #pragma unroll
            for (int q = 0; q < 4; ++q) {
                float nc = sigm(acc[1][q] + bF) * cst[q]
                         + sigm(acc[0][q] + bI) * tanhf(acc[2][q] + bG);
                cst[q] = nc;
                float hv = sigm(acc[3][q] + bO) * tanhf(nc);
                int idx = hbase + (rbase + q) * 8;
                Aus[idx] = bfbits(hv);
                Aus[idx + 512] = bfbits(hv - bfval(hv));
            }
            // stage seq for t+1
            {
                int i0 = tid * 2;
                int row = i0 >> 6, k0 = i0 & 63;
                float2 v = *(const float2*)&seq[((size_t)(b0 + row) * NT + (t + 1)) * 64 + k0];
                float v0 = fmaxf(v.x, 0.0f), v1 = fmaxf(v.y, 0.0f);
                int ks = k0 >> 5, kr = k0 & 31;
                int idx = (ks * 2) * 512 + (((kr >> 3) << 4) + row) * 8 + (kr & 7);
                Aus[idx] = bfbits(v0);
                Aus[idx + 512] = bfbits(v0 - bfval(v0));
                kr = (k0 + 1) & 31; ks = (k0 + 1) >> 5;
                idx = (ks * 2) * 512 + (((kr >> 3) << 4) + row) * 8 + (kr & 7);
                Aus[idx] = bfbits(v1);
                Aus[idx + 512] = bfbits(v1 - bfval(v1));
            }
            __syncthreads();   // A(t+1) fully staged
        }
    }
}

// ---------- FC head + softmax: one wave per row ----------
__global__ __launch_bounds__(256) void k_fc(const float* __restrict__ h,
                                            const float* __restrict__ fw1,
                                            const float* __restrict__ fb1,
                                            const float* __restrict__ fw2,
                                            const float* __restrict__ fb2,
                                            float* __restrict__ out) {
    __shared__ float hid[4][64];
    int tid = threadIdx.x;
    int lane = tid & 63;
    int w = tid >> 6;
    int b = blockIdx.x * 4 + w;
    const float* hr = h + b * 128;
    float acc = fb1[lane];
    #pragma unroll 4
    for (int k = 0; k < 128; ++k) acc = fmaf(hr[k], fw1[k * 64 + lane], acc);
    hid[w][lane] = fmaxf(acc, 0.0f);
    __syncthreads();
    if (lane == 0) {
        float lg[3];
        #pragma unroll
        for (int l = 0; l < 3; ++l) {
            float a = fb2[l];
            for (int j = 0; j < 64; ++j) a = fmaf(hid[w][j], fw2[j * 3 + l], a);
            lg[l] = a;
        }
        float m = fmaxf(lg[0], fmaxf(lg[1], lg[2]));
        float e0 = expf(lg[0] - m), e1 = expf(lg[1] - m), e2 = expf(lg[2] - m);
        float s = 1.0f / (e0 + e1 + e2);
        out[b * 3 + 0] = e0 * s;
        out[b * 3 + 1] = e1 * s;
        out[b * 3 + 2] = e2 * s;
    }
}

extern "C" void kernel_launch(void* const* d_in, const int* in_sizes, int n_in,
                              void* d_out, int out_size, void* d_ws, size_t ws_size,
                              hipStream_t stream) {
    const float* x    = (const float*)d_in[0];
    const float* ea   = (const float*)d_in[1];
    const float* W1   = (const float*)d_in[2];
    const float* b1   = (const float*)d_in[3];
    const float* W2   = (const float*)d_in[4];
    const float* b2   = (const float*)d_in[5];
    const float* W_ih = (const float*)d_in[6];
    const float* W_hh = (const float*)d_in[7];
    const float* b_ih = (const float*)d_in[8];
    const float* b_hh = (const float*)d_in[9];
    const float* fw1  = (const float*)d_in[10];
    const float* fb1  = (const float*)d_in[11];
    const float* fw2  = (const float*)d_in[12];
    const float* fb2  = (const float*)d_in[13];
    const int*   ei   = (const int*)d_in[14];
    float* out = (float*)d_out;

    float* ws    = (float*)d_ws;
    float* dinv  = ws;                          // NN
    float* bufA  = dinv + NN;                   // NN*64
    float* bufB  = bufA + NN * 64;              // NN*64
    unsigned short* Bus = (unsigned short*)(bufB + NN * 64);   // 196608 ushort
    float* biasb = bufB + NN * 64 + 98304;      // 512
    float* hbuf  = biasb + 512;                 // NB*128
    int*   cnt   = (int*)(hbuf + NB * 128);     // NN
    int*   off   = cnt + NN;                    // NN+1
    int*   cur   = off + NN + 1;                // NN
    uint2* edata = (uint2*)(cur + NN);          // NE * 8B

    // degree + histogram (fused), dinv
    k_init<<<250, 256, 0, stream>>>(dinv, cnt, cur);
    k_degcnt<<<4000, 256, 0, stream>>>(ei, ea, dinv, cnt);
    k_dinv<<<250, 256, 0, stream>>>(dinv);

    // CSR build (sorted by destination col)
    k_scan<<<1, 1024, 0, stream>>>(cnt, off);
    k_place<<<4000, 256, 0, stream>>>(ei, ea, dinv, off, cur, edata);

    // LSTM weight fragments
    k_wfrag<<<768, 256, 0, stream>>>(W_ih, W_hh, b_ih, b_hh, Bus, biasb);

    // GCN layer 1
    k_lin<16, false><<<16000, 256, 0, stream>>>(x, W1, bufA);
    k_gather<<<16000, 256, 0, stream>>>(bufA, edata, off, dinv, b1, bufB);

    // GCN layer 2 (relu fused into k_lin read)
    k_lin<64, true><<<16000, 256, 0, stream>>>(bufB, W2, bufA);
    k_gather<<<16000, 256, 0, stream>>>(bufA, edata, off, dinv, b2, bufB);

    // LSTM (relu fused into staging)
    k_lstm<<<250, 512, 0, stream>>>(bufB, Bus, biasb, hbuf);

    // FC head + softmax
    k_fc<<<1000, 256, 0, stream>>>(hbuf, fw1, fb1, fw2, fb2, out);
}

// Round 6
// 421.602 us; speedup vs baseline: 4.6478x; 1.2609x over previous
//
#include <hip/hip_runtime.h>
#include <hip/hip_bf16.h>
#include <math.h>

#define NN 64000      // nodes
#define NE 1024000    // edges
#define NB 4000       // sequences
#define NT 16         // timesteps
#define LROWS 16      // sequences per LSTM block

typedef __attribute__((ext_vector_type(8))) short short8;
typedef __attribute__((ext_vector_type(4))) float f32x4;

__device__ __forceinline__ float sigm(float x) { return 1.0f / (1.0f + expf(-x)); }
__device__ __forceinline__ unsigned short bfbits(float v) {
    __hip_bfloat16 h = __float2bfloat16(v);
    return reinterpret_cast<unsigned short&>(h);
}
__device__ __forceinline__ float bfval(float v) {
    return __bfloat162float(__float2bfloat16(v));
}

// ---------- init: deg=1, cnt=0, cur=0 ----------
__global__ __launch_bounds__(256) void k_init(float* __restrict__ deg,
                                              int* __restrict__ cnt,
                                              int* __restrict__ cur) {
    int i = blockIdx.x * 256 + threadIdx.x;
    if (i < NN) { deg[i] = 1.0f; cnt[i] = 0; cur[i] = 0; }
}

// ---------- fused degree-accum + histogram ----------
__global__ __launch_bounds__(256) void k_degcnt(const int* __restrict__ ei,
                                                const float* __restrict__ ew,
                                                float* __restrict__ deg,
                                                int* __restrict__ cnt) {
    int e = blockIdx.x * 256 + threadIdx.x;
    if (e < NE) {
        int c = ei[NE + e];
        atomicAdd(&deg[c], ew[e]);
        atomicAdd(&cnt[c], 1);
    }
}

__global__ __launch_bounds__(256) void k_dinv(float* __restrict__ deg) {
    int i = blockIdx.x * 256 + threadIdx.x;
    if (i < NN) deg[i] = rsqrtf(deg[i]);
}

// ---------- 3-phase multi-block exclusive scan over NN bins ----------
// A: per-block scan of 256 bins -> local-exclusive off + block total
__global__ __launch_bounds__(256) void k_scanA(const int* __restrict__ cnt,
                                               int* __restrict__ off,
                                               int* __restrict__ part) {
    __shared__ int sm[256];
    int tid = threadIdx.x;
    int i = blockIdx.x * 256 + tid;
    int v = cnt[i];
    sm[tid] = v;
    __syncthreads();
    #pragma unroll
    for (int d = 1; d < 256; d <<= 1) {
        int t = (tid >= d) ? sm[tid - d] : 0;
        __syncthreads();
        sm[tid] += t;
        __syncthreads();
    }
    off[i] = sm[tid] - v;              // block-local exclusive
    if (tid == 255) part[blockIdx.x] = sm[255];
}
// B: exclusive-scan the 250 block totals; write grand total to off[NN]
__global__ __launch_bounds__(256) void k_scanB(int* __restrict__ part,
                                               int* __restrict__ off) {
    __shared__ int sm[256];
    int tid = threadIdx.x;
    int v = (tid < 250) ? part[tid] : 0;
    sm[tid] = v;
    __syncthreads();
    #pragma unroll
    for (int d = 1; d < 256; d <<= 1) {
        int t = (tid >= d) ? sm[tid - d] : 0;
        __syncthreads();
        sm[tid] += t;
        __syncthreads();
    }
    if (tid < 250) part[tid] = sm[tid] - v;   // exclusive
    if (tid == 255) off[NN] = sm[255];        // grand total (= NE)
}
// C: add block offsets back
__global__ __launch_bounds__(256) void k_scanC(const int* __restrict__ part,
                                               int* __restrict__ off) {
    int i = blockIdx.x * 256 + threadIdx.x;
    off[i] += part[blockIdx.x];
}

// place edges into CSR slots; edata = {row, norm-weight}
__global__ __launch_bounds__(256) void k_place(const int* __restrict__ ei,
                                               const float* __restrict__ ew,
                                               const float* __restrict__ dinv,
                                               const int* __restrict__ off,
                                               int* __restrict__ cur,
                                               uint2* __restrict__ edata) {
    int e = blockIdx.x * 256 + threadIdx.x;
    if (e >= NE) return;
    int r = ei[e];
    int c = ei[NE + e];
    float w = ew[e] * dinv[r] * dinv[c];
    int p = off[c] + atomicAdd(&cur[c], 1);
    edata[p] = make_uint2((unsigned)r, __float_as_uint(w));
}

// ---------- node linear: Y[n][64] = (relu?)X[n][:K] @ W[K][64] ----------
template<int K, bool RELU_IN>
__global__ __launch_bounds__(256) void k_lin(const float* __restrict__ X,
                                             const float* __restrict__ W,
                                             float* __restrict__ Y) {
    __shared__ float Wl[K * 64];
    __shared__ float Xl[4][K];
    int tid = threadIdx.x;
    for (int i = tid; i < K * 64; i += 256) Wl[i] = W[i];
    int n0 = blockIdx.x * 4;
    for (int i = tid; i < 4 * K; i += 256) {
        int r = i / K, d = i % K;
        float v = X[(n0 + r) * K + d];
        Xl[r][d] = RELU_IN ? fmaxf(v, 0.0f) : v;
    }
    __syncthreads();
    int r = tid >> 6, f = tid & 63;
    float acc = 0.0f;
    #pragma unroll
    for (int d = 0; d < K; ++d) acc = fmaf(Xl[r][d], Wl[d * 64 + f], acc);
    Y[(n0 + r) * 64 + f] = acc;
}

// ---------- CSR gather (fused agg_init): one wave per node ----------
__global__ __launch_bounds__(256) void k_gather(const float* __restrict__ lin,
                                                const uint2* __restrict__ edata,
                                                const int* __restrict__ off,
                                                const float* __restrict__ dinv,
                                                const float* __restrict__ bvec,
                                                float* __restrict__ agg) {
    int tid = threadIdx.x;
    int f = tid & 63;
    int n = blockIdx.x * 4 + (tid >> 6);
    float di = dinv[n];
    float acc = bvec[f] + lin[n * 64 + f] * di * di;
    int s = off[n], e1 = off[n + 1];
    int e = s;
    for (; e + 1 < e1; e += 2) {
        uint2 d0 = edata[e];
        uint2 d1 = edata[e + 1];
        float l0 = lin[(size_t)d0.x * 64 + f];
        float l1 = lin[(size_t)d1.x * 64 + f];
        acc = fmaf(__uint_as_float(d0.y), l0, acc);
        acc = fmaf(__uint_as_float(d1.y), l1, acc);
    }
    if (e < e1) {
        uint2 d0 = edata[e];
        acc = fmaf(__uint_as_float(d0.y), lin[(size_t)d0.x * 64 + f], acc);
    }
    agg[n * 64 + f] = acc;
}

// ---------- LSTM weight fragment prep (bf16 hi/lo, MFMA B layout) ----------
// chunk ci = (ks*32+ntg)*2+hl, 1KB each: lane l, elem j -> col = ntg*16+(l&15),
// k = ks*32+(l>>4)*8+j; col = gate-row index g*128+u
__global__ __launch_bounds__(256) void k_wfrag(const float* __restrict__ W_ih,
                                               const float* __restrict__ W_hh,
                                               const float* __restrict__ b_ih,
                                               const float* __restrict__ b_hh,
                                               unsigned short* __restrict__ Bus,
                                               float* __restrict__ biasb) {
    int i = blockIdx.x * 256 + threadIdx.x;
    if (i < 192 * 512 * 2) {
        int j = i & 7;
        int l = (i >> 3) & 63;
        int ci = i >> 9;
        int hl = ci & 1;
        int ntg = (ci >> 1) & 31;
        int ks = ci >> 6;
        int col = ntg * 16 + (l & 15);
        int k = ks * 32 + ((l >> 4) << 3) + j;
        float w = (k < 64) ? W_ih[col * 64 + k] : W_hh[col * 128 + (k - 64)];
        float hi = bfval(w);
        Bus[i] = bfbits(hl ? (w - hi) : w);
    }
    if (i < 512) biasb[i] = b_ih[i] + b_hh[i];
}

// ---------- LSTM: MFMA bf16x3, 16 rows/block, gate-quad wave split ----------
// Wave w owns units u = w*16 + (lane&15) across ALL four gates
// (B chunks ntg = 8*g + w). Thread holds (i,f,g,o) for rows rbase..rbase+3
// at unit u -> activation fully in-register, c in 4 VGPRs. No gate LDS buffer.
__global__ __launch_bounds__(512, 2) void k_lstm(const float* __restrict__ seq,
                                                 const unsigned short* __restrict__ Bus,
                                                 const float* __restrict__ biasb,
                                                 float* __restrict__ hout) {
    __shared__ unsigned short Aus[12 * 512];   // 6 ks x hi/lo x 1KB
    int tid = threadIdx.x;
    int lane = tid & 63;
    int w = tid >> 6;
    int b0 = blockIdx.x * LROWS;

    int u = w * 16 + (lane & 15);
    int rbase = (lane >> 4) * 4;
    float bI = biasb[u], bF = biasb[128 + u], bG = biasb[256 + u], bO = biasb[384 + u];
    float cst[4] = {0.0f, 0.0f, 0.0f, 0.0f};

    // zero h region (chunks 4..11), stage seq t=0 (chunks 0..3)
    for (int i = tid; i < 2048; i += 512) ((unsigned int*)Aus)[2 * 512 + i] = 0;
    {
        int i0 = tid * 2;                 // 0..1022, two consecutive k same row
        int row = i0 >> 6, k0 = i0 & 63;
        float2 v = *(const float2*)&seq[((size_t)(b0 + row) * NT + 0) * 64 + k0];
        float v0 = fmaxf(v.x, 0.0f), v1 = fmaxf(v.y, 0.0f);
        int ks = k0 >> 5, kr = k0 & 31;
        int idx = (ks * 2) * 512 + (((kr >> 3) << 4) + row) * 8 + (kr & 7);
        Aus[idx] = bfbits(v0);
        Aus[idx + 512] = bfbits(v0 - bfval(v0));
        kr = (k0 + 1) & 31; ks = (k0 + 1) >> 5;
        idx = (ks * 2) * 512 + (((kr >> 3) << 4) + row) * 8 + (kr & 7);
        Aus[idx] = bfbits(v1);
        Aus[idx + 512] = bfbits(v1 - bfval(v1));
    }
    __syncthreads();

    for (int t = 0; t < NT; ++t) {
        // ---- MFMA phase: 4 accumulators = gates i,f,g,o for cols u ----
        f32x4 acc[4];
        #pragma unroll
        for (int g = 0; g < 4; ++g) acc[g] = (f32x4){0.f, 0.f, 0.f, 0.f};
        #pragma unroll
        for (int ks = 0; ks < 6; ++ks) {
            short8 ah = *(const short8*)&Aus[(ks * 2 + 0) * 512 + lane * 8];
            short8 al = *(const short8*)&Aus[(ks * 2 + 1) * 512 + lane * 8];
            short8 bh[4], bl[4];
            #pragma unroll
            for (int g = 0; g < 4; ++g) {
                size_t ci = (size_t)(ks * 32 + 8 * g + w) * 2;
                bh[g] = *(const short8*)&Bus[ci * 512 + lane * 8];
                bl[g] = *(const short8*)&Bus[(ci + 1) * 512 + lane * 8];
            }
            #pragma unroll
            for (int g = 0; g < 4; ++g)
                acc[g] = __builtin_amdgcn_mfma_f32_16x16x32_bf16(ah, bh[g], acc[g], 0, 0, 0);
            #pragma unroll
            for (int g = 0; g < 4; ++g)
                acc[g] = __builtin_amdgcn_mfma_f32_16x16x32_bf16(ah, bl[g], acc[g], 0, 0, 0);
            #pragma unroll
            for (int g = 0; g < 4; ++g)
                acc[g] = __builtin_amdgcn_mfma_f32_16x16x32_bf16(al, bh[g], acc[g], 0, 0, 0);
        }
        __syncthreads();   // all A reads of t complete

        // ---- in-register activation; h -> Aus (or hout at last t) ----
        if (t == NT - 1) {
            #pragma unroll
            for (int q = 0; q < 4; ++q) {
                float nc = sigm(acc[1][q] + bF) * cst[q]
                         + sigm(acc[0][q] + bI) * tanhf(acc[2][q] + bG);
                cst[q] = nc;
                float hv = sigm(acc[3][q] + bO) * tanhf(nc);
                hout[(size_t)(b0 + rbase + q) * 128 + u] = hv;
            }
        } else {
            int kh = 64 + u;
            int ksh = kh >> 5, krh = kh & 31;
            int hbase = (ksh * 2) * 512 + ((krh >> 3) << 4) * 8 + (krh & 7);
            #pragma unroll
            for (int q = 0; q < 4; ++q) {
                float nc = sigm(acc[1][q] + bF) * cst[q]
                         + sigm(acc[0][q] + bI) * tanhf(acc[2][q] + bG);
                cst[q] = nc;
                float hv = sigm(acc[3][q] + bO) * tanhf(nc);
                int idx = hbase + (rbase + q) * 8;
                Aus[idx] = bfbits(hv);
                Aus[idx + 512] = bfbits(hv - bfval(hv));
            }
            // stage seq for t+1
            {
                int i0 = tid * 2;
                int row = i0 >> 6, k0 = i0 & 63;
                float2 v = *(const float2*)&seq[((size_t)(b0 + row) * NT + (t + 1)) * 64 + k0];
                float v0 = fmaxf(v.x, 0.0f), v1 = fmaxf(v.y, 0.0f);
                int ks = k0 >> 5, kr = k0 & 31;
                int idx = (ks * 2) * 512 + (((kr >> 3) << 4) + row) * 8 + (kr & 7);
                Aus[idx] = bfbits(v0);
                Aus[idx + 512] = bfbits(v0 - bfval(v0));
                kr = (k0 + 1) & 31; ks = (k0 + 1) >> 5;
                idx = (ks * 2) * 512 + (((kr >> 3) << 4) + row) * 8 + (kr & 7);
                Aus[idx] = bfbits(v1);
                Aus[idx + 512] = bfbits(v1 - bfval(v1));
            }
            __syncthreads();   // A(t+1) fully staged
        }
    }
}

// ---------- FC head + softmax: one wave per row ----------
__global__ __launch_bounds__(256) void k_fc(const float* __restrict__ h,
                                            const float* __restrict__ fw1,
                                            const float* __restrict__ fb1,
                                            const float* __restrict__ fw2,
                                            const float* __restrict__ fb2,
                                            float* __restrict__ out) {
    __shared__ float hid[4][64];
    int tid = threadIdx.x;
    int lane = tid & 63;
    int w = tid >> 6;
    int b = blockIdx.x * 4 + w;
    const float* hr = h + b * 128;
    float acc = fb1[lane];
    #pragma unroll 4
    for (int k = 0; k < 128; ++k) acc = fmaf(hr[k], fw1[k * 64 + lane], acc);
    hid[w][lane] = fmaxf(acc, 0.0f);
    __syncthreads();
    if (lane == 0) {
        float lg[3];
        #pragma unroll
        for (int l = 0; l < 3; ++l) {
            float a = fb2[l];
            for (int j = 0; j < 64; ++j) a = fmaf(hid[w][j], fw2[j * 3 + l], a);
            lg[l] = a;
        }
        float m = fmaxf(lg[0], fmaxf(lg[1], lg[2]));
        float e0 = expf(lg[0] - m), e1 = expf(lg[1] - m), e2 = expf(lg[2] - m);
        float s = 1.0f / (e0 + e1 + e2);
        out[b * 3 + 0] = e0 * s;
        out[b * 3 + 1] = e1 * s;
        out[b * 3 + 2] = e2 * s;
    }
}

extern "C" void kernel_launch(void* const* d_in, const int* in_sizes, int n_in,
                              void* d_out, int out_size, void* d_ws, size_t ws_size,
                              hipStream_t stream) {
    const float* x    = (const float*)d_in[0];
    const float* ea   = (const float*)d_in[1];
    const float* W1   = (const float*)d_in[2];
    const float* b1   = (const float*)d_in[3];
    const float* W2   = (const float*)d_in[4];
    const float* b2   = (const float*)d_in[5];
    const float* W_ih = (const float*)d_in[6];
    const float* W_hh = (const float*)d_in[7];
    const float* b_ih = (const float*)d_in[8];
    const float* b_hh = (const float*)d_in[9];
    const float* fw1  = (const float*)d_in[10];
    const float* fb1  = (const float*)d_in[11];
    const float* fw2  = (const float*)d_in[12];
    const float* fb2  = (const float*)d_in[13];
    const int*   ei   = (const int*)d_in[14];
    float* out = (float*)d_out;

    float* ws    = (float*)d_ws;
    float* dinv  = ws;                          // NN
    float* bufA  = dinv + NN;                   // NN*64
    float* bufB  = bufA + NN * 64;              // NN*64
    unsigned short* Bus = (unsigned short*)(bufB + NN * 64);   // 196608 ushort
    float* biasb = bufB + NN * 64 + 98304;      // 512
    float* hbuf  = biasb + 512;                 // NB*128
    int*   cnt   = (int*)(hbuf + NB * 128);     // NN
    int*   off   = cnt + NN;                    // NN+1
    int*   cur   = off + NN + 1;                // NN
    int*   part  = cur + NN;                    // 256
    uint2* edata = (uint2*)(part + 256);        // NE * 8B

    // degree + histogram (fused), dinv
    k_init<<<250, 256, 0, stream>>>(dinv, cnt, cur);
    k_degcnt<<<4000, 256, 0, stream>>>(ei, ea, dinv, cnt);
    k_dinv<<<250, 256, 0, stream>>>(dinv);

    // CSR build (sorted by destination col) — 3-phase multi-block scan
    k_scanA<<<250, 256, 0, stream>>>(cnt, off, part);
    k_scanB<<<1, 256, 0, stream>>>(part, off);
    k_scanC<<<250, 256, 0, stream>>>(part, off);
    k_place<<<4000, 256, 0, stream>>>(ei, ea, dinv, off, cur, edata);

    // LSTM weight fragments
    k_wfrag<<<768, 256, 0, stream>>>(W_ih, W_hh, b_ih, b_hh, Bus, biasb);

    // GCN layer 1
    k_lin<16, false><<<16000, 256, 0, stream>>>(x, W1, bufA);
    k_gather<<<16000, 256, 0, stream>>>(bufA, edata, off, dinv, b1, bufB);

    // GCN layer 2 (relu fused into k_lin read)
    k_lin<64, true><<<16000, 256, 0, stream>>>(bufB, W2, bufA);
    k_gather<<<16000, 256, 0, stream>>>(bufA, edata, off, dinv, b2, bufB);

    // LSTM (relu fused into staging)
    k_lstm<<<250, 512, 0, stream>>>(bufB, Bus, biasb, hbuf);

    // FC head + softmax
    k_fc<<<1000, 256, 0, stream>>>(hbuf, fw1, fb1, fw2, fb2, out);
}

// Round 7
// 395.149 us; speedup vs baseline: 4.9589x; 1.0669x over previous
//
#include <hip/hip_runtime.h>
#include <hip/hip_bf16.h>
#include <math.h>

#define NN 64000      // nodes
#define NE 1024000    // edges
#define NB 4000       // sequences
#define NT 16         // timesteps
#define LROWS 16      // sequences per LSTM block

typedef __attribute__((ext_vector_type(8))) short short8;
typedef __attribute__((ext_vector_type(4))) float f32x4;

__device__ __forceinline__ float sigm(float x) { return 1.0f / (1.0f + expf(-x)); }
__device__ __forceinline__ unsigned short bfbits(float v) {
    __hip_bfloat16 h = __float2bfloat16(v);
    return reinterpret_cast<unsigned short&>(h);
}
__device__ __forceinline__ float bfval(float v) {
    return __bfloat162float(__float2bfloat16(v));
}

// ---------- init: cnt=0, cur=0 ----------
__global__ __launch_bounds__(256) void k_init(int* __restrict__ cnt,
                                              int* __restrict__ cur) {
    int i = blockIdx.x * 256 + threadIdx.x;
    if (i < NN) { cnt[i] = 0; cur[i] = 0; }
}

// ---------- histogram (single int atomic per edge) ----------
__global__ __launch_bounds__(256) void k_cnt(const int* __restrict__ ei,
                                             int* __restrict__ cnt) {
    int e = blockIdx.x * 256 + threadIdx.x;
    if (e < NE) atomicAdd(&cnt[ei[NE + e]], 1);
}

// ---------- 3-phase multi-block exclusive scan over NN bins ----------
__global__ __launch_bounds__(256) void k_scanA(const int* __restrict__ cnt,
                                               int* __restrict__ off,
                                               int* __restrict__ part) {
    __shared__ int sm[256];
    int tid = threadIdx.x;
    int i = blockIdx.x * 256 + tid;
    int v = cnt[i];
    sm[tid] = v;
    __syncthreads();
    #pragma unroll
    for (int d = 1; d < 256; d <<= 1) {
        int t = (tid >= d) ? sm[tid - d] : 0;
        __syncthreads();
        sm[tid] += t;
        __syncthreads();
    }
    off[i] = sm[tid] - v;              // block-local exclusive
    if (tid == 255) part[blockIdx.x] = sm[255];
}
__global__ __launch_bounds__(256) void k_scanB(int* __restrict__ part,
                                               int* __restrict__ off) {
    __shared__ int sm[256];
    int tid = threadIdx.x;
    int v = (tid < 250) ? part[tid] : 0;
    sm[tid] = v;
    __syncthreads();
    #pragma unroll
    for (int d = 1; d < 256; d <<= 1) {
        int t = (tid >= d) ? sm[tid - d] : 0;
        __syncthreads();
        sm[tid] += t;
        __syncthreads();
    }
    if (tid < 250) part[tid] = sm[tid] - v;   // exclusive
    if (tid == 255) off[NN] = sm[255];        // grand total (= NE)
}
__global__ __launch_bounds__(256) void k_scanC(const int* __restrict__ part,
                                               int* __restrict__ off) {
    int i = blockIdx.x * 256 + threadIdx.x;
    off[i] += part[blockIdx.x];
}

// place edges into CSR slots; edata = {row, RAW edge weight}
__global__ __launch_bounds__(256) void k_place(const int* __restrict__ ei,
                                               const float* __restrict__ ew,
                                               const int* __restrict__ off,
                                               int* __restrict__ cur,
                                               uint2* __restrict__ edata) {
    int e = blockIdx.x * 256 + threadIdx.x;
    if (e >= NE) return;
    int r = ei[e];
    int c = ei[NE + e];
    int p = off[c] + atomicAdd(&cur[c], 1);
    edata[p] = make_uint2((unsigned)r, __float_as_uint(ew[e]));
}

// ---------- per-node degree from CSR (no atomics): dinv = rsqrt(1 + sum ew) ----------
// 16 lanes per node, 16 nodes per 256-thread block
__global__ __launch_bounds__(256) void k_deg(const uint2* __restrict__ edata,
                                             const int* __restrict__ off,
                                             float* __restrict__ dinv) {
    int tid = threadIdx.x;
    int n = blockIdx.x * 16 + (tid >> 4);
    int j = tid & 15;
    int s = off[n], e1 = off[n + 1];
    float acc = 0.0f;
    for (int e = s + j; e < e1; e += 16) acc += __uint_as_float(edata[e].y);
    #pragma unroll
    for (int m = 1; m < 16; m <<= 1) acc += __shfl_xor(acc, m, 64);
    if (j == 0) dinv[n] = rsqrtf(1.0f + acc);
}

// ---------- node linear (+dinv fold): Y[n][64] = ((relu?)X[n][:K] @ W[K][64]) * dinv[n] ----------
template<int K, bool RELU_IN>
__global__ __launch_bounds__(256) void k_lin(const float* __restrict__ X,
                                             const float* __restrict__ W,
                                             const float* __restrict__ dinv,
                                             float* __restrict__ Y) {
    __shared__ float Wl[K * 64];
    __shared__ float Xl[4][K];
    int tid = threadIdx.x;
    for (int i = tid; i < K * 64; i += 256) Wl[i] = W[i];
    int n0 = blockIdx.x * 4;
    for (int i = tid; i < 4 * K; i += 256) {
        int r = i / K, d = i % K;
        float v = X[(n0 + r) * K + d];
        Xl[r][d] = RELU_IN ? fmaxf(v, 0.0f) : v;
    }
    __syncthreads();
    int r = tid >> 6, f = tid & 63;
    float acc = 0.0f;
    #pragma unroll
    for (int d = 0; d < K; ++d) acc = fmaf(Xl[r][d], Wl[d * 64 + f], acc);
    Y[(n0 + r) * 64 + f] = acc * dinv[n0 + r];
}

// ---------- CSR gather: agg = dinv[n]*(linp[n] + sum ew*linp[r]) + b ----------
__global__ __launch_bounds__(256) void k_gather(const float* __restrict__ linp,
                                                const uint2* __restrict__ edata,
                                                const int* __restrict__ off,
                                                const float* __restrict__ dinv,
                                                const float* __restrict__ bvec,
                                                float* __restrict__ agg) {
    int tid = threadIdx.x;
    int f = tid & 63;
    int n = blockIdx.x * 4 + (tid >> 6);
    float acc = linp[n * 64 + f];          // self term (linp = lin*dinv)
    int s = off[n], e1 = off[n + 1];
    int e = s;
    for (; e + 1 < e1; e += 2) {
        uint2 d0 = edata[e];
        uint2 d1 = edata[e + 1];
        float l0 = linp[(size_t)d0.x * 64 + f];
        float l1 = linp[(size_t)d1.x * 64 + f];
        acc = fmaf(__uint_as_float(d0.y), l0, acc);
        acc = fmaf(__uint_as_float(d1.y), l1, acc);
    }
    if (e < e1) {
        uint2 d0 = edata[e];
        acc = fmaf(__uint_as_float(d0.y), linp[(size_t)d0.x * 64 + f], acc);
    }
    agg[n * 64 + f] = dinv[n] * acc + bvec[f];
}

// ---------- LSTM weight fragment prep (bf16 hi/lo, MFMA B layout) ----------
__global__ __launch_bounds__(256) void k_wfrag(const float* __restrict__ W_ih,
                                               const float* __restrict__ W_hh,
                                               const float* __restrict__ b_ih,
                                               const float* __restrict__ b_hh,
                                               unsigned short* __restrict__ Bus,
                                               float* __restrict__ biasb) {
    int i = blockIdx.x * 256 + threadIdx.x;
    if (i < 192 * 512 * 2) {
        int j = i & 7;
        int l = (i >> 3) & 63;
        int ci = i >> 9;
        int hl = ci & 1;
        int ntg = (ci >> 1) & 31;
        int ks = ci >> 6;
        int col = ntg * 16 + (l & 15);
        int k = ks * 32 + ((l >> 4) << 3) + j;
        float w = (k < 64) ? W_ih[col * 64 + k] : W_hh[col * 128 + (k - 64)];
        float hi = bfval(w);
        Bus[i] = bfbits(hl ? (w - hi) : w);
    }
    if (i < 512) biasb[i] = b_ih[i] + b_hh[i];
}

// ---------- LSTM: MFMA bf16x3, 16 rows/block, gate-quad wave split ----------
__global__ __launch_bounds__(512, 2) void k_lstm(const float* __restrict__ seq,
                                                 const unsigned short* __restrict__ Bus,
                                                 const float* __restrict__ biasb,
                                                 float* __restrict__ hout) {
    __shared__ unsigned short Aus[12 * 512];   // 6 ks x hi/lo x 1KB
    int tid = threadIdx.x;
    int lane = tid & 63;
    int w = tid >> 6;
    int b0 = blockIdx.x * LROWS;

    int u = w * 16 + (lane & 15);
    int rbase = (lane >> 4) * 4;
    float bI = biasb[u], bF = biasb[128 + u], bG = biasb[256 + u], bO = biasb[384 + u];
    float cst[4] = {0.0f, 0.0f, 0.0f, 0.0f};

    // zero h region (chunks 4..11), stage seq t=0 (chunks 0..3)
    for (int i = tid; i < 2048; i += 512) ((unsigned int*)Aus)[2 * 512 + i] = 0;
    {
        int i0 = tid * 2;
        int row = i0 >> 6, k0 = i0 & 63;
        float2 v = *(const float2*)&seq[((size_t)(b0 + row) * NT + 0) * 64 + k0];
        float v0 = fmaxf(v.x, 0.0f), v1 = fmaxf(v.y, 0.0f);
        int ks = k0 >> 5, kr = k0 & 31;
        int idx = (ks * 2) * 512 + (((kr >> 3) << 4) + row) * 8 + (kr & 7);
        Aus[idx] = bfbits(v0);
        Aus[idx + 512] = bfbits(v0 - bfval(v0));
        kr = (k0 + 1) & 31; ks = (k0 + 1) >> 5;
        idx = (ks * 2) * 512 + (((kr >> 3) << 4) + row) * 8 + (kr & 7);
        Aus[idx] = bfbits(v1);
        Aus[idx + 512] = bfbits(v1 - bfval(v1));
    }
    __syncthreads();

    for (int t = 0; t < NT; ++t) {
        f32x4 acc[4];
        #pragma unroll
        for (int g = 0; g < 4; ++g) acc[g] = (f32x4){0.f, 0.f, 0.f, 0.f};
        #pragma unroll
        for (int ks = 0; ks < 6; ++ks) {
            short8 ah = *(const short8*)&Aus[(ks * 2 + 0) * 512 + lane * 8];
            short8 al = *(const short8*)&Aus[(ks * 2 + 1) * 512 + lane * 8];
            short8 bh[4], bl[4];
            #pragma unroll
            for (int g = 0; g < 4; ++g) {
                size_t ci = (size_t)(ks * 32 + 8 * g + w) * 2;
                bh[g] = *(const short8*)&Bus[ci * 512 + lane * 8];
                bl[g] = *(const short8*)&Bus[(ci + 1) * 512 + lane * 8];
            }
            #pragma unroll
            for (int g = 0; g < 4; ++g)
                acc[g] = __builtin_amdgcn_mfma_f32_16x16x32_bf16(ah, bh[g], acc[g], 0, 0, 0);
            #pragma unroll
            for (int g = 0; g < 4; ++g)
                acc[g] = __builtin_amdgcn_mfma_f32_16x16x32_bf16(ah, bl[g], acc[g], 0, 0, 0);
            #pragma unroll
            for (int g = 0; g < 4; ++g)
                acc[g] = __builtin_amdgcn_mfma_f32_16x16x32_bf16(al, bh[g], acc[g], 0, 0, 0);
        }
        __syncthreads();   // all A reads of t complete

        if (t == NT - 1) {
            #pragma unroll
            for (int q = 0; q < 4; ++q) {
                float nc = sigm(acc[1][q] + bF) * cst[q]
                         + sigm(acc[0][q] + bI) * tanhf(acc[2][q] + bG);
                cst[q] = nc;
                float hv = sigm(acc[3][q] + bO) * tanhf(nc);
                hout[(size_t)(b0 + rbase + q) * 128 + u] = hv;
            }
        } else {
            int kh = 64 + u;
            int ksh = kh >> 5, krh = kh & 31;
            int hbase = (ksh * 2) * 512 + ((krh >> 3) << 4) * 8 + (krh & 7);
            #pragma unroll
            for (int q = 0; q < 4; ++q) {
                float nc = sigm(acc[1][q] + bF) * cst[q]
                         + sigm(acc[0][q] + bI) * tanhf(acc[2][q] + bG);
                cst[q] = nc;
                float hv = sigm(acc[3][q] + bO) * tanhf(nc);
                int idx = hbase + (rbase + q) * 8;
                Aus[idx] = bfbits(hv);
                Aus[idx + 512] = bfbits(hv - bfval(hv));
            }
            {
                int i0 = tid * 2;
                int row = i0 >> 6, k0 = i0 & 63;
                float2 v = *(const float2*)&seq[((size_t)(b0 + row) * NT + (t + 1)) * 64 + k0];
                float v0 = fmaxf(v.x, 0.0f), v1 = fmaxf(v.y, 0.0f);
                int ks = k0 >> 5, kr = k0 & 31;
                int idx = (ks * 2) * 512 + (((kr >> 3) << 4) + row) * 8 + (kr & 7);
                Aus[idx] = bfbits(v0);
                Aus[idx + 512] = bfbits(v0 - bfval(v0));
                kr = (k0 + 1) & 31; ks = (k0 + 1) >> 5;
                idx = (ks * 2) * 512 + (((kr >> 3) << 4) + row) * 8 + (kr & 7);
                Aus[idx] = bfbits(v1);
                Aus[idx + 512] = bfbits(v1 - bfval(v1));
            }
            __syncthreads();
        }
    }
}

// ---------- FC head + softmax: one wave per row ----------
__global__ __launch_bounds__(256) void k_fc(const float* __restrict__ h,
                                            const float* __restrict__ fw1,
                                            const float* __restrict__ fb1,
                                            const float* __restrict__ fw2,
                                            const float* __restrict__ fb2,
                                            float* __restrict__ out) {
    __shared__ float hid[4][64];
    int tid = threadIdx.x;
    int lane = tid & 63;
    int w = tid >> 6;
    int b = blockIdx.x * 4 + w;
    const float* hr = h + b * 128;
    float acc = fb1[lane];
    #pragma unroll 4
    for (int k = 0; k < 128; ++k) acc = fmaf(hr[k], fw1[k * 64 + lane], acc);
    hid[w][lane] = fmaxf(acc, 0.0f);
    __syncthreads();
    if (lane == 0) {
        float lg[3];
        #pragma unroll
        for (int l = 0; l < 3; ++l) {
            float a = fb2[l];
            for (int j = 0; j < 64; ++j) a = fmaf(hid[w][j], fw2[j * 3 + l], a);
            lg[l] = a;
        }
        float m = fmaxf(lg[0], fmaxf(lg[1], lg[2]));
        float e0 = expf(lg[0] - m), e1 = expf(lg[1] - m), e2 = expf(lg[2] - m);
        float s = 1.0f / (e0 + e1 + e2);
        out[b * 3 + 0] = e0 * s;
        out[b * 3 + 1] = e1 * s;
        out[b * 3 + 2] = e2 * s;
    }
}

extern "C" void kernel_launch(void* const* d_in, const int* in_sizes, int n_in,
                              void* d_out, int out_size, void* d_ws, size_t ws_size,
                              hipStream_t stream) {
    const float* x    = (const float*)d_in[0];
    const float* ea   = (const float*)d_in[1];
    const float* W1   = (const float*)d_in[2];
    const float* b1   = (const float*)d_in[3];
    const float* W2   = (const float*)d_in[4];
    const float* b2   = (const float*)d_in[5];
    const float* W_ih = (const float*)d_in[6];
    const float* W_hh = (const float*)d_in[7];
    const float* b_ih = (const float*)d_in[8];
    const float* b_hh = (const float*)d_in[9];
    const float* fw1  = (const float*)d_in[10];
    const float* fb1  = (const float*)d_in[11];
    const float* fw2  = (const float*)d_in[12];
    const float* fb2  = (const float*)d_in[13];
    const int*   ei   = (const int*)d_in[14];
    float* out = (float*)d_out;

    float* ws    = (float*)d_ws;
    float* dinv  = ws;                          // NN
    float* bufA  = dinv + NN;                   // NN*64
    float* bufB  = bufA + NN * 64;              // NN*64
    unsigned short* Bus = (unsigned short*)(bufB + NN * 64);   // 196608 ushort
    float* biasb = bufB + NN * 64 + 98304;      // 512
    float* hbuf  = biasb + 512;                 // NB*128
    int*   cnt   = (int*)(hbuf + NB * 128);     // NN
    int*   off   = cnt + NN;                    // NN+1
    int*   cur   = off + NN + 1;                // NN
    int*   part  = cur + NN;                    // 256
    uint2* edata = (uint2*)(part + 256);        // NE * 8B

    // CSR build (sorted by destination col); single int atomic per edge
    k_init<<<250, 256, 0, stream>>>(cnt, cur);
    k_cnt<<<4000, 256, 0, stream>>>(ei, cnt);
    k_scanA<<<250, 256, 0, stream>>>(cnt, off, part);
    k_scanB<<<1, 256, 0, stream>>>(part, off);
    k_scanC<<<250, 256, 0, stream>>>(part, off);
    k_place<<<4000, 256, 0, stream>>>(ei, ea, off, cur, edata);

    // degree from CSR (no atomics)
    k_deg<<<4000, 256, 0, stream>>>(edata, off, dinv);

    // LSTM weight fragments
    k_wfrag<<<768, 256, 0, stream>>>(W_ih, W_hh, b_ih, b_hh, Bus, biasb);

    // GCN layer 1 (dinv folded into lin output)
    k_lin<16, false><<<16000, 256, 0, stream>>>(x, W1, dinv, bufA);
    k_gather<<<16000, 256, 0, stream>>>(bufA, edata, off, dinv, b1, bufB);

    // GCN layer 2 (relu fused into k_lin read)
    k_lin<64, true><<<16000, 256, 0, stream>>>(bufB, W2, dinv, bufA);
    k_gather<<<16000, 256, 0, stream>>>(bufA, edata, off, dinv, b2, bufB);

    // LSTM (relu fused into staging)
    k_lstm<<<250, 512, 0, stream>>>(bufB, Bus, biasb, hbuf);

    // FC head + softmax
    k_fc<<<1000, 256, 0, stream>>>(hbuf, fw1, fb1, fw2, fb2, out);
}

// Round 8
// 380.450 us; speedup vs baseline: 5.1505x; 1.0386x over previous
//
#include <hip/hip_runtime.h>
#include <hip/hip_bf16.h>
#include <math.h>

#define NN 64000      // nodes
#define NE 1024000    // edges
#define NB 4000       // sequences
#define NT 16         // timesteps
#define LROWS 16      // sequences per LSTM block

typedef __attribute__((ext_vector_type(8))) short short8;
typedef __attribute__((ext_vector_type(4))) float f32x4;

__device__ __forceinline__ float sigm(float x) { return 1.0f / (1.0f + expf(-x)); }
__device__ __forceinline__ unsigned short bfbits(float v) {
    __hip_bfloat16 h = __float2bfloat16(v);
    return reinterpret_cast<unsigned short&>(h);
}
__device__ __forceinline__ float bfval(float v) {
    return __bfloat162float(__float2bfloat16(v));
}

// ---------- init: cnt=0 ----------
__global__ __launch_bounds__(256) void k_init(int* __restrict__ cnt) {
    int i = blockIdx.x * 256 + threadIdx.x;
    if (i < NN) cnt[i] = 0;
}

// ---------- histogram (single int atomic per edge) ----------
__global__ __launch_bounds__(256) void k_cnt(const int* __restrict__ ei,
                                             int* __restrict__ cnt) {
    int e = blockIdx.x * 256 + threadIdx.x;
    if (e < NE) atomicAdd(&cnt[ei[NE + e]], 1);
}

// ---------- 3-phase multi-block exclusive scan over NN bins ----------
__global__ __launch_bounds__(256) void k_scanA(const int* __restrict__ cnt,
                                               int* __restrict__ off,
                                               int* __restrict__ part) {
    __shared__ int sm[256];
    int tid = threadIdx.x;
    int i = blockIdx.x * 256 + tid;
    int v = cnt[i];
    sm[tid] = v;
    __syncthreads();
    #pragma unroll
    for (int d = 1; d < 256; d <<= 1) {
        int t = (tid >= d) ? sm[tid - d] : 0;
        __syncthreads();
        sm[tid] += t;
        __syncthreads();
    }
    off[i] = sm[tid] - v;              // block-local exclusive
    if (tid == 255) part[blockIdx.x] = sm[255];
}
__global__ __launch_bounds__(256) void k_scanB(int* __restrict__ part,
                                               int* __restrict__ off) {
    __shared__ int sm[256];
    int tid = threadIdx.x;
    int v = (tid < 250) ? part[tid] : 0;
    sm[tid] = v;
    __syncthreads();
    #pragma unroll
    for (int d = 1; d < 256; d <<= 1) {
        int t = (tid >= d) ? sm[tid - d] : 0;
        __syncthreads();
        sm[tid] += t;
        __syncthreads();
    }
    if (tid < 250) part[tid] = sm[tid] - v;   // exclusive
    if (tid == 255) off[NN] = sm[255];        // grand total (= NE)
}
// C: add block offsets back; also emit cursor copy for k_place
__global__ __launch_bounds__(256) void k_scanC(const int* __restrict__ part,
                                               int* __restrict__ off,
                                               int* __restrict__ cur) {
    int i = blockIdx.x * 256 + threadIdx.x;
    int v = off[i] + part[blockIdx.x];
    off[i] = v;
    cur[i] = v;
}

// place edges into CSR slots; edata = {row, RAW edge weight}; cur IS the cursor
__global__ __launch_bounds__(256) void k_place(const int* __restrict__ ei,
                                               const float* __restrict__ ew,
                                               int* __restrict__ cur,
                                               uint2* __restrict__ edata) {
    int e = blockIdx.x * 256 + threadIdx.x;
    if (e >= NE) return;
    int r = ei[e];
    int c = ei[NE + e];
    int p = atomicAdd(&cur[c], 1);
    edata[p] = make_uint2((unsigned)r, __float_as_uint(ew[e]));
}

// ---------- per-node degree from CSR (no atomics): dinv = rsqrt(1 + sum ew) ----------
__global__ __launch_bounds__(256) void k_deg(const uint2* __restrict__ edata,
                                             const int* __restrict__ off,
                                             float* __restrict__ dinv) {
    int tid = threadIdx.x;
    int n = blockIdx.x * 16 + (tid >> 4);
    int j = tid & 15;
    int s = off[n], e1 = off[n + 1];
    float acc = 0.0f;
    for (int e = s + j; e < e1; e += 16) acc += __uint_as_float(edata[e].y);
    #pragma unroll
    for (int m = 1; m < 16; m <<= 1) acc += __shfl_xor(acc, m, 64);
    if (j == 0) dinv[n] = rsqrtf(1.0f + acc);
}

// ---------- node linear (+dinv fold): Y[n][64] = ((relu?)X[n][:K] @ W[K][64]) * dinv[n] ----------
template<int K, bool RELU_IN>
__global__ __launch_bounds__(256) void k_lin(const float* __restrict__ X,
                                             const float* __restrict__ W,
                                             const float* __restrict__ dinv,
                                             float* __restrict__ Y) {
    __shared__ float Wl[K * 64];
    __shared__ float Xl[4][K];
    int tid = threadIdx.x;
    for (int i = tid; i < K * 64; i += 256) Wl[i] = W[i];
    int n0 = blockIdx.x * 4;
    for (int i = tid; i < 4 * K; i += 256) {
        int r = i / K, d = i % K;
        float v = X[(n0 + r) * K + d];
        Xl[r][d] = RELU_IN ? fmaxf(v, 0.0f) : v;
    }
    __syncthreads();
    int r = tid >> 6, f = tid & 63;
    float acc = 0.0f;
    #pragma unroll
    for (int d = 0; d < K; ++d) acc = fmaf(Xl[r][d], Wl[d * 64 + f], acc);
    Y[(n0 + r) * 64 + f] = acc * dinv[n0 + r];
}

// ---------- CSR gather: agg = dinv[n]*(linp[n] + sum ew*linp[r]) + b ----------
__global__ __launch_bounds__(256) void k_gather(const float* __restrict__ linp,
                                                const uint2* __restrict__ edata,
                                                const int* __restrict__ off,
                                                const float* __restrict__ dinv,
                                                const float* __restrict__ bvec,
                                                float* __restrict__ agg) {
    int tid = threadIdx.x;
    int f = tid & 63;
    int n = blockIdx.x * 4 + (tid >> 6);
    float acc = linp[n * 64 + f];          // self term (linp = lin*dinv)
    int s = off[n], e1 = off[n + 1];
    int e = s;
    for (; e + 1 < e1; e += 2) {
        uint2 d0 = edata[e];
        uint2 d1 = edata[e + 1];
        float l0 = linp[(size_t)d0.x * 64 + f];
        float l1 = linp[(size_t)d1.x * 64 + f];
        acc = fmaf(__uint_as_float(d0.y), l0, acc);
        acc = fmaf(__uint_as_float(d1.y), l1, acc);
    }
    if (e < e1) {
        uint2 d0 = edata[e];
        acc = fmaf(__uint_as_float(d0.y), linp[(size_t)d0.x * 64 + f], acc);
    }
    agg[n * 64 + f] = dinv[n] * acc + bvec[f];
}

// ---------- LSTM weight fragment prep (bf16 hi/lo, MFMA B layout) ----------
__global__ __launch_bounds__(256) void k_wfrag(const float* __restrict__ W_ih,
                                               const float* __restrict__ W_hh,
                                               const float* __restrict__ b_ih,
                                               const float* __restrict__ b_hh,
                                               unsigned short* __restrict__ Bus,
                                               float* __restrict__ biasb) {
    int i = blockIdx.x * 256 + threadIdx.x;
    if (i < 192 * 512 * 2) {
        int j = i & 7;
        int l = (i >> 3) & 63;
        int ci = i >> 9;
        int hl = ci & 1;
        int ntg = (ci >> 1) & 31;
        int ks = ci >> 6;
        int col = ntg * 16 + (l & 15);
        int k = ks * 32 + ((l >> 4) << 3) + j;
        float w = (k < 64) ? W_ih[col * 64 + k] : W_hh[col * 128 + (k - 64)];
        float hi = bfval(w);
        Bus[i] = bfbits(hl ? (w - hi) : w);
    }
    if (i < 512) biasb[i] = b_ih[i] + b_hh[i];
}

// ---------- LSTM: MFMA bf16x3; per-wave B-slice REGISTER-RESIDENT across t ----------
// Wave w owns units u = w*16+(lane&15) across all 4 gates (B chunks ntg=8g+w).
// B slice = 6ks x 4g x hi/lo x short8 = 192 VGPRs, loaded once, reused 16 t.
__global__ __launch_bounds__(512, 2) void k_lstm(const float* __restrict__ seq,
                                                 const unsigned short* __restrict__ Bus,
                                                 const float* __restrict__ biasb,
                                                 float* __restrict__ hout) {
    __shared__ unsigned short Aus[12 * 512];   // 6 ks x hi/lo x 1KB
    int tid = threadIdx.x;
    int lane = tid & 63;
    int w = tid >> 6;
    int b0 = blockIdx.x * LROWS;

    int u = w * 16 + (lane & 15);
    int rbase = (lane >> 4) * 4;
    float bI = biasb[u], bF = biasb[128 + u], bG = biasb[256 + u], bO = biasb[384 + u];
    float cst[4] = {0.0f, 0.0f, 0.0f, 0.0f};

    // ---- load this wave's B slice into registers (once) ----
    short8 Bh[24], Bl[24];   // [ks*4+g]
    #pragma unroll
    for (int ks = 0; ks < 6; ++ks) {
        #pragma unroll
        for (int g = 0; g < 4; ++g) {
            size_t ci = (size_t)(ks * 32 + 8 * g + w) * 2;
            Bh[ks * 4 + g] = *(const short8*)&Bus[ci * 512 + lane * 8];
            Bl[ks * 4 + g] = *(const short8*)&Bus[(ci + 1) * 512 + lane * 8];
        }
    }

    // zero h region (chunks 4..11), stage seq t=0 (chunks 0..3)
    for (int i = tid; i < 2048; i += 512) ((unsigned int*)Aus)[2 * 512 + i] = 0;
    {
        int i0 = tid * 2;
        int row = i0 >> 6, k0 = i0 & 63;
        float2 v = *(const float2*)&seq[((size_t)(b0 + row) * NT + 0) * 64 + k0];
        float v0 = fmaxf(v.x, 0.0f), v1 = fmaxf(v.y, 0.0f);
        int ks = k0 >> 5, kr = k0 & 31;
        int idx = (ks * 2) * 512 + (((kr >> 3) << 4) + row) * 8 + (kr & 7);
        Aus[idx] = bfbits(v0);
        Aus[idx + 512] = bfbits(v0 - bfval(v0));
        kr = (k0 + 1) & 31; ks = (k0 + 1) >> 5;
        idx = (ks * 2) * 512 + (((kr >> 3) << 4) + row) * 8 + (kr & 7);
        Aus[idx] = bfbits(v1);
        Aus[idx + 512] = bfbits(v1 - bfval(v1));
    }
    __syncthreads();

    for (int t = 0; t < NT; ++t) {
        f32x4 acc[4];
        #pragma unroll
        for (int g = 0; g < 4; ++g) acc[g] = (f32x4){0.f, 0.f, 0.f, 0.f};
        #pragma unroll
        for (int ks = 0; ks < 6; ++ks) {
            short8 ah = *(const short8*)&Aus[(ks * 2 + 0) * 512 + lane * 8];
            short8 al = *(const short8*)&Aus[(ks * 2 + 1) * 512 + lane * 8];
            #pragma unroll
            for (int g = 0; g < 4; ++g)
                acc[g] = __builtin_amdgcn_mfma_f32_16x16x32_bf16(ah, Bh[ks * 4 + g], acc[g], 0, 0, 0);
            #pragma unroll
            for (int g = 0; g < 4; ++g)
                acc[g] = __builtin_amdgcn_mfma_f32_16x16x32_bf16(ah, Bl[ks * 4 + g], acc[g], 0, 0, 0);
            #pragma unroll
            for (int g = 0; g < 4; ++g)
                acc[g] = __builtin_amdgcn_mfma_f32_16x16x32_bf16(al, Bh[ks * 4 + g], acc[g], 0, 0, 0);
        }
        __syncthreads();   // all A reads of t complete

        if (t == NT - 1) {
            #pragma unroll
            for (int q = 0; q < 4; ++q) {
                float nc = sigm(acc[1][q] + bF) * cst[q]
                         + sigm(acc[0][q] + bI) * tanhf(acc[2][q] + bG);
                cst[q] = nc;
                float hv = sigm(acc[3][q] + bO) * tanhf(nc);
                hout[(size_t)(b0 + rbase + q) * 128 + u] = hv;
            }
        } else {
            int kh = 64 + u;
            int ksh = kh >> 5, krh = kh & 31;
            int hbase = (ksh * 2) * 512 + ((krh >> 3) << 4) * 8 + (krh & 7);
            #pragma unroll
            for (int q = 0; q < 4; ++q) {
                float nc = sigm(acc[1][q] + bF) * cst[q]
                         + sigm(acc[0][q] + bI) * tanhf(acc[2][q] + bG);
                cst[q] = nc;
                float hv = sigm(acc[3][q] + bO) * tanhf(nc);
                int idx = hbase + (rbase + q) * 8;
                Aus[idx] = bfbits(hv);
                Aus[idx + 512] = bfbits(hv - bfval(hv));
            }
            {
                int i0 = tid * 2;
                int row = i0 >> 6, k0 = i0 & 63;
                float2 v = *(const float2*)&seq[((size_t)(b0 + row) * NT + (t + 1)) * 64 + k0];
                float v0 = fmaxf(v.x, 0.0f), v1 = fmaxf(v.y, 0.0f);
                int ks = k0 >> 5, kr = k0 & 31;
                int idx = (ks * 2) * 512 + (((kr >> 3) << 4) + row) * 8 + (kr & 7);
                Aus[idx] = bfbits(v0);
                Aus[idx + 512] = bfbits(v0 - bfval(v0));
                kr = (k0 + 1) & 31; ks = (k0 + 1) >> 5;
                idx = (ks * 2) * 512 + (((kr >> 3) << 4) + row) * 8 + (kr & 7);
                Aus[idx] = bfbits(v1);
                Aus[idx + 512] = bfbits(v1 - bfval(v1));
            }
            __syncthreads();
        }
    }
}

// ---------- FC head + softmax: one wave per row ----------
__global__ __launch_bounds__(256) void k_fc(const float* __restrict__ h,
                                            const float* __restrict__ fw1,
                                            const float* __restrict__ fb1,
                                            const float* __restrict__ fw2,
                                            const float* __restrict__ fb2,
                                            float* __restrict__ out) {
    __shared__ float hid[4][64];
    int tid = threadIdx.x;
    int lane = tid & 63;
    int w = tid >> 6;
    int b = blockIdx.x * 4 + w;
    const float* hr = h + b * 128;
    float acc = fb1[lane];
    #pragma unroll 4
    for (int k = 0; k < 128; ++k) acc = fmaf(hr[k], fw1[k * 64 + lane], acc);
    hid[w][lane] = fmaxf(acc, 0.0f);
    __syncthreads();
    if (lane == 0) {
        float lg[3];
        #pragma unroll
        for (int l = 0; l < 3; ++l) {
            float a = fb2[l];
            for (int j = 0; j < 64; ++j) a = fmaf(hid[w][j], fw2[j * 3 + l], a);
            lg[l] = a;
        }
        float m = fmaxf(lg[0], fmaxf(lg[1], lg[2]));
        float e0 = expf(lg[0] - m), e1 = expf(lg[1] - m), e2 = expf(lg[2] - m);
        float s = 1.0f / (e0 + e1 + e2);
        out[b * 3 + 0] = e0 * s;
        out[b * 3 + 1] = e1 * s;
        out[b * 3 + 2] = e2 * s;
    }
}

extern "C" void kernel_launch(void* const* d_in, const int* in_sizes, int n_in,
                              void* d_out, int out_size, void* d_ws, size_t ws_size,
                              hipStream_t stream) {
    const float* x    = (const float*)d_in[0];
    const float* ea   = (const float*)d_in[1];
    const float* W1   = (const float*)d_in[2];
    const float* b1   = (const float*)d_in[3];
    const float* W2   = (const float*)d_in[4];
    const float* b2   = (const float*)d_in[5];
    const float* W_ih = (const float*)d_in[6];
    const float* W_hh = (const float*)d_in[7];
    const float* b_ih = (const float*)d_in[8];
    const float* b_hh = (const float*)d_in[9];
    const float* fw1  = (const float*)d_in[10];
    const float* fb1  = (const float*)d_in[11];
    const float* fw2  = (const float*)d_in[12];
    const float* fb2  = (const float*)d_in[13];
    const int*   ei   = (const int*)d_in[14];
    float* out = (float*)d_out;

    float* ws    = (float*)d_ws;
    float* dinv  = ws;                          // NN
    float* bufA  = dinv + NN;                   // NN*64
    float* bufB  = bufA + NN * 64;              // NN*64
    unsigned short* Bus = (unsigned short*)(bufB + NN * 64);   // 196608 ushort
    float* biasb = bufB + NN * 64 + 98304;      // 512
    float* hbuf  = biasb + 512;                 // NB*128
    int*   cnt   = (int*)(hbuf + NB * 128);     // NN
    int*   off   = cnt + NN;                    // NN+1
    int*   cur   = off + NN + 1;                // NN
    int*   part  = cur + NN;                    // 256
    uint2* edata = (uint2*)(part + 256);        // NE * 8B

    // CSR build (sorted by destination col); single int atomic per edge
    k_init<<<250, 256, 0, stream>>>(cnt);
    k_cnt<<<4000, 256, 0, stream>>>(ei, cnt);
    k_scanA<<<250, 256, 0, stream>>>(cnt, off, part);
    k_scanB<<<1, 256, 0, stream>>>(part, off);
    k_scanC<<<250, 256, 0, stream>>>(part, off, cur);
    k_place<<<4000, 256, 0, stream>>>(ei, ea, cur, edata);

    // degree from CSR (no atomics)
    k_deg<<<4000, 256, 0, stream>>>(edata, off, dinv);

    // LSTM weight fragments
    k_wfrag<<<768, 256, 0, stream>>>(W_ih, W_hh, b_ih, b_hh, Bus, biasb);

    // GCN layer 1 (dinv folded into lin output)
    k_lin<16, false><<<16000, 256, 0, stream>>>(x, W1, dinv, bufA);
    k_gather<<<16000, 256, 0, stream>>>(bufA, edata, off, dinv, b1, bufB);

    // GCN layer 2 (relu fused into k_lin read)
    k_lin<64, true><<<16000, 256, 0, stream>>>(bufB, W2, dinv, bufA);
    k_gather<<<16000, 256, 0, stream>>>(bufA, edata, off, dinv, b2, bufB);

    // LSTM (relu fused into staging)
    k_lstm<<<250, 512, 0, stream>>>(bufB, Bus, biasb, hbuf);

    // FC head + softmax
    k_fc<<<1000, 256, 0, stream>>>(hbuf, fw1, fb1, fw2, fb2, out);
}

// Round 9
// 300.577 us; speedup vs baseline: 6.5191x; 1.2657x over previous
//
#include <hip/hip_runtime.h>
#include <hip/hip_bf16.h>
#include <math.h>

#define NN 64000      // nodes
#define NE 1024000    // edges
#define NB 4000       // sequences
#define NT 16         // timesteps
#define LROWS 16      // sequences per LSTM block
#define NBKT 250      // coarse buckets (c>>8), NN/256

typedef __attribute__((ext_vector_type(8))) short short8;
typedef __attribute__((ext_vector_type(4))) float f32x4;

__device__ __forceinline__ float sigm(float x) { return 1.0f / (1.0f + expf(-x)); }
__device__ __forceinline__ unsigned short bfbits(float v) {
    __hip_bfloat16 h = __float2bfloat16(v);
    return reinterpret_cast<unsigned short&>(h);
}
__device__ __forceinline__ float bfval(float v) {
    return __bfloat162float(__float2bfloat16(v));
}

// ---------- zero the bucket counters ----------
__global__ __launch_bounds__(256) void k_zero256(int* __restrict__ p) {
    p[threadIdx.x] = 0;
}

// ---------- P0: coarse bucket histogram (LDS-privatized) ----------
__global__ __launch_bounds__(256) void k_bhist(const int* __restrict__ ei,
                                               int* __restrict__ bcnt) {
    __shared__ int h[256];
    int tid = threadIdx.x;
    h[tid] = 0;
    __syncthreads();
    int base = blockIdx.x * 4096;
    #pragma unroll
    for (int j = 0; j < 16; ++j) {
        int c = ei[NE + base + j * 256 + tid];
        atomicAdd(&h[c >> 8], 1);
    }
    __syncthreads();
    if (tid < NBKT && h[tid]) atomicAdd(&bcnt[tid], h[tid]);
}

// ---------- scan 250 bucket counts -> bbase[251]; cursor copy ----------
__global__ __launch_bounds__(256) void k_bscan(const int* __restrict__ bcnt,
                                               int* __restrict__ bbase,
                                               int* __restrict__ bcur) {
    __shared__ int sm[256];
    int tid = threadIdx.x;
    int v = (tid < NBKT) ? bcnt[tid] : 0;
    sm[tid] = v;
    __syncthreads();
    #pragma unroll
    for (int d = 1; d < 256; d <<= 1) {
        int t = (tid >= d) ? sm[tid - d] : 0;
        __syncthreads();
        sm[tid] += t;
        __syncthreads();
    }
    if (tid < NBKT) { int ex = sm[tid] - v; bbase[tid] = ex; bcur[tid] = ex; }
    if (tid == 255) bbase[NBKT] = sm[255];   // = NE
}

// ---------- P1: bin edges by bucket via LDS sort; coalesced run writes ----------
// record: x = r | (c&255)<<16 | bucket<<24 ; y = raw ew bits
__global__ __launch_bounds__(256) void k_bin(const int* __restrict__ ei,
                                             const float* __restrict__ ew,
                                             int* __restrict__ bcur,
                                             uint2* __restrict__ binned) {
    __shared__ uint2 stage[4096];
    __shared__ int sm[256];
    __shared__ int lofs[256], lcur[256], ladj[256];
    int tid = threadIdx.x;
    sm[tid] = 0;
    __syncthreads();
    int base = blockIdx.x * 4096;
    int cs[16];
    #pragma unroll
    for (int j = 0; j < 16; ++j) {
        cs[j] = ei[NE + base + j * 256 + tid];
        atomicAdd(&sm[cs[j] >> 8], 1);
    }
    __syncthreads();
    int v = sm[tid];
    #pragma unroll
    for (int d = 1; d < 256; d <<= 1) {
        int t = (tid >= d) ? sm[tid - d] : 0;
        __syncthreads();
        sm[tid] += t;
        __syncthreads();
    }
    int ex = sm[tid] - v;
    lofs[tid] = ex;
    lcur[tid] = ex;
    if (tid < NBKT) ladj[tid] = atomicAdd(&bcur[tid], v) - ex;
    __syncthreads();
    #pragma unroll
    for (int j = 0; j < 16; ++j) {
        int e = base + j * 256 + tid;
        int c = cs[j];
        int b = c >> 8;
        unsigned r = (unsigned)ei[e];
        float wv = ew[e];
        int slot = atomicAdd(&lcur[b], 1);
        stage[slot] = make_uint2(r | ((unsigned)(c & 255) << 16) | ((unsigned)b << 24),
                                 __float_as_uint(wv));
    }
    __syncthreads();
    #pragma unroll
    for (int j = 0; j < 16; ++j) {
        int i = j * 256 + tid;
        uint2 rec = stage[i];
        int b = rec.x >> 24;
        binned[ladj[b] + i] = rec;
    }
}

// ---------- P2: per-bucket final CSR sort + off[] + dinv (deg folded) ----------
__global__ __launch_bounds__(256) void k_csr(const uint2* __restrict__ binned,
                                             const int* __restrict__ bbase,
                                             uint2* __restrict__ edata,
                                             int* __restrict__ off,
                                             float* __restrict__ dinv) {
    __shared__ int cnt[256];
    __shared__ float sumw[256];
    __shared__ int lcur[256];
    __shared__ int sm[256];
    int tid = threadIdx.x;
    int b = blockIdx.x;
    int s = bbase[b], e1 = bbase[b + 1];
    cnt[tid] = 0;
    sumw[tid] = 0.0f;
    __syncthreads();
    for (int i = s + tid; i < e1; i += 256) {
        uint2 rec = binned[i];
        int nl = (rec.x >> 16) & 255;
        atomicAdd(&cnt[nl], 1);
        atomicAdd(&sumw[nl], __uint_as_float(rec.y));
    }
    __syncthreads();
    int v = cnt[tid];
    sm[tid] = v;
    __syncthreads();
    #pragma unroll
    for (int d = 1; d < 256; d <<= 1) {
        int t = (tid >= d) ? sm[tid - d] : 0;
        __syncthreads();
        sm[tid] += t;
        __syncthreads();
    }
    int ex = sm[tid] - v;
    off[b * 256 + tid] = s + ex;
    dinv[b * 256 + tid] = rsqrtf(1.0f + sumw[tid]);
    lcur[tid] = ex;
    if (b == 0 && tid == 0) off[NN] = NE;
    __syncthreads();
    for (int i = s + tid; i < e1; i += 256) {
        uint2 rec = binned[i];
        int nl = (rec.x >> 16) & 255;
        int p = atomicAdd(&lcur[nl], 1);
        edata[s + p] = make_uint2(rec.x & 0xFFFFu, rec.y);
    }
}

// ---------- node linear (+dinv fold): Y[n][64] = ((relu?)X[n][:K] @ W[K][64]) * dinv[n] ----------
template<int K, bool RELU_IN>
__global__ __launch_bounds__(256) void k_lin(const float* __restrict__ X,
                                             const float* __restrict__ W,
                                             const float* __restrict__ dinv,
                                             float* __restrict__ Y) {
    __shared__ float Wl[K * 64];
    __shared__ float Xl[4][K];
    int tid = threadIdx.x;
    for (int i = tid; i < K * 64; i += 256) Wl[i] = W[i];
    int n0 = blockIdx.x * 4;
    for (int i = tid; i < 4 * K; i += 256) {
        int r = i / K, d = i % K;
        float v = X[(n0 + r) * K + d];
        Xl[r][d] = RELU_IN ? fmaxf(v, 0.0f) : v;
    }
    __syncthreads();
    int r = tid >> 6, f = tid & 63;
    float acc = 0.0f;
    #pragma unroll
    for (int d = 0; d < K; ++d) acc = fmaf(Xl[r][d], Wl[d * 64 + f], acc);
    Y[(n0 + r) * 64 + f] = acc * dinv[n0 + r];
}

// ---------- CSR gather: agg = dinv[n]*(linp[n] + sum ew*linp[r]) + b ----------
__global__ __launch_bounds__(256) void k_gather(const float* __restrict__ linp,
                                                const uint2* __restrict__ edata,
                                                const int* __restrict__ off,
                                                const float* __restrict__ dinv,
                                                const float* __restrict__ bvec,
                                                float* __restrict__ agg) {
    int tid = threadIdx.x;
    int f = tid & 63;
    int n = blockIdx.x * 4 + (tid >> 6);
    float acc = linp[n * 64 + f];          // self term (linp = lin*dinv)
    int s = off[n], e1 = off[n + 1];
    int e = s;
    for (; e + 1 < e1; e += 2) {
        uint2 d0 = edata[e];
        uint2 d1 = edata[e + 1];
        float l0 = linp[(size_t)d0.x * 64 + f];
        float l1 = linp[(size_t)d1.x * 64 + f];
        acc = fmaf(__uint_as_float(d0.y), l0, acc);
        acc = fmaf(__uint_as_float(d1.y), l1, acc);
    }
    if (e < e1) {
        uint2 d0 = edata[e];
        acc = fmaf(__uint_as_float(d0.y), linp[(size_t)d0.x * 64 + f], acc);
    }
    agg[n * 64 + f] = dinv[n] * acc + bvec[f];
}

// ---------- LSTM weight fragment prep (bf16 hi/lo, MFMA B layout) ----------
__global__ __launch_bounds__(256) void k_wfrag(const float* __restrict__ W_ih,
                                               const float* __restrict__ W_hh,
                                               const float* __restrict__ b_ih,
                                               const float* __restrict__ b_hh,
                                               unsigned short* __restrict__ Bus,
                                               float* __restrict__ biasb) {
    int i = blockIdx.x * 256 + threadIdx.x;
    if (i < 192 * 512 * 2) {
        int j = i & 7;
        int l = (i >> 3) & 63;
        int ci = i >> 9;
        int hl = ci & 1;
        int ntg = (ci >> 1) & 31;
        int ks = ci >> 6;
        int col = ntg * 16 + (l & 15);
        int k = ks * 32 + ((l >> 4) << 3) + j;
        float w = (k < 64) ? W_ih[col * 64 + k] : W_hh[col * 128 + (k - 64)];
        float hi = bfval(w);
        Bus[i] = bfbits(hl ? (w - hi) : w);
    }
    if (i < 512) biasb[i] = b_ih[i] + b_hh[i];
}

// ---------- LSTM: MFMA bf16x3; per-wave B-slice register-resident across t ----------
__global__ __launch_bounds__(512, 2) void k_lstm(const float* __restrict__ seq,
                                                 const unsigned short* __restrict__ Bus,
                                                 const float* __restrict__ biasb,
                                                 float* __restrict__ hout) {
    __shared__ unsigned short Aus[12 * 512];   // 6 ks x hi/lo x 1KB
    int tid = threadIdx.x;
    int lane = tid & 63;
    int w = tid >> 6;
    int b0 = blockIdx.x * LROWS;

    int u = w * 16 + (lane & 15);
    int rbase = (lane >> 4) * 4;
    float bI = biasb[u], bF = biasb[128 + u], bG = biasb[256 + u], bO = biasb[384 + u];
    float cst[4] = {0.0f, 0.0f, 0.0f, 0.0f};

    // ---- load this wave's B slice into registers (once) ----
    short8 Bh[24], Bl[24];   // [ks*4+g]
    #pragma unroll
    for (int ks = 0; ks < 6; ++ks) {
        #pragma unroll
        for (int g = 0; g < 4; ++g) {
            size_t ci = (size_t)(ks * 32 + 8 * g + w) * 2;
            Bh[ks * 4 + g] = *(const short8*)&Bus[ci * 512 + lane * 8];
            Bl[ks * 4 + g] = *(const short8*)&Bus[(ci + 1) * 512 + lane * 8];
        }
    }

    // zero h region (chunks 4..11), stage seq t=0 (chunks 0..3)
    for (int i = tid; i < 2048; i += 512) ((unsigned int*)Aus)[2 * 512 + i] = 0;
    {
        int i0 = tid * 2;
        int row = i0 >> 6, k0 = i0 & 63;
        float2 v = *(const float2*)&seq[((size_t)(b0 + row) * NT + 0) * 64 + k0];
        float v0 = fmaxf(v.x, 0.0f), v1 = fmaxf(v.y, 0.0f);
        int ks = k0 >> 5, kr = k0 & 31;
        int idx = (ks * 2) * 512 + (((kr >> 3) << 4) + row) * 8 + (kr & 7);
        Aus[idx] = bfbits(v0);
        Aus[idx + 512] = bfbits(v0 - bfval(v0));
        kr = (k0 + 1) & 31; ks = (k0 + 1) >> 5;
        idx = (ks * 2) * 512 + (((kr >> 3) << 4) + row) * 8 + (kr & 7);
        Aus[idx] = bfbits(v1);
        Aus[idx + 512] = bfbits(v1 - bfval(v1));
    }
    __syncthreads();

    for (int t = 0; t < NT; ++t) {
        f32x4 acc[4];
        #pragma unroll
        for (int g = 0; g < 4; ++g) acc[g] = (f32x4){0.f, 0.f, 0.f, 0.f};
        #pragma unroll
        for (int ks = 0; ks < 6; ++ks) {
            short8 ah = *(const short8*)&Aus[(ks * 2 + 0) * 512 + lane * 8];
            short8 al = *(const short8*)&Aus[(ks * 2 + 1) * 512 + lane * 8];
            #pragma unroll
            for (int g = 0; g < 4; ++g)
                acc[g] = __builtin_amdgcn_mfma_f32_16x16x32_bf16(ah, Bh[ks * 4 + g], acc[g], 0, 0, 0);
            #pragma unroll
            for (int g = 0; g < 4; ++g)
                acc[g] = __builtin_amdgcn_mfma_f32_16x16x32_bf16(ah, Bl[ks * 4 + g], acc[g], 0, 0, 0);
            #pragma unroll
            for (int g = 0; g < 4; ++g)
                acc[g] = __builtin_amdgcn_mfma_f32_16x16x32_bf16(al, Bh[ks * 4 + g], acc[g], 0, 0, 0);
        }
        __syncthreads();   // all A reads of t complete

        if (t == NT - 1) {
            #pragma unroll
            for (int q = 0; q < 4; ++q) {
                float nc = sigm(acc[1][q] + bF) * cst[q]
                         + sigm(acc[0][q] + bI) * tanhf(acc[2][q] + bG);
                cst[q] = nc;
                float hv = sigm(acc[3][q] + bO) * tanhf(nc);
                hout[(size_t)(b0 + rbase + q) * 128 + u] = hv;
            }
        } else {
            int kh = 64 + u;
            int ksh = kh >> 5, krh = kh & 31;
            int hbase = (ksh * 2) * 512 + ((krh >> 3) << 4) * 8 + (krh & 7);
            #pragma unroll
            for (int q = 0; q < 4; ++q) {
                float nc = sigm(acc[1][q] + bF) * cst[q]
                         + sigm(acc[0][q] + bI) * tanhf(acc[2][q] + bG);
                cst[q] = nc;
                float hv = sigm(acc[3][q] + bO) * tanhf(nc);
                int idx = hbase + (rbase + q) * 8;
                Aus[idx] = bfbits(hv);
                Aus[idx + 512] = bfbits(hv - bfval(hv));
            }
            {
                int i0 = tid * 2;
                int row = i0 >> 6, k0 = i0 & 63;
                float2 v = *(const float2*)&seq[((size_t)(b0 + row) * NT + (t + 1)) * 64 + k0];
                float v0 = fmaxf(v.x, 0.0f), v1 = fmaxf(v.y, 0.0f);
                int ks = k0 >> 5, kr = k0 & 31;
                int idx = (ks * 2) * 512 + (((kr >> 3) << 4) + row) * 8 + (kr & 7);
                Aus[idx] = bfbits(v0);
                Aus[idx + 512] = bfbits(v0 - bfval(v0));
                kr = (k0 + 1) & 31; ks = (k0 + 1) >> 5;
                idx = (ks * 2) * 512 + (((kr >> 3) << 4) + row) * 8 + (kr & 7);
                Aus[idx] = bfbits(v1);
                Aus[idx + 512] = bfbits(v1 - bfval(v1));
            }
            __syncthreads();
        }
    }
}

// ---------- FC head + softmax: one wave per row ----------
__global__ __launch_bounds__(256) void k_fc(const float* __restrict__ h,
                                            const float* __restrict__ fw1,
                                            const float* __restrict__ fb1,
                                            const float* __restrict__ fw2,
                                            const float* __restrict__ fb2,
                                            float* __restrict__ out) {
    __shared__ float hid[4][64];
    int tid = threadIdx.x;
    int lane = tid & 63;
    int w = tid >> 6;
    int b = blockIdx.x * 4 + w;
    const float* hr = h + b * 128;
    float acc = fb1[lane];
    #pragma unroll 4
    for (int k = 0; k < 128; ++k) acc = fmaf(hr[k], fw1[k * 64 + lane], acc);
    hid[w][lane] = fmaxf(acc, 0.0f);
    __syncthreads();
    if (lane == 0) {
        float lg[3];
        #pragma unroll
        for (int l = 0; l < 3; ++l) {
            float a = fb2[l];
            for (int j = 0; j < 64; ++j) a = fmaf(hid[w][j], fw2[j * 3 + l], a);
            lg[l] = a;
        }
        float m = fmaxf(lg[0], fmaxf(lg[1], lg[2]));
        float e0 = expf(lg[0] - m), e1 = expf(lg[1] - m), e2 = expf(lg[2] - m);
        float s = 1.0f / (e0 + e1 + e2);
        out[b * 3 + 0] = e0 * s;
        out[b * 3 + 1] = e1 * s;
        out[b * 3 + 2] = e2 * s;
    }
}

extern "C" void kernel_launch(void* const* d_in, const int* in_sizes, int n_in,
                              void* d_out, int out_size, void* d_ws, size_t ws_size,
                              hipStream_t stream) {
    const float* x    = (const float*)d_in[0];
    const float* ea   = (const float*)d_in[1];
    const float* W1   = (const float*)d_in[2];
    const float* b1   = (const float*)d_in[3];
    const float* W2   = (const float*)d_in[4];
    const float* b2   = (const float*)d_in[5];
    const float* W_ih = (const float*)d_in[6];
    const float* W_hh = (const float*)d_in[7];
    const float* b_ih = (const float*)d_in[8];
    const float* b_hh = (const float*)d_in[9];
    const float* fw1  = (const float*)d_in[10];
    const float* fb1  = (const float*)d_in[11];
    const float* fw2  = (const float*)d_in[12];
    const float* fb2  = (const float*)d_in[13];
    const int*   ei   = (const int*)d_in[14];
    float* out = (float*)d_out;

    float* ws    = (float*)d_ws;
    float* dinv  = ws;                          // NN
    float* bufA  = dinv + NN;                   // NN*64  (aliased as `binned` during CSR build)
    float* bufB  = bufA + NN * 64;              // NN*64
    unsigned short* Bus = (unsigned short*)(bufB + NN * 64);   // 196608 ushort
    float* biasb = bufB + NN * 64 + 98304;      // 512
    float* hbuf  = biasb + 512;                 // NB*128
    int*   bcnt  = (int*)(hbuf + NB * 128);     // 256
    int*   bbase = bcnt + 256;                  // 256
    int*   bcur  = bbase + 256;                 // 256
    int*   off   = bcur + 256;                  // NN+1
    uint2* edata = (uint2*)(off + NN + 1);      // NE * 8B
    uint2* binned = (uint2*)bufA;               // NE * 8B (dead before k_lin L1)

    // ---- CSR build via two-level counting sort (deg folded into P2) ----
    k_zero256<<<1, 256, 0, stream>>>(bcnt);
    k_bhist<<<NBKT, 256, 0, stream>>>(ei, bcnt);
    k_bscan<<<1, 256, 0, stream>>>(bcnt, bbase, bcur);
    k_bin<<<NBKT, 256, 0, stream>>>(ei, ea, bcur, binned);
    k_csr<<<NBKT, 256, 0, stream>>>(binned, bbase, edata, off, dinv);

    // LSTM weight fragments
    k_wfrag<<<768, 256, 0, stream>>>(W_ih, W_hh, b_ih, b_hh, Bus, biasb);

    // GCN layer 1 (dinv folded into lin output)
    k_lin<16, false><<<16000, 256, 0, stream>>>(x, W1, dinv, bufA);
    k_gather<<<16000, 256, 0, stream>>>(bufA, edata, off, dinv, b1, bufB);

    // GCN layer 2 (relu fused into k_lin read)
    k_lin<64, true><<<16000, 256, 0, stream>>>(bufB, W2, dinv, bufA);
    k_gather<<<16000, 256, 0, stream>>>(bufA, edata, off, dinv, b2, bufB);

    // LSTM (relu fused into staging)
    k_lstm<<<250, 512, 0, stream>>>(bufB, Bus, biasb, hbuf);

    // FC head + softmax
    k_fc<<<1000, 256, 0, stream>>>(hbuf, fw1, fb1, fw2, fb2, out);
}

// Round 10
// 262.421 us; speedup vs baseline: 7.4670x; 1.1454x over previous
//
#include <hip/hip_runtime.h>
#include <hip/hip_bf16.h>
#include <hip/hip_fp16.h>
#include <math.h>

#define NN 64000      // nodes
#define NE 1024000    // edges
#define NB 4000       // sequences
#define NT 16         // timesteps
#define LROWS 16      // sequences per LSTM block
#define NBKT 250      // coarse buckets (c>>8), NN/256

typedef __attribute__((ext_vector_type(8))) short short8;
typedef __attribute__((ext_vector_type(4))) float f32x4;

__device__ __forceinline__ float sigm(float x) { return 1.0f / (1.0f + expf(-x)); }
__device__ __forceinline__ unsigned short bfbits(float v) {
    __hip_bfloat16 h = __float2bfloat16(v);
    return reinterpret_cast<unsigned short&>(h);
}
__device__ __forceinline__ float bfval(float v) {
    return __bfloat162float(__float2bfloat16(v));
}

// ---------- zero the bucket counters ----------
__global__ __launch_bounds__(256) void k_zero256(int* __restrict__ p) {
    p[threadIdx.x] = 0;
}

// ---------- P0: coarse bucket histogram (LDS-privatized) ----------
__global__ __launch_bounds__(256) void k_bhist(const int* __restrict__ ei,
                                               int* __restrict__ bcnt) {
    __shared__ int h[256];
    int tid = threadIdx.x;
    h[tid] = 0;
    __syncthreads();
    int base = blockIdx.x * 4096;
    #pragma unroll
    for (int j = 0; j < 16; ++j) {
        int c = ei[NE + base + j * 256 + tid];
        atomicAdd(&h[c >> 8], 1);
    }
    __syncthreads();
    if (tid < NBKT && h[tid]) atomicAdd(&bcnt[tid], h[tid]);
}

// ---------- scan 250 bucket counts -> bbase[251]; cursor copy ----------
__global__ __launch_bounds__(256) void k_bscan(const int* __restrict__ bcnt,
                                               int* __restrict__ bbase,
                                               int* __restrict__ bcur) {
    __shared__ int sm[256];
    int tid = threadIdx.x;
    int v = (tid < NBKT) ? bcnt[tid] : 0;
    sm[tid] = v;
    __syncthreads();
    #pragma unroll
    for (int d = 1; d < 256; d <<= 1) {
        int t = (tid >= d) ? sm[tid - d] : 0;
        __syncthreads();
        sm[tid] += t;
        __syncthreads();
    }
    if (tid < NBKT) { int ex = sm[tid] - v; bbase[tid] = ex; bcur[tid] = ex; }
    if (tid == 255) bbase[NBKT] = sm[255];   // = NE
}

// ---------- P1: bin edges by bucket via LDS sort; coalesced run writes ----------
// record: x = r | (c&255)<<16 | bucket<<24 ; y = raw ew bits
__global__ __launch_bounds__(256) void k_bin(const int* __restrict__ ei,
                                             const float* __restrict__ ew,
                                             int* __restrict__ bcur,
                                             uint2* __restrict__ binned) {
    __shared__ uint2 stage[4096];
    __shared__ int sm[256];
    __shared__ int lofs[256], lcur[256], ladj[256];
    int tid = threadIdx.x;
    sm[tid] = 0;
    __syncthreads();
    int base = blockIdx.x * 4096;
    int cs[16];
    #pragma unroll
    for (int j = 0; j < 16; ++j) {
        cs[j] = ei[NE + base + j * 256 + tid];
        atomicAdd(&sm[cs[j] >> 8], 1);
    }
    __syncthreads();
    int v = sm[tid];
    #pragma unroll
    for (int d = 1; d < 256; d <<= 1) {
        int t = (tid >= d) ? sm[tid - d] : 0;
        __syncthreads();
        sm[tid] += t;
        __syncthreads();
    }
    int ex = sm[tid] - v;
    lofs[tid] = ex;
    lcur[tid] = ex;
    if (tid < NBKT) ladj[tid] = atomicAdd(&bcur[tid], v) - ex;
    __syncthreads();
    #pragma unroll
    for (int j = 0; j < 16; ++j) {
        int e = base + j * 256 + tid;
        int c = cs[j];
        int b = c >> 8;
        unsigned r = (unsigned)ei[e];
        float wv = ew[e];
        int slot = atomicAdd(&lcur[b], 1);
        stage[slot] = make_uint2(r | ((unsigned)(c & 255) << 16) | ((unsigned)b << 24),
                                 __float_as_uint(wv));
    }
    __syncthreads();
    #pragma unroll
    for (int j = 0; j < 16; ++j) {
        int i = j * 256 + tid;
        uint2 rec = stage[i];
        int b = rec.x >> 24;
        binned[ladj[b] + i] = rec;
    }
}

// ---------- P2: per-bucket final CSR sort + off[] + dinv (deg folded) ----------
__global__ __launch_bounds__(256) void k_csr(const uint2* __restrict__ binned,
                                             const int* __restrict__ bbase,
                                             uint2* __restrict__ edata,
                                             int* __restrict__ off,
                                             float* __restrict__ dinv) {
    __shared__ int cnt[256];
    __shared__ float sumw[256];
    __shared__ int lcur[256];
    __shared__ int sm[256];
    int tid = threadIdx.x;
    int b = blockIdx.x;
    int s = bbase[b], e1 = bbase[b + 1];
    cnt[tid] = 0;
    sumw[tid] = 0.0f;
    __syncthreads();
    for (int i = s + tid; i < e1; i += 256) {
        uint2 rec = binned[i];
        int nl = (rec.x >> 16) & 255;
        atomicAdd(&cnt[nl], 1);
        atomicAdd(&sumw[nl], __uint_as_float(rec.y));
    }
    __syncthreads();
    int v = cnt[tid];
    sm[tid] = v;
    __syncthreads();
    #pragma unroll
    for (int d = 1; d < 256; d <<= 1) {
        int t = (tid >= d) ? sm[tid - d] : 0;
        __syncthreads();
        sm[tid] += t;
        __syncthreads();
    }
    int ex = sm[tid] - v;
    off[b * 256 + tid] = s + ex;
    dinv[b * 256 + tid] = rsqrtf(1.0f + sumw[tid]);
    lcur[tid] = ex;
    if (b == 0 && tid == 0) off[NN] = NE;
    __syncthreads();
    for (int i = s + tid; i < e1; i += 256) {
        uint2 rec = binned[i];
        int nl = (rec.x >> 16) & 255;
        int p = atomicAdd(&lcur[nl], 1);
        edata[s + p] = make_uint2(rec.x & 0xFFFFu, rec.y);
    }
}

// ---------- node linear (+dinv fold), fp16 output: Y = ((relu?)X @ W) * dinv ----------
template<int K, bool RELU_IN>
__global__ __launch_bounds__(256) void k_lin(const float* __restrict__ X,
                                             const float* __restrict__ W,
                                             const float* __restrict__ dinv,
                                             __half* __restrict__ Y) {
    __shared__ float Wl[K * 64];
    __shared__ float Xl[4][K];
    int tid = threadIdx.x;
    for (int i = tid; i < K * 64; i += 256) Wl[i] = W[i];
    int n0 = blockIdx.x * 4;
    for (int i = tid; i < 4 * K; i += 256) {
        int r = i / K, d = i % K;
        float v = X[(n0 + r) * K + d];
        Xl[r][d] = RELU_IN ? fmaxf(v, 0.0f) : v;
    }
    __syncthreads();
    int r = tid >> 6, f = tid & 63;
    float acc = 0.0f;
    #pragma unroll
    for (int d = 0; d < K; ++d) acc = fmaf(Xl[r][d], Wl[d * 64 + f], acc);
    Y[(n0 + r) * 64 + f] = __float2half(acc * dinv[n0 + r]);
}

// ---------- CSR gather (fp16 rows): agg = dinv[n]*(linp[n] + sum ew*linp[r]) + b ----------
__global__ __launch_bounds__(256) void k_gather(const __half* __restrict__ linp,
                                                const uint2* __restrict__ edata,
                                                const int* __restrict__ off,
                                                const float* __restrict__ dinv,
                                                const float* __restrict__ bvec,
                                                float* __restrict__ agg) {
    int tid = threadIdx.x;
    int f = tid & 63;
    int n = blockIdx.x * 4 + (tid >> 6);
    float acc = __half2float(linp[((size_t)n << 6) + f]);   // self term (linp = lin*dinv)
    int s = off[n], e1 = off[n + 1];
    int e = s;
    for (; e + 3 < e1; e += 4) {
        uint2 d0 = edata[e];
        uint2 d1 = edata[e + 1];
        uint2 d2 = edata[e + 2];
        uint2 d3 = edata[e + 3];
        float l0 = __half2float(linp[((size_t)d0.x << 6) + f]);
        float l1 = __half2float(linp[((size_t)d1.x << 6) + f]);
        float l2 = __half2float(linp[((size_t)d2.x << 6) + f]);
        float l3 = __half2float(linp[((size_t)d3.x << 6) + f]);
        acc = fmaf(__uint_as_float(d0.y), l0, acc);
        acc = fmaf(__uint_as_float(d1.y), l1, acc);
        acc = fmaf(__uint_as_float(d2.y), l2, acc);
        acc = fmaf(__uint_as_float(d3.y), l3, acc);
    }
    for (; e < e1; ++e) {
        uint2 d0 = edata[e];
        acc = fmaf(__uint_as_float(d0.y), __half2float(linp[((size_t)d0.x << 6) + f]), acc);
    }
    agg[((size_t)n << 6) + f] = dinv[n] * acc + bvec[f];
}

// ---------- LSTM weight fragment prep (bf16 hi/lo, MFMA B layout) ----------
__global__ __launch_bounds__(256) void k_wfrag(const float* __restrict__ W_ih,
                                               const float* __restrict__ W_hh,
                                               const float* __restrict__ b_ih,
                                               const float* __restrict__ b_hh,
                                               unsigned short* __restrict__ Bus,
                                               float* __restrict__ biasb) {
    int i = blockIdx.x * 256 + threadIdx.x;
    if (i < 192 * 512 * 2) {
        int j = i & 7;
        int l = (i >> 3) & 63;
        int ci = i >> 9;
        int hl = ci & 1;
        int ntg = (ci >> 1) & 31;
        int ks = ci >> 6;
        int col = ntg * 16 + (l & 15);
        int k = ks * 32 + ((l >> 4) << 3) + j;
        float w = (k < 64) ? W_ih[col * 64 + k] : W_hh[col * 128 + (k - 64)];
        float hi = bfval(w);
        Bus[i] = bfbits(hl ? (w - hi) : w);
    }
    if (i < 512) biasb[i] = b_ih[i] + b_hh[i];
}

// ---------- LSTM: MFMA bf16x3; per-wave B-slice register-resident across t ----------
__global__ __launch_bounds__(512, 2) void k_lstm(const float* __restrict__ seq,
                                                 const unsigned short* __restrict__ Bus,
                                                 const float* __restrict__ biasb,
                                                 float* __restrict__ hout) {
    __shared__ unsigned short Aus[12 * 512];   // 6 ks x hi/lo x 1KB
    int tid = threadIdx.x;
    int lane = tid & 63;
    int w = tid >> 6;
    int b0 = blockIdx.x * LROWS;

    int u = w * 16 + (lane & 15);
    int rbase = (lane >> 4) * 4;
    float bI = biasb[u], bF = biasb[128 + u], bG = biasb[256 + u], bO = biasb[384 + u];
    float cst[4] = {0.0f, 0.0f, 0.0f, 0.0f};

    // ---- load this wave's B slice into registers (once) ----
    short8 Bh[24], Bl[24];   // [ks*4+g]
    #pragma unroll
    for (int ks = 0; ks < 6; ++ks) {
        #pragma unroll
        for (int g = 0; g < 4; ++g) {
            size_t ci = (size_t)(ks * 32 + 8 * g + w) * 2;
            Bh[ks * 4 + g] = *(const short8*)&Bus[ci * 512 + lane * 8];
            Bl[ks * 4 + g] = *(const short8*)&Bus[(ci + 1) * 512 + lane * 8];
        }
    }

    // zero h region (chunks 4..11), stage seq t=0 (chunks 0..3)
    for (int i = tid; i < 2048; i += 512) ((unsigned int*)Aus)[2 * 512 + i] = 0;
    {
        int i0 = tid * 2;
        int row = i0 >> 6, k0 = i0 & 63;
        float2 v = *(const float2*)&seq[((size_t)(b0 + row) * NT + 0) * 64 + k0];
        float v0 = fmaxf(v.x, 0.0f), v1 = fmaxf(v.y, 0.0f);
        int ks = k0 >> 5, kr = k0 & 31;
        int idx = (ks * 2) * 512 + (((kr >> 3) << 4) + row) * 8 + (kr & 7);
        Aus[idx] = bfbits(v0);
        Aus[idx + 512] = bfbits(v0 - bfval(v0));
        kr = (k0 + 1) & 31; ks = (k0 + 1) >> 5;
        idx = (ks * 2) * 512 + (((kr >> 3) << 4) + row) * 8 + (kr & 7);
        Aus[idx] = bfbits(v1);
        Aus[idx + 512] = bfbits(v1 - bfval(v1));
    }
    __syncthreads();

    for (int t = 0; t < NT; ++t) {
        f32x4 acc[4];
        #pragma unroll
        for (int g = 0; g < 4; ++g) acc[g] = (f32x4){0.f, 0.f, 0.f, 0.f};
        #pragma unroll
        for (int ks = 0; ks < 6; ++ks) {
            short8 ah = *(const short8*)&Aus[(ks * 2 + 0) * 512 + lane * 8];
            short8 al = *(const short8*)&Aus[(ks * 2 + 1) * 512 + lane * 8];
            #pragma unroll
            for (int g = 0; g < 4; ++g)
                acc[g] = __builtin_amdgcn_mfma_f32_16x16x32_bf16(ah, Bh[ks * 4 + g], acc[g], 0, 0, 0);
            #pragma unroll
            for (int g = 0; g < 4; ++g)
                acc[g] = __builtin_amdgcn_mfma_f32_16x16x32_bf16(ah, Bl[ks * 4 + g], acc[g], 0, 0, 0);
            #pragma unroll
            for (int g = 0; g < 4; ++g)
                acc[g] = __builtin_amdgcn_mfma_f32_16x16x32_bf16(al, Bh[ks * 4 + g], acc[g], 0, 0, 0);
        }
        __syncthreads();   // all A reads of t complete

        if (t == NT - 1) {
            #pragma unroll
            for (int q = 0; q < 4; ++q) {
                float nc = sigm(acc[1][q] + bF) * cst[q]
                         + sigm(acc[0][q] + bI) * tanhf(acc[2][q] + bG);
                cst[q] = nc;
                float hv = sigm(acc[3][q] + bO) * tanhf(nc);
                hout[(size_t)(b0 + rbase + q) * 128 + u] = hv;
            }
        } else {
            int kh = 64 + u;
            int ksh = kh >> 5, krh = kh & 31;
            int hbase = (ksh * 2) * 512 + ((krh >> 3) << 4) * 8 + (krh & 7);
            #pragma unroll
            for (int q = 0; q < 4; ++q) {
                float nc = sigm(acc[1][q] + bF) * cst[q]
                         + sigm(acc[0][q] + bI) * tanhf(acc[2][q] + bG);
                cst[q] = nc;
                float hv = sigm(acc[3][q] + bO) * tanhf(nc);
                int idx = hbase + (rbase + q) * 8;
                Aus[idx] = bfbits(hv);
                Aus[idx + 512] = bfbits(hv - bfval(hv));
            }
            {
                int i0 = tid * 2;
                int row = i0 >> 6, k0 = i0 & 63;
                float2 v = *(const float2*)&seq[((size_t)(b0 + row) * NT + (t + 1)) * 64 + k0];
                float v0 = fmaxf(v.x, 0.0f), v1 = fmaxf(v.y, 0.0f);
                int ks = k0 >> 5, kr = k0 & 31;
                int idx = (ks * 2) * 512 + (((kr >> 3) << 4) + row) * 8 + (kr & 7);
                Aus[idx] = bfbits(v0);
                Aus[idx + 512] = bfbits(v0 - bfval(v0));
                kr = (k0 + 1) & 31; ks = (k0 + 1) >> 5;
                idx = (ks * 2) * 512 + (((kr >> 3) << 4) + row) * 8 + (kr & 7);
                Aus[idx] = bfbits(v1);
                Aus[idx + 512] = bfbits(v1 - bfval(v1));
            }
            __syncthreads();
        }
    }
}

// ---------- FC head + softmax: one wave per row ----------
__global__ __launch_bounds__(256) void k_fc(const float* __restrict__ h,
                                            const float* __restrict__ fw1,
                                            const float* __restrict__ fb1,
                                            const float* __restrict__ fw2,
                                            const float* __restrict__ fb2,
                                            float* __restrict__ out) {
    __shared__ float hid[4][64];
    int tid = threadIdx.x;
    int lane = tid & 63;
    int w = tid >> 6;
    int b = blockIdx.x * 4 + w;
    const float* hr = h + b * 128;
    float acc = fb1[lane];
    #pragma unroll 4
    for (int k = 0; k < 128; ++k) acc = fmaf(hr[k], fw1[k * 64 + lane], acc);
    hid[w][lane] = fmaxf(acc, 0.0f);
    __syncthreads();
    if (lane == 0) {
        float lg[3];
        #pragma unroll
        for (int l = 0; l < 3; ++l) {
            float a = fb2[l];
            for (int j = 0; j < 64; ++j) a = fmaf(hid[w][j], fw2[j * 3 + l], a);
            lg[l] = a;
        }
        float m = fmaxf(lg[0], fmaxf(lg[1], lg[2]));
        float e0 = expf(lg[0] - m), e1 = expf(lg[1] - m), e2 = expf(lg[2] - m);
        float s = 1.0f / (e0 + e1 + e2);
        out[b * 3 + 0] = e0 * s;
        out[b * 3 + 1] = e1 * s;
        out[b * 3 + 2] = e2 * s;
    }
}

extern "C" void kernel_launch(void* const* d_in, const int* in_sizes, int n_in,
                              void* d_out, int out_size, void* d_ws, size_t ws_size,
                              hipStream_t stream) {
    const float* x    = (const float*)d_in[0];
    const float* ea   = (const float*)d_in[1];
    const float* W1   = (const float*)d_in[2];
    const float* b1   = (const float*)d_in[3];
    const float* W2   = (const float*)d_in[4];
    const float* b2   = (const float*)d_in[5];
    const float* W_ih = (const float*)d_in[6];
    const float* W_hh = (const float*)d_in[7];
    const float* b_ih = (const float*)d_in[8];
    const float* b_hh = (const float*)d_in[9];
    const float* fw1  = (const float*)d_in[10];
    const float* fb1  = (const float*)d_in[11];
    const float* fw2  = (const float*)d_in[12];
    const float* fb2  = (const float*)d_in[13];
    const int*   ei   = (const int*)d_in[14];
    float* out = (float*)d_out;

    float* ws    = (float*)d_ws;
    float* dinv  = ws;                          // NN
    float* bufA  = dinv + NN;                   // NN*64 fp32 region (reused: binned, fp16 linp)
    float* bufB  = bufA + NN * 64;              // NN*64 fp32
    unsigned short* Bus = (unsigned short*)(bufB + NN * 64);   // 196608 ushort
    float* biasb = bufB + NN * 64 + 98304;      // 512
    float* hbuf  = biasb + 512;                 // NB*128
    int*   bcnt  = (int*)(hbuf + NB * 128);     // 256
    int*   bbase = bcnt + 256;                  // 256
    int*   bcur  = bbase + 256;                 // 256
    int*   off   = bcur + 256;                  // NN+4 (padded for edata alignment)
    uint2* edata = (uint2*)(off + NN + 4);      // NE * 8B (16B-aligned)
    uint2* binned = (uint2*)bufA;               // NE * 8B (dead before k_lin L1)
    __half* linp  = (__half*)bufA;              // NN*64 fp16 (after binned is dead)

    // ---- CSR build via two-level counting sort (deg folded into P2) ----
    k_zero256<<<1, 256, 0, stream>>>(bcnt);
    k_bhist<<<NBKT, 256, 0, stream>>>(ei, bcnt);
    k_bscan<<<1, 256, 0, stream>>>(bcnt, bbase, bcur);
    k_bin<<<NBKT, 256, 0, stream>>>(ei, ea, bcur, binned);
    k_csr<<<NBKT, 256, 0, stream>>>(binned, bbase, edata, off, dinv);

    // LSTM weight fragments
    k_wfrag<<<768, 256, 0, stream>>>(W_ih, W_hh, b_ih, b_hh, Bus, biasb);

    // GCN layer 1 (dinv folded into fp16 lin output)
    k_lin<16, false><<<16000, 256, 0, stream>>>(x, W1, dinv, linp);
    k_gather<<<16000, 256, 0, stream>>>(linp, edata, off, dinv, b1, bufB);

    // GCN layer 2 (relu fused into k_lin read; fp16 linp overwrites dead layer-1 copy)
    k_lin<64, true><<<16000, 256, 0, stream>>>(bufB, W2, dinv, linp);
    k_gather<<<16000, 256, 0, stream>>>(linp, edata, off, dinv, b2, bufB);

    // LSTM (relu fused into staging)
    k_lstm<<<250, 512, 0, stream>>>(bufB, Bus, biasb, hbuf);

    // FC head + softmax
    k_fc<<<1000, 256, 0, stream>>>(hbuf, fw1, fb1, fw2, fb2, out);
}

// Round 11
// 230.364 us; speedup vs baseline: 8.5061x; 1.1392x over previous
//
#include <hip/hip_runtime.h>
#include <hip/hip_bf16.h>
#include <hip/hip_fp16.h>
#include <math.h>

#define NN 64000      // nodes
#define NE 1024000    // edges
#define NB 4000       // sequences
#define NT 16         // timesteps
#define LROWS 16      // sequences per LSTM block
#define NBKT 250      // coarse buckets (c>>8), NN/256

typedef __attribute__((ext_vector_type(8))) short short8;
typedef __attribute__((ext_vector_type(4))) float f32x4;

// fast sigmoid/tanh: v_exp + v_rcp (exact at +-inf limits)
__device__ __forceinline__ float fsigm(float x) {
    return __builtin_amdgcn_rcpf(1.0f + __expf(-x));
}
__device__ __forceinline__ float ftanh(float x) {
    return 1.0f - 2.0f * __builtin_amdgcn_rcpf(1.0f + __expf(2.0f * x));
}
__device__ __forceinline__ unsigned short hbits(float v) {
    __half h = __float2half(v);
    return reinterpret_cast<unsigned short&>(h);
}

// ---------- zero the bucket counters ----------
__global__ __launch_bounds__(256) void k_zero256(int* __restrict__ p) {
    p[threadIdx.x] = 0;
}

// ---------- P0: coarse bucket histogram (LDS-privatized) ----------
__global__ __launch_bounds__(256) void k_bhist(const int* __restrict__ ei,
                                               int* __restrict__ bcnt) {
    __shared__ int h[256];
    int tid = threadIdx.x;
    h[tid] = 0;
    __syncthreads();
    int base = blockIdx.x * 4096;
    #pragma unroll
    for (int j = 0; j < 16; ++j) {
        int c = ei[NE + base + j * 256 + tid];
        atomicAdd(&h[c >> 8], 1);
    }
    __syncthreads();
    if (tid < NBKT && h[tid]) atomicAdd(&bcnt[tid], h[tid]);
}

// ---------- scan 250 bucket counts -> bbase[251]; cursor copy ----------
__global__ __launch_bounds__(256) void k_bscan(const int* __restrict__ bcnt,
                                               int* __restrict__ bbase,
                                               int* __restrict__ bcur) {
    __shared__ int sm[256];
    int tid = threadIdx.x;
    int v = (tid < NBKT) ? bcnt[tid] : 0;
    sm[tid] = v;
    __syncthreads();
    #pragma unroll
    for (int d = 1; d < 256; d <<= 1) {
        int t = (tid >= d) ? sm[tid - d] : 0;
        __syncthreads();
        sm[tid] += t;
        __syncthreads();
    }
    if (tid < NBKT) { int ex = sm[tid] - v; bbase[tid] = ex; bcur[tid] = ex; }
    if (tid == 255) bbase[NBKT] = sm[255];   // = NE
}

// ---------- P1: bin edges by bucket via LDS sort; coalesced run writes ----------
// record: x = r | (c&255)<<16 | bucket<<24 ; y = raw ew bits
__global__ __launch_bounds__(256) void k_bin(const int* __restrict__ ei,
                                             const float* __restrict__ ew,
                                             int* __restrict__ bcur,
                                             uint2* __restrict__ binned) {
    __shared__ uint2 stage[4096];
    __shared__ int sm[256];
    __shared__ int lofs[256], lcur[256], ladj[256];
    int tid = threadIdx.x;
    sm[tid] = 0;
    __syncthreads();
    int base = blockIdx.x * 4096;
    int cs[16];
    #pragma unroll
    for (int j = 0; j < 16; ++j) {
        cs[j] = ei[NE + base + j * 256 + tid];
        atomicAdd(&sm[cs[j] >> 8], 1);
    }
    __syncthreads();
    int v = sm[tid];
    #pragma unroll
    for (int d = 1; d < 256; d <<= 1) {
        int t = (tid >= d) ? sm[tid - d] : 0;
        __syncthreads();
        sm[tid] += t;
        __syncthreads();
    }
    int ex = sm[tid] - v;
    lofs[tid] = ex;
    lcur[tid] = ex;
    if (tid < NBKT) ladj[tid] = atomicAdd(&bcur[tid], v) - ex;
    __syncthreads();
    #pragma unroll
    for (int j = 0; j < 16; ++j) {
        int e = base + j * 256 + tid;
        int c = cs[j];
        int b = c >> 8;
        unsigned r = (unsigned)ei[e];
        float wv = ew[e];
        int slot = atomicAdd(&lcur[b], 1);
        stage[slot] = make_uint2(r | ((unsigned)(c & 255) << 16) | ((unsigned)b << 24),
                                 __float_as_uint(wv));
    }
    __syncthreads();
    #pragma unroll
    for (int j = 0; j < 16; ++j) {
        int i = j * 256 + tid;
        uint2 rec = stage[i];
        int b = rec.x >> 24;
        binned[ladj[b] + i] = rec;
    }
}

// ---------- P2: per-bucket final CSR sort + off[] + dinv (deg folded) ----------
__global__ __launch_bounds__(256) void k_csr(const uint2* __restrict__ binned,
                                             const int* __restrict__ bbase,
                                             uint2* __restrict__ edata,
                                             int* __restrict__ off,
                                             float* __restrict__ dinv) {
    __shared__ int cnt[256];
    __shared__ float sumw[256];
    __shared__ int lcur[256];
    __shared__ int sm[256];
    int tid = threadIdx.x;
    int b = blockIdx.x;
    int s = bbase[b], e1 = bbase[b + 1];
    cnt[tid] = 0;
    sumw[tid] = 0.0f;
    __syncthreads();
    for (int i = s + tid; i < e1; i += 256) {
        uint2 rec = binned[i];
        int nl = (rec.x >> 16) & 255;
        atomicAdd(&cnt[nl], 1);
        atomicAdd(&sumw[nl], __uint_as_float(rec.y));
    }
    __syncthreads();
    int v = cnt[tid];
    sm[tid] = v;
    __syncthreads();
    #pragma unroll
    for (int d = 1; d < 256; d <<= 1) {
        int t = (tid >= d) ? sm[tid - d] : 0;
        __syncthreads();
        sm[tid] += t;
        __syncthreads();
    }
    int ex = sm[tid] - v;
    off[b * 256 + tid] = s + ex;
    dinv[b * 256 + tid] = rsqrtf(1.0f + sumw[tid]);
    lcur[tid] = ex;
    if (b == 0 && tid == 0) off[NN] = NE;
    __syncthreads();
    for (int i = s + tid; i < e1; i += 256) {
        uint2 rec = binned[i];
        int nl = (rec.x >> 16) & 255;
        int p = atomicAdd(&lcur[nl], 1);
        edata[s + p] = make_uint2(rec.x & 0xFFFFu, rec.y);
    }
}

// ---------- node linear (+dinv fold), fp16 output: Y = ((relu?)X @ W) * dinv ----------
template<int K, bool RELU_IN>
__global__ __launch_bounds__(256) void k_lin(const float* __restrict__ X,
                                             const float* __restrict__ W,
                                             const float* __restrict__ dinv,
                                             __half* __restrict__ Y) {
    __shared__ float Wl[K * 64];
    __shared__ float Xl[4][K];
    int tid = threadIdx.x;
    for (int i = tid; i < K * 64; i += 256) Wl[i] = W[i];
    int n0 = blockIdx.x * 4;
    for (int i = tid; i < 4 * K; i += 256) {
        int r = i / K, d = i % K;
        float v = X[(n0 + r) * K + d];
        Xl[r][d] = RELU_IN ? fmaxf(v, 0.0f) : v;
    }
    __syncthreads();
    int r = tid >> 6, f = tid & 63;
    float acc = 0.0f;
    #pragma unroll
    for (int d = 0; d < K; ++d) acc = fmaf(Xl[r][d], Wl[d * 64 + f], acc);
    Y[(n0 + r) * 64 + f] = __float2half(acc * dinv[n0 + r]);
}

// ---------- CSR gather (fp16 rows): agg = dinv[n]*(linp[n] + sum ew*linp[r]) + b ----------
__global__ __launch_bounds__(256) void k_gather(const __half* __restrict__ linp,
                                                const uint2* __restrict__ edata,
                                                const int* __restrict__ off,
                                                const float* __restrict__ dinv,
                                                const float* __restrict__ bvec,
                                                float* __restrict__ agg) {
    int tid = threadIdx.x;
    int f = tid & 63;
    int n = blockIdx.x * 4 + (tid >> 6);
    float acc = __half2float(linp[((size_t)n << 6) + f]);   // self term (linp = lin*dinv)
    int s = off[n], e1 = off[n + 1];
    int e = s;
    for (; e + 3 < e1; e += 4) {
        uint2 d0 = edata[e];
        uint2 d1 = edata[e + 1];
        uint2 d2 = edata[e + 2];
        uint2 d3 = edata[e + 3];
        float l0 = __half2float(linp[((size_t)d0.x << 6) + f]);
        float l1 = __half2float(linp[((size_t)d1.x << 6) + f]);
        float l2 = __half2float(linp[((size_t)d2.x << 6) + f]);
        float l3 = __half2float(linp[((size_t)d3.x << 6) + f]);
        acc = fmaf(__uint_as_float(d0.y), l0, acc);
        acc = fmaf(__uint_as_float(d1.y), l1, acc);
        acc = fmaf(__uint_as_float(d2.y), l2, acc);
        acc = fmaf(__uint_as_float(d3.y), l3, acc);
    }
    for (; e < e1; ++e) {
        uint2 d0 = edata[e];
        acc = fmaf(__uint_as_float(d0.y), __half2float(linp[((size_t)d0.x << 6) + f]), acc);
    }
    agg[((size_t)n << 6) + f] = dinv[n] * acc + bvec[f];
}

// ---------- LSTM weight fragment prep (single f16, MFMA B layout) ----------
// chunk ci = ks*32+ntg, 1KB: lane l, elem j -> col = ntg*16+(l&15), k = ks*32+(l>>4)*8+j
__global__ __launch_bounds__(256) void k_wfrag(const float* __restrict__ W_ih,
                                               const float* __restrict__ W_hh,
                                               const float* __restrict__ b_ih,
                                               const float* __restrict__ b_hh,
                                               unsigned short* __restrict__ Bus,
                                               float* __restrict__ biasb) {
    int i = blockIdx.x * 256 + threadIdx.x;
    if (i < 192 * 512) {
        int j = i & 7;
        int l = (i >> 3) & 63;
        int ci = i >> 9;
        int ntg = ci & 31;
        int ks = ci >> 5;
        int col = ntg * 16 + (l & 15);
        int k = ks * 32 + ((l >> 4) << 3) + j;
        float w = (k < 64) ? W_ih[col * 64 + k] : W_hh[col * 128 + (k - 64)];
        Bus[i] = hbits(w);
    }
    if (i < 512) biasb[i] = b_ih[i] + b_hh[i];
}

// ---------- LSTM: single-product f16 MFMA; B-slice register-resident (96 VGPR) ----------
// Wave w owns units u = w*16+(lane&15) across all 4 gates (B chunks ntg=8g+w).
__global__ __launch_bounds__(512, 2) void k_lstm(const float* __restrict__ seq,
                                                 const unsigned short* __restrict__ Bus,
                                                 const float* __restrict__ biasb,
                                                 float* __restrict__ hout) {
    __shared__ unsigned short Aus[6 * 512];   // 6 ks x 1KB (f16)
    int tid = threadIdx.x;
    int lane = tid & 63;
    int w = tid >> 6;
    int b0 = blockIdx.x * LROWS;

    int u = w * 16 + (lane & 15);
    int rbase = (lane >> 4) * 4;
    float bI = biasb[u], bF = biasb[128 + u], bG = biasb[256 + u], bO = biasb[384 + u];
    float cst[4] = {0.0f, 0.0f, 0.0f, 0.0f};

    // ---- load this wave's B slice into registers (once): 24 x short8 = 96 VGPR ----
    short8 Bf[24];   // [ks*4+g]
    #pragma unroll
    for (int ks = 0; ks < 6; ++ks) {
        #pragma unroll
        for (int g = 0; g < 4; ++g) {
            int ci = ks * 32 + 8 * g + w;
            Bf[ks * 4 + g] = *(const short8*)&Bus[(size_t)ci * 512 + lane * 8];
        }
    }

    // zero h region (chunks 2..5), stage seq t=0 (chunks 0..1)
    for (int i = tid; i < 1024; i += 512) ((unsigned int*)Aus)[512 + i] = 0;
    {
        int i0 = tid * 2;
        int row = i0 >> 6, k0 = i0 & 63;
        float2 v = *(const float2*)&seq[((size_t)(b0 + row) * NT + 0) * 64 + k0];
        int ks = k0 >> 5, kr = k0 & 31;
        Aus[ks * 512 + (((kr >> 3) << 4) + row) * 8 + (kr & 7)] = hbits(fmaxf(v.x, 0.0f));
        kr = (k0 + 1) & 31; ks = (k0 + 1) >> 5;
        Aus[ks * 512 + (((kr >> 3) << 4) + row) * 8 + (kr & 7)] = hbits(fmaxf(v.y, 0.0f));
    }
    __syncthreads();

    for (int t = 0; t < NT; ++t) {
        f32x4 acc[4];
        #pragma unroll
        for (int g = 0; g < 4; ++g) acc[g] = (f32x4){0.f, 0.f, 0.f, 0.f};
        #pragma unroll
        for (int ks = 0; ks < 6; ++ks) {
            short8 ah = *(const short8*)&Aus[ks * 512 + lane * 8];
            #pragma unroll
            for (int g = 0; g < 4; ++g)
                acc[g] = __builtin_amdgcn_mfma_f32_16x16x32_f16(ah, Bf[ks * 4 + g], acc[g], 0, 0, 0);
        }
        __syncthreads();   // all A reads of t complete

        if (t == NT - 1) {
            #pragma unroll
            for (int q = 0; q < 4; ++q) {
                float nc = fsigm(acc[1][q] + bF) * cst[q]
                         + fsigm(acc[0][q] + bI) * ftanh(acc[2][q] + bG);
                cst[q] = nc;
                float hv = fsigm(acc[3][q] + bO) * ftanh(nc);
                hout[(size_t)(b0 + rbase + q) * 128 + u] = hv;
            }
        } else {
            int kh = 64 + u;
            int ksh = kh >> 5, krh = kh & 31;
            int hbase = ksh * 512 + ((krh >> 3) << 4) * 8 + (krh & 7);
            #pragma unroll
            for (int q = 0; q < 4; ++q) {
                float nc = fsigm(acc[1][q] + bF) * cst[q]
                         + fsigm(acc[0][q] + bI) * ftanh(acc[2][q] + bG);
                cst[q] = nc;
                float hv = fsigm(acc[3][q] + bO) * ftanh(nc);
                Aus[hbase + (rbase + q) * 8] = hbits(hv);
            }
            {
                int i0 = tid * 2;
                int row = i0 >> 6, k0 = i0 & 63;
                float2 v = *(const float2*)&seq[((size_t)(b0 + row) * NT + (t + 1)) * 64 + k0];
                int ks = k0 >> 5, kr = k0 & 31;
                Aus[ks * 512 + (((kr >> 3) << 4) + row) * 8 + (kr & 7)] = hbits(fmaxf(v.x, 0.0f));
                kr = (k0 + 1) & 31; ks = (k0 + 1) >> 5;
                Aus[ks * 512 + (((kr >> 3) << 4) + row) * 8 + (kr & 7)] = hbits(fmaxf(v.y, 0.0f));
            }
            __syncthreads();
        }
    }
}

// ---------- FC head + softmax: one wave per row ----------
__global__ __launch_bounds__(256) void k_fc(const float* __restrict__ h,
                                            const float* __restrict__ fw1,
                                            const float* __restrict__ fb1,
                                            const float* __restrict__ fw2,
                                            const float* __restrict__ fb2,
                                            float* __restrict__ out) {
    __shared__ float hid[4][64];
    int tid = threadIdx.x;
    int lane = tid & 63;
    int w = tid >> 6;
    int b = blockIdx.x * 4 + w;
    const float* hr = h + b * 128;
    float acc = fb1[lane];
    #pragma unroll 4
    for (int k = 0; k < 128; ++k) acc = fmaf(hr[k], fw1[k * 64 + lane], acc);
    hid[w][lane] = fmaxf(acc, 0.0f);
    __syncthreads();
    if (lane == 0) {
        float lg[3];
        #pragma unroll
        for (int l = 0; l < 3; ++l) {
            float a = fb2[l];
            for (int j = 0; j < 64; ++j) a = fmaf(hid[w][j], fw2[j * 3 + l], a);
            lg[l] = a;
        }
        float m = fmaxf(lg[0], fmaxf(lg[1], lg[2]));
        float e0 = expf(lg[0] - m), e1 = expf(lg[1] - m), e2 = expf(lg[2] - m);
        float s = 1.0f / (e0 + e1 + e2);
        out[b * 3 + 0] = e0 * s;
        out[b * 3 + 1] = e1 * s;
        out[b * 3 + 2] = e2 * s;
    }
}

extern "C" void kernel_launch(void* const* d_in, const int* in_sizes, int n_in,
                              void* d_out, int out_size, void* d_ws, size_t ws_size,
                              hipStream_t stream) {
    const float* x    = (const float*)d_in[0];
    const float* ea   = (const float*)d_in[1];
    const float* W1   = (const float*)d_in[2];
    const float* b1   = (const float*)d_in[3];
    const float* W2   = (const float*)d_in[4];
    const float* b2   = (const float*)d_in[5];
    const float* W_ih = (const float*)d_in[6];
    const float* W_hh = (const float*)d_in[7];
    const float* b_ih = (const float*)d_in[8];
    const float* b_hh = (const float*)d_in[9];
    const float* fw1  = (const float*)d_in[10];
    const float* fb1  = (const float*)d_in[11];
    const float* fw2  = (const float*)d_in[12];
    const float* fb2  = (const float*)d_in[13];
    const int*   ei   = (const int*)d_in[14];
    float* out = (float*)d_out;

    float* ws    = (float*)d_ws;
    float* dinv  = ws;                          // NN
    float* bufA  = dinv + NN;                   // NN*64 fp32 region (reused: binned, fp16 linp)
    float* bufB  = bufA + NN * 64;              // NN*64 fp32
    unsigned short* Bus = (unsigned short*)(bufB + NN * 64);   // 98304 ushort (f16 frags)
    float* biasb = bufB + NN * 64 + 98304;      // 512
    float* hbuf  = biasb + 512;                 // NB*128
    int*   bcnt  = (int*)(hbuf + NB * 128);     // 256
    int*   bbase = bcnt + 256;                  // 256
    int*   bcur  = bbase + 256;                 // 256
    int*   off   = bcur + 256;                  // NN+4 (padded for edata alignment)
    uint2* edata = (uint2*)(off + NN + 4);      // NE * 8B (16B-aligned)
    uint2* binned = (uint2*)bufA;               // NE * 8B (dead before k_lin L1)
    __half* linp  = (__half*)bufA;              // NN*64 fp16 (after binned is dead)

    // ---- CSR build via two-level counting sort (deg folded into P2) ----
    k_zero256<<<1, 256, 0, stream>>>(bcnt);
    k_bhist<<<NBKT, 256, 0, stream>>>(ei, bcnt);
    k_bscan<<<1, 256, 0, stream>>>(bcnt, bbase, bcur);
    k_bin<<<NBKT, 256, 0, stream>>>(ei, ea, bcur, binned);
    k_csr<<<NBKT, 256, 0, stream>>>(binned, bbase, edata, off, dinv);

    // LSTM weight fragments (f16)
    k_wfrag<<<384, 256, 0, stream>>>(W_ih, W_hh, b_ih, b_hh, Bus, biasb);

    // GCN layer 1 (dinv folded into fp16 lin output)
    k_lin<16, false><<<16000, 256, 0, stream>>>(x, W1, dinv, linp);
    k_gather<<<16000, 256, 0, stream>>>(linp, edata, off, dinv, b1, bufB);

    // GCN layer 2 (relu fused into k_lin read; fp16 linp overwrites dead layer-1 copy)
    k_lin<64, true><<<16000, 256, 0, stream>>>(bufB, W2, dinv, linp);
    k_gather<<<16000, 256, 0, stream>>>(linp, edata, off, dinv, b2, bufB);

    // LSTM (relu fused into staging)
    k_lstm<<<250, 512, 0, stream>>>(bufB, Bus, biasb, hbuf);

    // FC head + softmax
    k_fc<<<1000, 256, 0, stream>>>(hbuf, fw1, fb1, fw2, fb2, out);
}

// Round 12
// 215.871 us; speedup vs baseline: 9.0772x; 1.0671x over previous
//
#include <hip/hip_runtime.h>
#include <hip/hip_bf16.h>
#include <hip/hip_fp16.h>
#include <math.h>

#define NN 64000      // nodes
#define NE 1024000    // edges
#define NB 4000       // sequences
#define NT 16         // timesteps
#define LROWS 16      // sequences per LSTM block
#define NBKT 250      // coarse buckets (c>>8), NN/256

typedef __attribute__((ext_vector_type(8))) short short8;
typedef __attribute__((ext_vector_type(4))) float f32x4;

// fast sigmoid/tanh: v_exp + v_rcp (exact at +-inf limits)
__device__ __forceinline__ float fsigm(float x) {
    return __builtin_amdgcn_rcpf(1.0f + __expf(-x));
}
__device__ __forceinline__ float ftanh(float x) {
    return 1.0f - 2.0f * __builtin_amdgcn_rcpf(1.0f + __expf(2.0f * x));
}
__device__ __forceinline__ unsigned short hbits(float v) {
    __half h = __float2half(v);
    return reinterpret_cast<unsigned short&>(h);
}

// ---------- zero the bucket counters ----------
__global__ __launch_bounds__(256) void k_zero256(int* __restrict__ p) {
    p[threadIdx.x] = 0;
}

// ---------- P0: coarse bucket histogram (LDS-privatized) ----------
__global__ __launch_bounds__(256) void k_bhist(const int* __restrict__ ei,
                                               int* __restrict__ bcnt) {
    __shared__ int h[256];
    int tid = threadIdx.x;
    h[tid] = 0;
    __syncthreads();
    int base = blockIdx.x * 4096;
    #pragma unroll
    for (int j = 0; j < 16; ++j) {
        int c = ei[NE + base + j * 256 + tid];
        atomicAdd(&h[c >> 8], 1);
    }
    __syncthreads();
    if (tid < NBKT && h[tid]) atomicAdd(&bcnt[tid], h[tid]);
}

// ---------- scan 250 bucket counts -> bbase[251]; cursor copy ----------
__global__ __launch_bounds__(256) void k_bscan(const int* __restrict__ bcnt,
                                               int* __restrict__ bbase,
                                               int* __restrict__ bcur) {
    __shared__ int sm[256];
    int tid = threadIdx.x;
    int v = (tid < NBKT) ? bcnt[tid] : 0;
    sm[tid] = v;
    __syncthreads();
    #pragma unroll
    for (int d = 1; d < 256; d <<= 1) {
        int t = (tid >= d) ? sm[tid - d] : 0;
        __syncthreads();
        sm[tid] += t;
        __syncthreads();
    }
    if (tid < NBKT) { int ex = sm[tid] - v; bbase[tid] = ex; bcur[tid] = ex; }
    if (tid == 255) bbase[NBKT] = sm[255];   // = NE
}

// ---------- P1: bin edges by bucket via LDS sort; coalesced run writes ----------
// record: x = r | (c&255)<<16 | bucket<<24 ; y = raw ew bits
__global__ __launch_bounds__(256) void k_bin(const int* __restrict__ ei,
                                             const float* __restrict__ ew,
                                             int* __restrict__ bcur,
                                             uint2* __restrict__ binned) {
    __shared__ uint2 stage[4096];
    __shared__ int sm[256];
    __shared__ int lofs[256], lcur[256], ladj[256];
    int tid = threadIdx.x;
    sm[tid] = 0;
    __syncthreads();
    int base = blockIdx.x * 4096;
    int cs[16];
    #pragma unroll
    for (int j = 0; j < 16; ++j) {
        cs[j] = ei[NE + base + j * 256 + tid];
        atomicAdd(&sm[cs[j] >> 8], 1);
    }
    __syncthreads();
    int v = sm[tid];
    #pragma unroll
    for (int d = 1; d < 256; d <<= 1) {
        int t = (tid >= d) ? sm[tid - d] : 0;
        __syncthreads();
        sm[tid] += t;
        __syncthreads();
    }
    int ex = sm[tid] - v;
    lofs[tid] = ex;
    lcur[tid] = ex;
    if (tid < NBKT) ladj[tid] = atomicAdd(&bcur[tid], v) - ex;
    __syncthreads();
    #pragma unroll
    for (int j = 0; j < 16; ++j) {
        int e = base + j * 256 + tid;
        int c = cs[j];
        int b = c >> 8;
        unsigned r = (unsigned)ei[e];
        float wv = ew[e];
        int slot = atomicAdd(&lcur[b], 1);
        stage[slot] = make_uint2(r | ((unsigned)(c & 255) << 16) | ((unsigned)b << 24),
                                 __float_as_uint(wv));
    }
    __syncthreads();
    #pragma unroll
    for (int j = 0; j < 16; ++j) {
        int i = j * 256 + tid;
        uint2 rec = stage[i];
        int b = rec.x >> 24;
        binned[ladj[b] + i] = rec;
    }
}

// ---------- P2: per-bucket final CSR sort + off[] + dinv (deg folded) ----------
__global__ __launch_bounds__(256) void k_csr(const uint2* __restrict__ binned,
                                             const int* __restrict__ bbase,
                                             uint2* __restrict__ edata,
                                             int* __restrict__ off,
                                             float* __restrict__ dinv) {
    __shared__ int cnt[256];
    __shared__ float sumw[256];
    __shared__ int lcur[256];
    __shared__ int sm[256];
    int tid = threadIdx.x;
    int b = blockIdx.x;
    int s = bbase[b], e1 = bbase[b + 1];
    cnt[tid] = 0;
    sumw[tid] = 0.0f;
    __syncthreads();
    for (int i = s + tid; i < e1; i += 256) {
        uint2 rec = binned[i];
        int nl = (rec.x >> 16) & 255;
        atomicAdd(&cnt[nl], 1);
        atomicAdd(&sumw[nl], __uint_as_float(rec.y));
    }
    __syncthreads();
    int v = cnt[tid];
    sm[tid] = v;
    __syncthreads();
    #pragma unroll
    for (int d = 1; d < 256; d <<= 1) {
        int t = (tid >= d) ? sm[tid - d] : 0;
        __syncthreads();
        sm[tid] += t;
        __syncthreads();
    }
    int ex = sm[tid] - v;
    off[b * 256 + tid] = s + ex;
    dinv[b * 256 + tid] = rsqrtf(1.0f + sumw[tid]);
    lcur[tid] = ex;
    if (b == 0 && tid == 0) off[NN] = NE;
    __syncthreads();
    for (int i = s + tid; i < e1; i += 256) {
        uint2 rec = binned[i];
        int nl = (rec.x >> 16) & 255;
        int p = atomicAdd(&lcur[nl], 1);
        edata[s + p] = make_uint2(rec.x & 0xFFFFu, rec.y);
    }
}

// ---------- node linear (+dinv fold), fp16 output: Y = ((relu?)X @ W) * dinv ----------
template<int K, bool RELU_IN>
__global__ __launch_bounds__(256) void k_lin(const float* __restrict__ X,
                                             const float* __restrict__ W,
                                             const float* __restrict__ dinv,
                                             __half* __restrict__ Y) {
    __shared__ float Wl[K * 64];
    __shared__ float Xl[4][K];
    int tid = threadIdx.x;
    for (int i = tid; i < K * 64; i += 256) Wl[i] = W[i];
    int n0 = blockIdx.x * 4;
    for (int i = tid; i < 4 * K; i += 256) {
        int r = i / K, d = i % K;
        float v = X[(n0 + r) * K + d];
        Xl[r][d] = RELU_IN ? fmaxf(v, 0.0f) : v;
    }
    __syncthreads();
    int r = tid >> 6, f = tid & 63;
    float acc = 0.0f;
    #pragma unroll
    for (int d = 0; d < K; ++d) acc = fmaf(Xl[r][d], Wl[d * 64 + f], acc);
    Y[(n0 + r) * 64 + f] = __float2half(acc * dinv[n0 + r]);
}

// ---------- CSR gather, split-wave half2: lanes 0-31 even edges, 32-63 odd ----------
// Each lane loads half2 (2 features, 4B) -> one wave instruction fetches TWO rows;
// 4-deep unroll = 8 edges in flight. agg = dinv[n]*(linp[n] + sum ew*linp[r]) + b
__global__ __launch_bounds__(256) void k_gather(const __half* __restrict__ linp,
                                                const uint2* __restrict__ edata,
                                                const int* __restrict__ off,
                                                const float* __restrict__ dinv,
                                                const float* __restrict__ bvec,
                                                float* __restrict__ agg) {
    int tid = threadIdx.x;
    int lane = tid & 63;
    int wv = tid >> 6;
    int n = blockIdx.x * 4 + wv;
    int hf = lane >> 5;
    int fl = lane & 31;                       // feature-pair index (features 2fl, 2fl+1)
    const __half2* lp2 = (const __half2*)linp;
    float2 acc = make_float2(0.0f, 0.0f);
    if (hf == 0) {
        acc = __half22float2(lp2[((size_t)n << 5) + fl]);   // self term (once)
    }
    int s = off[n], e1 = off[n + 1];
    int e = s + hf;
    for (; e + 6 < e1; e += 8) {
        uint2 d0 = edata[e];
        uint2 d1 = edata[e + 2];
        uint2 d2 = edata[e + 4];
        uint2 d3 = edata[e + 6];
        float2 l0 = __half22float2(lp2[((size_t)d0.x << 5) + fl]);
        float2 l1 = __half22float2(lp2[((size_t)d1.x << 5) + fl]);
        float2 l2 = __half22float2(lp2[((size_t)d2.x << 5) + fl]);
        float2 l3 = __half22float2(lp2[((size_t)d3.x << 5) + fl]);
        float w0 = __uint_as_float(d0.y), w1 = __uint_as_float(d1.y);
        float w2 = __uint_as_float(d2.y), w3 = __uint_as_float(d3.y);
        acc.x = fmaf(w0, l0.x, acc.x); acc.y = fmaf(w0, l0.y, acc.y);
        acc.x = fmaf(w1, l1.x, acc.x); acc.y = fmaf(w1, l1.y, acc.y);
        acc.x = fmaf(w2, l2.x, acc.x); acc.y = fmaf(w2, l2.y, acc.y);
        acc.x = fmaf(w3, l3.x, acc.x); acc.y = fmaf(w3, l3.y, acc.y);
    }
    for (; e < e1; e += 2) {
        uint2 d0 = edata[e];
        float2 l0 = __half22float2(lp2[((size_t)d0.x << 5) + fl]);
        float w0 = __uint_as_float(d0.y);
        acc.x = fmaf(w0, l0.x, acc.x);
        acc.y = fmaf(w0, l0.y, acc.y);
    }
    // combine the two parity halves
    acc.x += __shfl_xor(acc.x, 32, 64);
    acc.y += __shfl_xor(acc.y, 32, 64);
    if (hf == 0) {
        float dn = dinv[n];
        float2 outv;
        outv.x = fmaf(dn, acc.x, bvec[fl * 2]);
        outv.y = fmaf(dn, acc.y, bvec[fl * 2 + 1]);
        *(float2*)&agg[((size_t)n << 6) + fl * 2] = outv;
    }
}

// ---------- LSTM weight fragment prep (single f16, MFMA B layout) ----------
// chunk ci = ks*32+ntg, 1KB: lane l, elem j -> col = ntg*16+(l&15), k = ks*32+(l>>4)*8+j
__global__ __launch_bounds__(256) void k_wfrag(const float* __restrict__ W_ih,
                                               const float* __restrict__ W_hh,
                                               const float* __restrict__ b_ih,
                                               const float* __restrict__ b_hh,
                                               unsigned short* __restrict__ Bus,
                                               float* __restrict__ biasb) {
    int i = blockIdx.x * 256 + threadIdx.x;
    if (i < 192 * 512) {
        int j = i & 7;
        int l = (i >> 3) & 63;
        int ci = i >> 9;
        int ntg = ci & 31;
        int ks = ci >> 5;
        int col = ntg * 16 + (l & 15);
        int k = ks * 32 + ((l >> 4) << 3) + j;
        float w = (k < 64) ? W_ih[col * 64 + k] : W_hh[col * 128 + (k - 64)];
        Bus[i] = hbits(w);
    }
    if (i < 512) biasb[i] = b_ih[i] + b_hh[i];
}

// ---------- LSTM: single-product f16 MFMA; B-slice register-resident (96 VGPR) ----------
// Wave w owns units u = w*16+(lane&15) across all 4 gates (B chunks ntg=8g+w).
__global__ __launch_bounds__(512, 2) void k_lstm(const float* __restrict__ seq,
                                                 const unsigned short* __restrict__ Bus,
                                                 const float* __restrict__ biasb,
                                                 float* __restrict__ hout) {
    __shared__ unsigned short Aus[6 * 512];   // 6 ks x 1KB (f16)
    int tid = threadIdx.x;
    int lane = tid & 63;
    int w = tid >> 6;
    int b0 = blockIdx.x * LROWS;

    int u = w * 16 + (lane & 15);
    int rbase = (lane >> 4) * 4;
    float bI = biasb[u], bF = biasb[128 + u], bG = biasb[256 + u], bO = biasb[384 + u];
    float cst[4] = {0.0f, 0.0f, 0.0f, 0.0f};

    // ---- load this wave's B slice into registers (once): 24 x short8 = 96 VGPR ----
    short8 Bf[24];   // [ks*4+g]
    #pragma unroll
    for (int ks = 0; ks < 6; ++ks) {
        #pragma unroll
        for (int g = 0; g < 4; ++g) {
            int ci = ks * 32 + 8 * g + w;
            Bf[ks * 4 + g] = *(const short8*)&Bus[(size_t)ci * 512 + lane * 8];
        }
    }

    // zero h region (chunks 2..5), stage seq t=0 (chunks 0..1)
    for (int i = tid; i < 1024; i += 512) ((unsigned int*)Aus)[512 + i] = 0;
    {
        int i0 = tid * 2;
        int row = i0 >> 6, k0 = i0 & 63;
        float2 v = *(const float2*)&seq[((size_t)(b0 + row) * NT + 0) * 64 + k0];
        int ks = k0 >> 5, kr = k0 & 31;
        Aus[ks * 512 + (((kr >> 3) << 4) + row) * 8 + (kr & 7)] = hbits(fmaxf(v.x, 0.0f));
        kr = (k0 + 1) & 31; ks = (k0 + 1) >> 5;
        Aus[ks * 512 + (((kr >> 3) << 4) + row) * 8 + (kr & 7)] = hbits(fmaxf(v.y, 0.0f));
    }
    __syncthreads();

    for (int t = 0; t < NT; ++t) {
        f32x4 acc[4];
        #pragma unroll
        for (int g = 0; g < 4; ++g) acc[g] = (f32x4){0.f, 0.f, 0.f, 0.f};
        #pragma unroll
        for (int ks = 0; ks < 6; ++ks) {
            short8 ah = *(const short8*)&Aus[ks * 512 + lane * 8];
            #pragma unroll
            for (int g = 0; g < 4; ++g)
                acc[g] = __builtin_amdgcn_mfma_f32_16x16x32_f16(ah, Bf[ks * 4 + g], acc[g], 0, 0, 0);
        }
        __syncthreads();   // all A reads of t complete

        if (t == NT - 1) {
            #pragma unroll
            for (int q = 0; q < 4; ++q) {
                float nc = fsigm(acc[1][q] + bF) * cst[q]
                         + fsigm(acc[0][q] + bI) * ftanh(acc[2][q] + bG);
                cst[q] = nc;
                float hv = fsigm(acc[3][q] + bO) * ftanh(nc);
                hout[(size_t)(b0 + rbase + q) * 128 + u] = hv;
            }
        } else {
            int kh = 64 + u;
            int ksh = kh >> 5, krh = kh & 31;
            int hbase = ksh * 512 + ((krh >> 3) << 4) * 8 + (krh & 7);
            #pragma unroll
            for (int q = 0; q < 4; ++q) {
                float nc = fsigm(acc[1][q] + bF) * cst[q]
                         + fsigm(acc[0][q] + bI) * ftanh(acc[2][q] + bG);
                cst[q] = nc;
                float hv = fsigm(acc[3][q] + bO) * ftanh(nc);
                Aus[hbase + (rbase + q) * 8] = hbits(hv);
            }
            {
                int i0 = tid * 2;
                int row = i0 >> 6, k0 = i0 & 63;
                float2 v = *(const float2*)&seq[((size_t)(b0 + row) * NT + (t + 1)) * 64 + k0];
                int ks = k0 >> 5, kr = k0 & 31;
                Aus[ks * 512 + (((kr >> 3) << 4) + row) * 8 + (kr & 7)] = hbits(fmaxf(v.x, 0.0f));
                kr = (k0 + 1) & 31; ks = (k0 + 1) >> 5;
                Aus[ks * 512 + (((kr >> 3) << 4) + row) * 8 + (kr & 7)] = hbits(fmaxf(v.y, 0.0f));
            }
            __syncthreads();
        }
    }
}

// ---------- FC head + softmax: one wave per row ----------
__global__ __launch_bounds__(256) void k_fc(const float* __restrict__ h,
                                            const float* __restrict__ fw1,
                                            const float* __restrict__ fb1,
                                            const float* __restrict__ fw2,
                                            const float* __restrict__ fb2,
                                            float* __restrict__ out) {
    __shared__ float hid[4][64];
    int tid = threadIdx.x;
    int lane = tid & 63;
    int w = tid >> 6;
    int b = blockIdx.x * 4 + w;
    const float* hr = h + b * 128;
    float acc = fb1[lane];
    #pragma unroll 4
    for (int k = 0; k < 128; ++k) acc = fmaf(hr[k], fw1[k * 64 + lane], acc);
    hid[w][lane] = fmaxf(acc, 0.0f);
    __syncthreads();
    if (lane == 0) {
        float lg[3];
        #pragma unroll
        for (int l = 0; l < 3; ++l) {
            float a = fb2[l];
            for (int j = 0; j < 64; ++j) a = fmaf(hid[w][j], fw2[j * 3 + l], a);
            lg[l] = a;
        }
        float m = fmaxf(lg[0], fmaxf(lg[1], lg[2]));
        float e0 = expf(lg[0] - m), e1 = expf(lg[1] - m), e2 = expf(lg[2] - m);
        float s = 1.0f / (e0 + e1 + e2);
        out[b * 3 + 0] = e0 * s;
        out[b * 3 + 1] = e1 * s;
        out[b * 3 + 2] = e2 * s;
    }
}

extern "C" void kernel_launch(void* const* d_in, const int* in_sizes, int n_in,
                              void* d_out, int out_size, void* d_ws, size_t ws_size,
                              hipStream_t stream) {
    const float* x    = (const float*)d_in[0];
    const float* ea   = (const float*)d_in[1];
    const float* W1   = (const float*)d_in[2];
    const float* b1   = (const float*)d_in[3];
    const float* W2   = (const float*)d_in[4];
    const float* b2   = (const float*)d_in[5];
    const float* W_ih = (const float*)d_in[6];
    const float* W_hh = (const float*)d_in[7];
    const float* b_ih = (const float*)d_in[8];
    const float* b_hh = (const float*)d_in[9];
    const float* fw1  = (const float*)d_in[10];
    const float* fb1  = (const float*)d_in[11];
    const float* fw2  = (const float*)d_in[12];
    const float* fb2  = (const float*)d_in[13];
    const int*   ei   = (const int*)d_in[14];
    float* out = (float*)d_out;

    float* ws    = (float*)d_ws;
    float* dinv  = ws;                          // NN
    float* bufA  = dinv + NN;                   // NN*64 fp32 region (reused: binned, fp16 linp)
    float* bufB  = bufA + NN * 64;              // NN*64 fp32
    unsigned short* Bus = (unsigned short*)(bufB + NN * 64);   // 98304 ushort (f16 frags)
    float* biasb = bufB + NN * 64 + 98304;      // 512
    float* hbuf  = biasb + 512;                 // NB*128
    int*   bcnt  = (int*)(hbuf + NB * 128);     // 256
    int*   bbase = bcnt + 256;                  // 256
    int*   bcur  = bbase + 256;                 // 256
    int*   off   = bcur + 256;                  // NN+4 (padded for edata alignment)
    uint2* edata = (uint2*)(off + NN + 4);      // NE * 8B (16B-aligned)
    uint2* binned = (uint2*)bufA;               // NE * 8B (dead before k_lin L1)
    __half* linp  = (__half*)bufA;              // NN*64 fp16 (after binned is dead)

    // ---- CSR build via two-level counting sort (deg folded into P2) ----
    k_zero256<<<1, 256, 0, stream>>>(bcnt);
    k_bhist<<<NBKT, 256, 0, stream>>>(ei, bcnt);
    k_bscan<<<1, 256, 0, stream>>>(bcnt, bbase, bcur);
    k_bin<<<NBKT, 256, 0, stream>>>(ei, ea, bcur, binned);
    k_csr<<<NBKT, 256, 0, stream>>>(binned, bbase, edata, off, dinv);

    // LSTM weight fragments (f16)
    k_wfrag<<<384, 256, 0, stream>>>(W_ih, W_hh, b_ih, b_hh, Bus, biasb);

    // GCN layer 1 (dinv folded into fp16 lin output)
    k_lin<16, false><<<16000, 256, 0, stream>>>(x, W1, dinv, linp);
    k_gather<<<16000, 256, 0, stream>>>(linp, edata, off, dinv, b1, bufB);

    // GCN layer 2 (relu fused into k_lin read; fp16 linp overwrites dead layer-1 copy)
    k_lin<64, true><<<16000, 256, 0, stream>>>(bufB, W2, dinv, linp);
    k_gather<<<16000, 256, 0, stream>>>(linp, edata, off, dinv, b2, bufB);

    // LSTM (relu fused into staging)
    k_lstm<<<250, 512, 0, stream>>>(bufB, Bus, biasb, hbuf);

    // FC head + softmax
    k_fc<<<1000, 256, 0, stream>>>(hbuf, fw1, fb1, fw2, fb2, out);
}